// Round 1
// baseline (748.604 us; speedup 1.0000x reference)
//
#include <hip/hip_runtime.h>
#include <math.h>

typedef __bf16 bf16x8 __attribute__((ext_vector_type(8)));
typedef float f32x4 __attribute__((ext_vector_type(4)));
typedef unsigned short u16;

#define BB 2
#define TT 2048
#define EE 768
#define HH 12
#define DD 64
#define BH (BB*HH)      /* 24 */
#define M4 (BB*TT)      /* 4096 */
#define NQKV (3*EE)     /* 2304 */

__device__ __forceinline__ u16 f2bf(float f) {
    union { float f; unsigned u; } v; v.f = f;
    unsigned r = v.u + 0x7FFFu + ((v.u >> 16) & 1u);
    return (u16)(r >> 16);
}
__device__ __forceinline__ float bf2f(u16 u) {
    union { unsigned u; float f; } v; v.u = ((unsigned)u) << 16;
    return v.f;
}

// ---------------------------------------------------------------- casts
__global__ void cast_x_kernel(const float* __restrict__ x, u16* __restrict__ xb, int n) {
    int i = blockIdx.x * blockDim.x + threadIdx.x;
    if (i < n) xb[i] = f2bf(x[i]);
}

// dst[n*K + k] = src[k*N + n]  (cast to bf16)
__global__ void transpose_cast_kernel(const float* __restrict__ src, u16* __restrict__ dst, int N, int K) {
    int i = blockIdx.x * blockDim.x + threadIdx.x;
    if (i >= N * K) return;
    int n = i / K, k = i - n * K;
    dst[i] = f2bf(src[(size_t)k * N + n]);
}

// ---------------------------------------------------------------- QKV GEMM
// A: xb (4096 x 768) bf16 row-major. Bt: wqkv_t (2304 x 768) bf16 (N x K).
// Writes q/k/v as (B,H,T,D) bf16.
__global__ __launch_bounds__(256) void gemm_qkv_kernel(
    const u16* __restrict__ A, const u16* __restrict__ Bt,
    u16* __restrict__ qb, u16* __restrict__ kb, u16* __restrict__ vb)
{
    const int K = EE;
    int w = threadIdx.x >> 6, l = threadIdx.x & 63;
    int lo = l & 15, hi = l >> 4;
    int m0 = blockIdx.x * 64 + (w >> 1) * 32;
    int n0 = blockIdx.y * 64 + (w & 1) * 32;
    f32x4 c[2][2] = {};
    for (int k0 = 0; k0 < K; k0 += 32) {
        bf16x8 a0 = *(const bf16x8*)(A + (size_t)(m0 + lo) * K + k0 + hi * 8);
        bf16x8 a1 = *(const bf16x8*)(A + (size_t)(m0 + 16 + lo) * K + k0 + hi * 8);
        bf16x8 b0 = *(const bf16x8*)(Bt + (size_t)(n0 + lo) * K + k0 + hi * 8);
        bf16x8 b1 = *(const bf16x8*)(Bt + (size_t)(n0 + 16 + lo) * K + k0 + hi * 8);
        c[0][0] = __builtin_amdgcn_mfma_f32_16x16x32_bf16(a0, b0, c[0][0], 0, 0, 0);
        c[0][1] = __builtin_amdgcn_mfma_f32_16x16x32_bf16(a0, b1, c[0][1], 0, 0, 0);
        c[1][0] = __builtin_amdgcn_mfma_f32_16x16x32_bf16(a1, b0, c[1][0], 0, 0, 0);
        c[1][1] = __builtin_amdgcn_mfma_f32_16x16x32_bf16(a1, b1, c[1][1], 0, 0, 0);
    }
#pragma unroll
    for (int i = 0; i < 2; i++)
#pragma unroll
        for (int j = 0; j < 2; j++)
#pragma unroll
            for (int r = 0; r < 4; r++) {
                int m = m0 + 16 * i + hi * 4 + r;
                int n = n0 + 16 * j + lo;
                int sel = n / EE, rem = n - sel * EE;
                int h = rem >> 6, d = rem & 63;
                int b = m >> 11, t = m & 2047;
                size_t idx = ((size_t)(b * HH + h) * TT + t) * DD + d;
                u16 val = f2bf(c[i][j][r]);
                u16* dst = (sel == 0) ? qb : (sel == 1) ? kb : vb;
                dst[idx] = val;
            }
}

// ---------------------------------------------------------------- r = scale * x . wr  (per (b,h,t))
__global__ __launch_bounds__(256) void r_kernel(const float* __restrict__ x,
                                                const float* __restrict__ wr,
                                                float* __restrict__ r) {
    __shared__ float xs[256][33];
    int blk = blockIdx.x;
    int t0 = (blk & 7) * 256;
    int h = (blk >> 3) % HH;
    int b = blk / (8 * HH);
    int tid = threadIdx.x;
    const float scale = 0.125f;
    float acc = 0.f;
    for (int e0 = 0; e0 < EE; e0 += 32) {
        __syncthreads();
#pragma unroll
        for (int i = 0; i < 32; i++) {
            int idx = i * 256 + tid;
            int ttr = idx >> 5, ee = idx & 31;
            xs[ttr][ee] = x[((size_t)b * TT + t0 + ttr) * EE + e0 + ee];
        }
        __syncthreads();
#pragma unroll 8
        for (int ee = 0; ee < 32; ee++)
            acc += xs[tid][ee] * wr[((size_t)h * EE + e0 + ee) * TT + t0 + tid];
    }
    r[((size_t)b * HH + h) * TT + t0 + tid] = acc * scale;
}

__global__ void rmax_kernel(const float* __restrict__ r, float* __restrict__ rmax) {
    int bh = blockIdx.x, tid = threadIdx.x;
    float m = -INFINITY;
    for (int j = tid; j < TT; j += 256) m = fmaxf(m, r[(size_t)bh * TT + j]);
    __shared__ float sm[256];
    sm[tid] = m; __syncthreads();
    for (int s = 128; s > 0; s >>= 1) {
        if (tid < s) sm[tid] = fmaxf(sm[tid], sm[tid + s]);
        __syncthreads();
    }
    if (tid == 0) rmax[bh] = sm[0];
}

// ---------------------------------------------------------------- rr attention = prefix scan
// out_r[bh][t][d] = sum_{j<=t} w_j v[j][d] / sum_{j<=t} w_j,  w_j = exp(r_j - max)
__global__ __launch_bounds__(64) void scan_kernel(const float* __restrict__ r,
                                                  const float* __restrict__ rmax,
                                                  const u16* __restrict__ vb,
                                                  float* __restrict__ outr) {
    int bh = blockIdx.x, d = threadIdx.x;
    float mx = rmax[bh];
    float acc = 0.f, l = 0.f;
    const float* rp = r + (size_t)bh * TT;
    const u16* vp = vb + (size_t)bh * TT * DD + d;
    float* op = outr + (size_t)bh * TT * DD + d;
#pragma unroll 4
    for (int j = 0; j < TT; j++) {
        float w = __expf(rp[j] - mx);
        l += w;
        acc += w * bf2f(vp[(size_t)j * DD]);
        op[(size_t)j * DD] = acc / l;
    }
}

// ---------------------------------------------------------------- content flash attention
// one wave per 16 q rows; key chunks of 32; MFMA 16x16x32 bf16
__global__ __launch_bounds__(64) void flash_kernel(const u16* __restrict__ qb,
                                                   const u16* __restrict__ kb,
                                                   const u16* __restrict__ vb,
                                                   float* __restrict__ outc) {
    __shared__ __align__(16) u16 p_lds[16][40];
    int bh = blockIdx.y;
    int q0 = blockIdx.x * 16;
    int l = threadIdx.x;
    int lo = l & 15, hi = l >> 4;
    const float scale = 0.125f;
    const u16* qbase = qb + (size_t)bh * TT * DD;
    const u16* kbase = kb + (size_t)bh * TT * DD;
    const u16* vbase = vb + (size_t)bh * TT * DD;

    bf16x8 aQ0 = *(const bf16x8*)(qbase + (size_t)(q0 + lo) * DD + hi * 8);
    bf16x8 aQ1 = *(const bf16x8*)(qbase + (size_t)(q0 + lo) * DD + 32 + hi * 8);

    float m[4], lsum[4];
    f32x4 o[4] = {};
#pragma unroll
    for (int r = 0; r < 4; r++) { m[r] = -INFINITY; lsum[r] = 0.f; }

    for (int j0 = 0; j0 <= q0 + 15; j0 += 32) {
        f32x4 s[2] = {};
#pragma unroll
        for (int j = 0; j < 2; j++) {
            const u16* kp = kbase + (size_t)(j0 + 16 * j + lo) * DD + hi * 8;
            bf16x8 bk0 = *(const bf16x8*)(kp);
            bf16x8 bk1 = *(const bf16x8*)(kp + 32);
            s[j] = __builtin_amdgcn_mfma_f32_16x16x32_bf16(aQ0, bk0, s[j], 0, 0, 0);
            s[j] = __builtin_amdgcn_mfma_f32_16x16x32_bf16(aQ1, bk1, s[j], 0, 0, 0);
        }
        float tm[4], p0a[4], p1a[4];
#pragma unroll
        for (int r = 0; r < 4; r++) {
            int q = q0 + hi * 4 + r;
            float v0 = s[0][r] * scale, v1 = s[1][r] * scale;
            if (j0 + lo > q) v0 = -INFINITY;
            if (j0 + 16 + lo > q) v1 = -INFINITY;
            s[0][r] = v0; s[1][r] = v1;
            tm[r] = fmaxf(v0, v1);
        }
#pragma unroll
        for (int msk = 1; msk < 16; msk <<= 1)
#pragma unroll
            for (int r = 0; r < 4; r++) tm[r] = fmaxf(tm[r], __shfl_xor(tm[r], msk, 64));
        float rs[4];
#pragma unroll
        for (int r = 0; r < 4; r++) {
            float mn = fmaxf(m[r], tm[r]);
            float f = __expf(m[r] - mn);
            m[r] = mn;
            float p0 = __expf(s[0][r] - mn);
            float p1 = __expf(s[1][r] - mn);
            p0a[r] = p0; p1a[r] = p1;
            rs[r] = p0 + p1;
            lsum[r] *= f;
#pragma unroll
            for (int jd = 0; jd < 4; jd++) o[jd][r] *= f;
        }
#pragma unroll
        for (int msk = 1; msk < 16; msk <<= 1)
#pragma unroll
            for (int r = 0; r < 4; r++) rs[r] += __shfl_xor(rs[r], msk, 64);
#pragma unroll
        for (int r = 0; r < 4; r++) lsum[r] += rs[r];
        // P (C-layout) -> LDS -> A-layout fragment (intra-wave; HW DS ops in order)
#pragma unroll
        for (int r = 0; r < 4; r++) {
            p_lds[hi * 4 + r][lo] = f2bf(p0a[r]);
            p_lds[hi * 4 + r][16 + lo] = f2bf(p1a[r]);
        }
        asm volatile("" ::: "memory");
        bf16x8 aP = *(const bf16x8*)(&p_lds[lo][hi * 8]);
        asm volatile("" ::: "memory");
#pragma unroll
        for (int jd = 0; jd < 4; jd++) {
            union { u16 u[8]; bf16x8 v; } vv;
#pragma unroll
            for (int e = 0; e < 8; e++)
                vv.u[e] = vbase[(size_t)(j0 + hi * 8 + e) * DD + jd * 16 + lo];
            o[jd] = __builtin_amdgcn_mfma_f32_16x16x32_bf16(aP, vv.v, o[jd], 0, 0, 0);
        }
    }
    float* ob = outc + (size_t)bh * TT * DD;
#pragma unroll
    for (int r = 0; r < 4; r++) {
        float inv = 1.f / lsum[r];
#pragma unroll
        for (int jd = 0; jd < 4; jd++)
            ob[(size_t)(q0 + hi * 4 + r) * DD + jd * 16 + lo] = o[jd][r] * inv;
    }
}

// ---------------------------------------------------------------- combine: a*rr + (1-a)*content -> (B,T,H*D) bf16
__global__ void combine_kernel(const float* __restrict__ outr, const float* __restrict__ outc,
                               const float* __restrict__ alpha, u16* __restrict__ comb) {
    int i = blockIdx.x * blockDim.x + threadIdx.x;
    if (i >= M4 * EE) return;
    int bt = i / EE, c = i - bt * EE;
    int h = c >> 6, d = c & 63;
    int b = bt >> 11, t = bt & 2047;
    size_t src = ((size_t)(b * HH + h) * TT + t) * DD + d;
    float a = 1.f / (1.f + __expf(-alpha[h]));
    comb[i] = f2bf(a * outr[src] + (1.f - a) * outc[src]);
}

// ---------------------------------------------------------------- output GEMM: comb (4096x768) @ wo -> out fp32
__global__ __launch_bounds__(256) void gemm_out_kernel(const u16* __restrict__ A,
                                                       const u16* __restrict__ Bt,
                                                       float* __restrict__ C) {
    const int K = EE, N = EE;
    int w = threadIdx.x >> 6, l = threadIdx.x & 63;
    int lo = l & 15, hi = l >> 4;
    int m0 = blockIdx.x * 64 + (w >> 1) * 32;
    int n0 = blockIdx.y * 64 + (w & 1) * 32;
    f32x4 c[2][2] = {};
    for (int k0 = 0; k0 < K; k0 += 32) {
        bf16x8 a0 = *(const bf16x8*)(A + (size_t)(m0 + lo) * K + k0 + hi * 8);
        bf16x8 a1 = *(const bf16x8*)(A + (size_t)(m0 + 16 + lo) * K + k0 + hi * 8);
        bf16x8 b0 = *(const bf16x8*)(Bt + (size_t)(n0 + lo) * K + k0 + hi * 8);
        bf16x8 b1 = *(const bf16x8*)(Bt + (size_t)(n0 + 16 + lo) * K + k0 + hi * 8);
        c[0][0] = __builtin_amdgcn_mfma_f32_16x16x32_bf16(a0, b0, c[0][0], 0, 0, 0);
        c[0][1] = __builtin_amdgcn_mfma_f32_16x16x32_bf16(a0, b1, c[0][1], 0, 0, 0);
        c[1][0] = __builtin_amdgcn_mfma_f32_16x16x32_bf16(a1, b0, c[1][0], 0, 0, 0);
        c[1][1] = __builtin_amdgcn_mfma_f32_16x16x32_bf16(a1, b1, c[1][1], 0, 0, 0);
    }
#pragma unroll
    for (int i = 0; i < 2; i++)
#pragma unroll
        for (int j = 0; j < 2; j++)
#pragma unroll
            for (int r = 0; r < 4; r++)
                C[(size_t)(m0 + 16 * i + hi * 4 + r) * N + n0 + 16 * j + lo] = c[i][j][r];
}

// ----------------------------------------------------------------
extern "C" void kernel_launch(void* const* d_in, const int* in_sizes, int n_in,
                              void* d_out, int out_size, void* d_ws, size_t ws_size,
                              hipStream_t stream) {
    const float* x = (const float*)d_in[0];
    const float* wq = (const float*)d_in[1];
    const float* wk = (const float*)d_in[2];
    const float* wv = (const float*)d_in[3];
    const float* wr = (const float*)d_in[4];
    const float* alpha = (const float*)d_in[5];
    const float* wo = (const float*)d_in[6];
    float* out = (float*)d_out;

    char* ws = (char*)d_ws;
    size_t off = 0;
    auto carve = [&](size_t bytes) -> char* {
        char* p = ws + off;
        off += (bytes + 255) & ~(size_t)255;
        return p;
    };
    u16* xb    = (u16*)carve((size_t)M4 * EE * 2);
    u16* wqkvt = (u16*)carve((size_t)NQKV * EE * 2);
    u16* wot   = (u16*)carve((size_t)EE * EE * 2);
    u16* qb    = (u16*)carve((size_t)BH * TT * DD * 2);
    u16* kb    = (u16*)carve((size_t)BH * TT * DD * 2);
    u16* vb    = (u16*)carve((size_t)BH * TT * DD * 2);
    float* rbuf = (float*)carve((size_t)BH * TT * 4);
    float* rmx  = (float*)carve((size_t)BH * 4);
    float* outr = (float*)carve((size_t)BH * TT * DD * 4);
    float* outc = (float*)carve((size_t)BH * TT * DD * 4);
    u16* comb  = (u16*)carve((size_t)M4 * EE * 2);

    cast_x_kernel<<<(M4 * EE + 255) / 256, 256, 0, stream>>>(x, xb, M4 * EE);
    transpose_cast_kernel<<<(EE * EE + 255) / 256, 256, 0, stream>>>(wq, wqkvt, EE, EE);
    transpose_cast_kernel<<<(EE * EE + 255) / 256, 256, 0, stream>>>(wk, wqkvt + (size_t)EE * EE, EE, EE);
    transpose_cast_kernel<<<(EE * EE + 255) / 256, 256, 0, stream>>>(wv, wqkvt + 2 * (size_t)EE * EE, EE, EE);
    transpose_cast_kernel<<<(EE * EE + 255) / 256, 256, 0, stream>>>(wo, wot, EE, EE);

    dim3 gq(M4 / 64, NQKV / 64);
    gemm_qkv_kernel<<<gq, 256, 0, stream>>>(xb, wqkvt, qb, kb, vb);

    r_kernel<<<BB * HH * 8, 256, 0, stream>>>(x, wr, rbuf);
    rmax_kernel<<<BH, 256, 0, stream>>>(rbuf, rmx);
    scan_kernel<<<BH, 64, 0, stream>>>(rbuf, rmx, vb, outr);

    dim3 gf(TT / 16, BH);
    flash_kernel<<<gf, 64, 0, stream>>>(qb, kb, vb, outc);

    combine_kernel<<<(M4 * EE + 255) / 256, 256, 0, stream>>>(outr, outc, alpha, comb);

    dim3 go(M4 / 64, EE / 64);
    gemm_out_kernel<<<go, 256, 0, stream>>>(comb, wot, out);
}

// Round 2
// 394.551 us; speedup vs baseline: 1.8974x; 1.8974x over previous
//
#include <hip/hip_runtime.h>
#include <math.h>

typedef __bf16 bf16x8 __attribute__((ext_vector_type(8)));
typedef float f32x4 __attribute__((ext_vector_type(4)));
typedef unsigned short u16;

#define BB 2
#define TT 2048
#define EE 768
#define HH 12
#define DD 64
#define BH (BB*HH)      /* 24 */
#define M4 (BB*TT)      /* 4096 */
#define NQKV (3*EE)     /* 2304 */
#define SCH 16          /* scan chunks (128 t each) */

__device__ __forceinline__ u16 f2bf(float f) {
    union { float f; unsigned u; } v; v.f = f;
    unsigned r = v.u + 0x7FFFu + ((v.u >> 16) & 1u);
    return (u16)(r >> 16);
}
__device__ __forceinline__ float bf2f(u16 u) {
    union { unsigned u; float f; } v; v.u = ((unsigned)u) << 16;
    return v.f;
}

// ---------------------------------------------------------------- casts
__global__ void cast_x_kernel(const float* __restrict__ x, u16* __restrict__ xb, int n) {
    int i = blockIdx.x * blockDim.x + threadIdx.x;
    if (i < n) xb[i] = f2bf(x[i]);
}

// dst[n][k] = bf16(src[k][n]) — LDS-tiled, coalesced both sides
__global__ __launch_bounds__(256) void transpose_cast_kernel(
    const float* __restrict__ src, u16* __restrict__ dst, int N, int K) {
    __shared__ float tile[32][33];
    int n0 = blockIdx.x * 32, k0 = blockIdx.y * 32;
    int tx = threadIdx.x & 31, ty = threadIdx.x >> 5;
#pragma unroll
    for (int i = 0; i < 4; i++)
        tile[ty + 8 * i][tx] = src[(size_t)(k0 + ty + 8 * i) * N + n0 + tx];
    __syncthreads();
#pragma unroll
    for (int i = 0; i < 4; i++)
        dst[(size_t)(n0 + ty + 8 * i) * K + k0 + tx] = f2bf(tile[tx][ty + 8 * i]);
}

// xt[b][e][t] = x[b][t][e]  (fp32, LDS-tiled)
__global__ __launch_bounds__(256) void transpose_x_kernel(
    const float* __restrict__ x, float* __restrict__ xt) {
    __shared__ float tile[32][33];
    int t0 = blockIdx.x * 32, e0 = blockIdx.y * 32, b = blockIdx.z;
    int tx = threadIdx.x & 31, ty = threadIdx.x >> 5;
#pragma unroll
    for (int i = 0; i < 4; i++)
        tile[ty + 8 * i][tx] = x[((size_t)b * TT + t0 + ty + 8 * i) * EE + e0 + tx];
    __syncthreads();
#pragma unroll
    for (int i = 0; i < 4; i++)
        xt[((size_t)b * EE + e0 + ty + 8 * i) * TT + t0 + tx] = tile[tx][ty + 8 * i];
}

// vt[bh][d][j] = vb[bh][j][d]  (bf16, LDS-tiled 64x64)
__global__ __launch_bounds__(256) void transpose_v_kernel(
    const u16* __restrict__ vb, u16* __restrict__ vt) {
    __shared__ u16 tile[64][66];
    int j0 = blockIdx.x * 64, bh = blockIdx.y;
    int tid = threadIdx.x;
#pragma unroll
    for (int i = 0; i < 16; i++) {
        int idx = i * 256 + tid;
        int j = idx >> 6, d = idx & 63;
        tile[j][d] = vb[((size_t)bh * TT + j0 + j) * DD + d];
    }
    __syncthreads();
#pragma unroll
    for (int i = 0; i < 16; i++) {
        int idx = i * 256 + tid;
        int d = idx >> 6, j = idx & 63;
        vt[((size_t)bh * DD + d) * TT + j0 + j] = tile[j][d];
    }
}

// ---------------------------------------------------------------- QKV GEMM
// A: xb (4096 x 768) bf16. Bt: wqkv_t (2304 x 768) bf16 (NxK). q pre-scaled by 1/8.
__global__ __launch_bounds__(256) void gemm_qkv_kernel(
    const u16* __restrict__ A, const u16* __restrict__ Bt,
    u16* __restrict__ qb, u16* __restrict__ kb, u16* __restrict__ vb)
{
    const int K = EE;
    int w = threadIdx.x >> 6, l = threadIdx.x & 63;
    int lo = l & 15, hi = l >> 4;
    int m0 = blockIdx.x * 64 + (w >> 1) * 32;
    int n0 = blockIdx.y * 64 + (w & 1) * 32;
    f32x4 c[2][2] = {};
    for (int k0 = 0; k0 < K; k0 += 32) {
        bf16x8 a0 = *(const bf16x8*)(A + (size_t)(m0 + lo) * K + k0 + hi * 8);
        bf16x8 a1 = *(const bf16x8*)(A + (size_t)(m0 + 16 + lo) * K + k0 + hi * 8);
        bf16x8 b0 = *(const bf16x8*)(Bt + (size_t)(n0 + lo) * K + k0 + hi * 8);
        bf16x8 b1 = *(const bf16x8*)(Bt + (size_t)(n0 + 16 + lo) * K + k0 + hi * 8);
        c[0][0] = __builtin_amdgcn_mfma_f32_16x16x32_bf16(a0, b0, c[0][0], 0, 0, 0);
        c[0][1] = __builtin_amdgcn_mfma_f32_16x16x32_bf16(a0, b1, c[0][1], 0, 0, 0);
        c[1][0] = __builtin_amdgcn_mfma_f32_16x16x32_bf16(a1, b0, c[1][0], 0, 0, 0);
        c[1][1] = __builtin_amdgcn_mfma_f32_16x16x32_bf16(a1, b1, c[1][1], 0, 0, 0);
    }
#pragma unroll
    for (int i = 0; i < 2; i++)
#pragma unroll
        for (int j = 0; j < 2; j++)
#pragma unroll
            for (int r = 0; r < 4; r++) {
                int m = m0 + 16 * i + hi * 4 + r;
                int n = n0 + 16 * j + lo;
                int sel = n / EE, rem = n - sel * EE;
                int h = rem >> 6, d = rem & 63;
                int b = m >> 11, t = m & 2047;
                size_t idx = ((size_t)(b * HH + h) * TT + t) * DD + d;
                float val = c[i][j][r];
                if (sel == 0) val *= 0.125f;  // fold QK^T scale into q
                u16* dst = (sel == 0) ? qb : (sel == 1) ? kb : vb;
                dst[idx] = f2bf(val);
            }
}

// ---------------------------------------------------------------- r = scale * x . wr
// partials: rp[ech][b][h][t], e-chunks of 16; all streams coalesced along t
__global__ __launch_bounds__(256) void r_partial_kernel(
    const float* __restrict__ xt, const float* __restrict__ wr, float* __restrict__ rp) {
    int ech = blockIdx.x;           // 0..47
    int tch = blockIdx.y;           // 0..1
    int hg = blockIdx.z;            // 0..1
    int e0 = ech * 16, h0 = hg * 6;
    int tv = tch * 256 + threadIdx.x;   // float4 index into 512-wide rows
    const f32x4* xt4 = (const f32x4*)xt;
    const f32x4* wr4 = (const f32x4*)wr;
    f32x4 acc[2][6] = {};
#pragma unroll 4
    for (int e = 0; e < 16; e++) {
        f32x4 x0 = xt4[(size_t)(e0 + e) * 512 + tv];
        f32x4 x1 = xt4[(size_t)(EE + e0 + e) * 512 + tv];
#pragma unroll
        for (int hh = 0; hh < 6; hh++) {
            f32x4 w = wr4[((size_t)(h0 + hh) * EE + e0 + e) * 512 + tv];
            acc[0][hh] += w * x0;
            acc[1][hh] += w * x1;
        }
    }
    f32x4* rp4 = (f32x4*)rp;
#pragma unroll
    for (int b = 0; b < 2; b++)
#pragma unroll
        for (int hh = 0; hh < 6; hh++)
            rp4[((size_t)ech * 24 + b * 12 + h0 + hh) * 512 + tv] = acc[b][hh];
}

// reduce 48 partials -> r[bh][t] (scaled), fused per-bh max -> rmax
__global__ __launch_bounds__(256) void r_reduce_kernel(
    const float* __restrict__ rp, float* __restrict__ r, float* __restrict__ rmax) {
    int bh = blockIdx.x, tid = threadIdx.x;
    const f32x4* rp4 = (const f32x4*)rp;
    f32x4* r4 = (f32x4*)r;
    float mloc = -INFINITY;
#pragma unroll
    for (int seg = 0; seg < 2; seg++) {
        int tv = seg * 256 + tid;
        f32x4 s = {};
#pragma unroll 8
        for (int ech = 0; ech < 48; ech++)
            s += rp4[((size_t)ech * 24 + bh) * 512 + tv];
        s *= 0.125f;
        r4[(size_t)bh * 512 + tv] = s;
        mloc = fmaxf(mloc, fmaxf(fmaxf(s[0], s[1]), fmaxf(s[2], s[3])));
    }
    __shared__ float sm[256];
    sm[tid] = mloc; __syncthreads();
    for (int s = 128; s > 0; s >>= 1) {
        if (tid < s) sm[tid] = fmaxf(sm[tid], sm[tid + s]);
        __syncthreads();
    }
    if (tid == 0) rmax[bh] = sm[0];
}

// ---------------------------------------------------------------- rr attention = chunked prefix scan
// S1: per-chunk sums
__global__ __launch_bounds__(64) void scan_part_kernel(
    const float* __restrict__ r, const float* __restrict__ rmax,
    const u16* __restrict__ vb, float* __restrict__ Sv, float* __restrict__ Sl) {
    int c = blockIdx.x, bh = blockIdx.y, d = threadIdx.x;
    float mx = rmax[bh];
    const float* rp = r + (size_t)bh * TT + c * 128;
    const u16* vp = vb + ((size_t)bh * TT + c * 128) * DD + d;
    float accv = 0.f, accl = 0.f;
#pragma unroll 4
    for (int j = 0; j < 128; j++) {
        float w = __expf(rp[j] - mx);
        accv += w * bf2f(vp[(size_t)j * DD]);
        accl += w;
    }
    Sv[((size_t)bh * SCH + c) * DD + d] = accv;
    if (d == 0) Sl[bh * SCH + c] = accl;
}

// S3: chunk prefix + in-chunk scan + divide
__global__ __launch_bounds__(64) void scan_out_kernel(
    const float* __restrict__ r, const float* __restrict__ rmax,
    const u16* __restrict__ vb, const float* __restrict__ Sv, const float* __restrict__ Sl,
    float* __restrict__ outr) {
    int c = blockIdx.x, bh = blockIdx.y, d = threadIdx.x;
    float mx = rmax[bh];
    float acc = 0.f, accl = 0.f;
    for (int cp = 0; cp < c; cp++) {
        acc += Sv[((size_t)bh * SCH + cp) * DD + d];
        accl += Sl[bh * SCH + cp];
    }
    const float* rp = r + (size_t)bh * TT + c * 128;
    const u16* vp = vb + ((size_t)bh * TT + c * 128) * DD + d;
    float* op = outr + ((size_t)bh * TT + c * 128) * DD + d;
#pragma unroll 2
    for (int j = 0; j < 128; j++) {
        float w = __expf(rp[j] - mx);
        acc += w * bf2f(vp[(size_t)j * DD]);
        accl += w;
        op[(size_t)j * DD] = acc * __builtin_amdgcn_rcpf(accl);
    }
}

// ---------------------------------------------------------------- content flash attention
// 1 wave / 16 q rows; 64-key chunks; V transposed (vt[d][j]) for vector B-frag loads
__global__ __launch_bounds__(64) void flash_kernel(
    const u16* __restrict__ qb, const u16* __restrict__ kb,
    const u16* __restrict__ vt, float* __restrict__ outc) {
    __shared__ __align__(16) u16 p_lds[16][72];
    int bh = blockIdx.y;
    int q0 = blockIdx.x * 16;
    int l = threadIdx.x;
    int lo = l & 15, hi = l >> 4;
    const u16* qbase = qb + (size_t)bh * TT * DD;
    const u16* kbase = kb + (size_t)bh * TT * DD;
    const u16* vtb = vt + (size_t)bh * DD * TT;

    bf16x8 aQ0 = *(const bf16x8*)(qbase + (size_t)(q0 + lo) * DD + hi * 8);
    bf16x8 aQ1 = *(const bf16x8*)(qbase + (size_t)(q0 + lo) * DD + 32 + hi * 8);

    float m[4], ls[4];
    f32x4 o[4] = {};
#pragma unroll
    for (int r = 0; r < 4; r++) { m[r] = -INFINITY; ls[r] = 0.f; }

    for (int j0 = 0; j0 < q0 + 16; j0 += 64) {
        f32x4 s[4] = {};
#pragma unroll
        for (int jj = 0; jj < 4; jj++) {
            const u16* kp = kbase + (size_t)(j0 + 16 * jj + lo) * DD + hi * 8;
            bf16x8 bk0 = *(const bf16x8*)(kp);
            bf16x8 bk1 = *(const bf16x8*)(kp + 32);
            s[jj] = __builtin_amdgcn_mfma_f32_16x16x32_bf16(aQ0, bk0, s[jj], 0, 0, 0);
            s[jj] = __builtin_amdgcn_mfma_f32_16x16x32_bf16(aQ1, bk1, s[jj], 0, 0, 0);
        }
        float p[4][4], tm[4], rs[4];
#pragma unroll
        for (int r = 0; r < 4; r++) {
            int q = q0 + hi * 4 + r;
#pragma unroll
            for (int jj = 0; jj < 4; jj++)
                if (j0 + 16 * jj + lo > q) s[jj][r] = -INFINITY;
            tm[r] = fmaxf(fmaxf(s[0][r], s[1][r]), fmaxf(s[2][r], s[3][r]));
        }
#pragma unroll
        for (int msk = 1; msk < 16; msk <<= 1)
#pragma unroll
            for (int r = 0; r < 4; r++) tm[r] = fmaxf(tm[r], __shfl_xor(tm[r], msk, 64));
#pragma unroll
        for (int r = 0; r < 4; r++) {
            float mn = fmaxf(m[r], tm[r]);
            float f = __expf(m[r] - mn);
            m[r] = mn;
            rs[r] = 0.f;
#pragma unroll
            for (int jj = 0; jj < 4; jj++) {
                p[jj][r] = __expf(s[jj][r] - mn);
                rs[r] += p[jj][r];
            }
            ls[r] *= f;
#pragma unroll
            for (int jd = 0; jd < 4; jd++) o[jd][r] *= f;
        }
#pragma unroll
        for (int msk = 1; msk < 16; msk <<= 1)
#pragma unroll
            for (int r = 0; r < 4; r++) rs[r] += __shfl_xor(rs[r], msk, 64);
#pragma unroll
        for (int r = 0; r < 4; r++) ls[r] += rs[r];

#pragma unroll
        for (int r = 0; r < 4; r++)
#pragma unroll
            for (int jj = 0; jj < 4; jj++)
                p_lds[hi * 4 + r][jj * 16 + lo] = f2bf(p[jj][r]);
        asm volatile("" ::: "memory");
        bf16x8 aP0 = *(const bf16x8*)(&p_lds[lo][hi * 8]);
        bf16x8 aP1 = *(const bf16x8*)(&p_lds[lo][32 + hi * 8]);
        asm volatile("" ::: "memory");
#pragma unroll
        for (int jd = 0; jd < 4; jd++) {
            const u16* vp = vtb + (size_t)(jd * 16 + lo) * TT + j0 + hi * 8;
            bf16x8 bV0 = *(const bf16x8*)(vp);
            bf16x8 bV1 = *(const bf16x8*)(vp + 32);
            o[jd] = __builtin_amdgcn_mfma_f32_16x16x32_bf16(aP0, bV0, o[jd], 0, 0, 0);
            o[jd] = __builtin_amdgcn_mfma_f32_16x16x32_bf16(aP1, bV1, o[jd], 0, 0, 0);
        }
    }
    float* ob = outc + (size_t)bh * TT * DD;
#pragma unroll
    for (int r = 0; r < 4; r++) {
        float inv = 1.f / ls[r];
#pragma unroll
        for (int jd = 0; jd < 4; jd++)
            ob[(size_t)(q0 + hi * 4 + r) * DD + jd * 16 + lo] = o[jd][r] * inv;
    }
}

// ---------------------------------------------------------------- combine
__global__ void combine_kernel(const float* __restrict__ outr, const float* __restrict__ outc,
                               const float* __restrict__ alpha, u16* __restrict__ comb) {
    int i = blockIdx.x * blockDim.x + threadIdx.x;
    if (i >= M4 * EE) return;
    int bt = i / EE, c = i - bt * EE;
    int h = c >> 6, d = c & 63;
    int b = bt >> 11, t = bt & 2047;
    size_t src = ((size_t)(b * HH + h) * TT + t) * DD + d;
    float a = 1.f / (1.f + __expf(-alpha[h]));
    comb[i] = f2bf(a * outr[src] + (1.f - a) * outc[src]);
}

// ---------------------------------------------------------------- output GEMM
__global__ __launch_bounds__(256) void gemm_out_kernel(const u16* __restrict__ A,
                                                       const u16* __restrict__ Bt,
                                                       float* __restrict__ C) {
    const int K = EE, N = EE;
    int w = threadIdx.x >> 6, l = threadIdx.x & 63;
    int lo = l & 15, hi = l >> 4;
    int m0 = blockIdx.x * 64 + (w >> 1) * 32;
    int n0 = blockIdx.y * 64 + (w & 1) * 32;
    f32x4 c[2][2] = {};
    for (int k0 = 0; k0 < K; k0 += 32) {
        bf16x8 a0 = *(const bf16x8*)(A + (size_t)(m0 + lo) * K + k0 + hi * 8);
        bf16x8 a1 = *(const bf16x8*)(A + (size_t)(m0 + 16 + lo) * K + k0 + hi * 8);
        bf16x8 b0 = *(const bf16x8*)(Bt + (size_t)(n0 + lo) * K + k0 + hi * 8);
        bf16x8 b1 = *(const bf16x8*)(Bt + (size_t)(n0 + 16 + lo) * K + k0 + hi * 8);
        c[0][0] = __builtin_amdgcn_mfma_f32_16x16x32_bf16(a0, b0, c[0][0], 0, 0, 0);
        c[0][1] = __builtin_amdgcn_mfma_f32_16x16x32_bf16(a0, b1, c[0][1], 0, 0, 0);
        c[1][0] = __builtin_amdgcn_mfma_f32_16x16x32_bf16(a1, b0, c[1][0], 0, 0, 0);
        c[1][1] = __builtin_amdgcn_mfma_f32_16x16x32_bf16(a1, b1, c[1][1], 0, 0, 0);
    }
#pragma unroll
    for (int i = 0; i < 2; i++)
#pragma unroll
        for (int j = 0; j < 2; j++)
#pragma unroll
            for (int r = 0; r < 4; r++)
                C[(size_t)(m0 + 16 * i + hi * 4 + r) * N + n0 + 16 * j + lo] = c[i][j][r];
}

// ----------------------------------------------------------------
extern "C" void kernel_launch(void* const* d_in, const int* in_sizes, int n_in,
                              void* d_out, int out_size, void* d_ws, size_t ws_size,
                              hipStream_t stream) {
    const float* x = (const float*)d_in[0];
    const float* wq = (const float*)d_in[1];
    const float* wk = (const float*)d_in[2];
    const float* wv = (const float*)d_in[3];
    const float* wr = (const float*)d_in[4];
    const float* alpha = (const float*)d_in[5];
    const float* wo = (const float*)d_in[6];
    float* out = (float*)d_out;

    char* ws = (char*)d_ws;
    size_t off = 0;
    auto carve = [&](size_t bytes) -> char* {
        char* p = ws + off;
        off += (bytes + 255) & ~(size_t)255;
        return p;
    };
    u16* xb    = (u16*)carve((size_t)M4 * EE * 2);
    u16* wqkvt = (u16*)carve((size_t)NQKV * EE * 2);
    u16* wot   = (u16*)carve((size_t)EE * EE * 2);
    u16* qb    = (u16*)carve((size_t)BH * TT * DD * 2);
    u16* kb    = (u16*)carve((size_t)BH * TT * DD * 2);
    u16* vb    = (u16*)carve((size_t)BH * TT * DD * 2);
    u16* vt    = (u16*)carve((size_t)BH * TT * DD * 2);
    float* xt   = (float*)carve((size_t)BB * EE * TT * 4);
    float* rpbuf= (float*)carve((size_t)48 * BH * TT * 4);
    float* rbuf = (float*)carve((size_t)BH * TT * 4);
    float* rmx  = (float*)carve((size_t)BH * 4);
    float* Sv   = (float*)carve((size_t)BH * SCH * DD * 4);
    float* Sl   = (float*)carve((size_t)BH * SCH * 4);
    float* outr = (float*)carve((size_t)BH * TT * DD * 4);
    float* outc = (float*)carve((size_t)BH * TT * DD * 4);
    u16* comb  = (u16*)carve((size_t)M4 * EE * 2);

    cast_x_kernel<<<(M4 * EE + 255) / 256, 256, 0, stream>>>(x, xb, M4 * EE);
    {
        dim3 g(EE / 32, EE / 32);
        transpose_cast_kernel<<<g, 256, 0, stream>>>(wq, wqkvt, EE, EE);
        transpose_cast_kernel<<<g, 256, 0, stream>>>(wk, wqkvt + (size_t)EE * EE, EE, EE);
        transpose_cast_kernel<<<g, 256, 0, stream>>>(wv, wqkvt + 2 * (size_t)EE * EE, EE, EE);
        transpose_cast_kernel<<<g, 256, 0, stream>>>(wo, wot, EE, EE);
    }
    transpose_x_kernel<<<dim3(TT / 32, EE / 32, BB), 256, 0, stream>>>(x, xt);

    dim3 gq(M4 / 64, NQKV / 64);
    gemm_qkv_kernel<<<gq, 256, 0, stream>>>(xb, wqkvt, qb, kb, vb);
    transpose_v_kernel<<<dim3(TT / 64, BH), 256, 0, stream>>>(vb, vt);

    r_partial_kernel<<<dim3(48, 2, 2), 256, 0, stream>>>(xt, wr, rpbuf);
    r_reduce_kernel<<<BH, 256, 0, stream>>>(rpbuf, rbuf, rmx);

    scan_part_kernel<<<dim3(SCH, BH), 64, 0, stream>>>(rbuf, rmx, vb, Sv, Sl);
    scan_out_kernel<<<dim3(SCH, BH), 64, 0, stream>>>(rbuf, rmx, vb, Sv, Sl, outr);

    dim3 gf(TT / 16, BH);
    flash_kernel<<<gf, 64, 0, stream>>>(qb, kb, vt, outc);

    combine_kernel<<<(M4 * EE + 255) / 256, 256, 0, stream>>>(outr, outc, alpha, comb);

    dim3 go(M4 / 64, EE / 64);
    gemm_out_kernel<<<go, 256, 0, stream>>>(comb, wot, out);
}

// Round 3
// 336.117 us; speedup vs baseline: 2.2272x; 1.1738x over previous
//
#include <hip/hip_runtime.h>
#include <math.h>

typedef __bf16 bf16x8 __attribute__((ext_vector_type(8)));
typedef float f32x4 __attribute__((ext_vector_type(4)));
typedef unsigned short u16;

#define BB 2
#define TT 2048
#define EE 768
#define HH 12
#define DD 64
#define BH (BB*HH)      /* 24 */
#define M4 (BB*TT)      /* 4096 */
#define NQKV (3*EE)     /* 2304 */
#define SCH 16          /* scan chunks (128 t each) */
#define QBLK 128
#define KVB 64

__device__ __forceinline__ u16 f2bf(float f) {
    union { float f; unsigned u; } v; v.f = f;
    unsigned r = v.u + 0x7FFFu + ((v.u >> 16) & 1u);
    return (u16)(r >> 16);
}
__device__ __forceinline__ float bf2f(u16 u) {
    union { unsigned u; float f; } v; v.u = ((unsigned)u) << 16;
    return v.f;
}

// ---------------------------------------------------------------- casts
__global__ void cast_x_kernel(const float* __restrict__ x, u16* __restrict__ xb, int n4) {
    int i = blockIdx.x * blockDim.x + threadIdx.x;
    if (i >= n4) return;
    f32x4 v = ((const f32x4*)x)[i];
    u16* o = xb + i * 4;
    o[0] = f2bf(v[0]); o[1] = f2bf(v[1]); o[2] = f2bf(v[2]); o[3] = f2bf(v[3]);
}

// dst[n][k] = bf16(src[k][n]) — LDS-tiled, coalesced both sides
__global__ __launch_bounds__(256) void transpose_cast_kernel(
    const float* __restrict__ src, u16* __restrict__ dst, int N, int K) {
    __shared__ float tile[32][33];
    int n0 = blockIdx.x * 32, k0 = blockIdx.y * 32;
    int tx = threadIdx.x & 31, ty = threadIdx.x >> 5;
#pragma unroll
    for (int i = 0; i < 4; i++)
        tile[ty + 8 * i][tx] = src[(size_t)(k0 + ty + 8 * i) * N + n0 + tx];
    __syncthreads();
#pragma unroll
    for (int i = 0; i < 4; i++)
        dst[(size_t)(n0 + ty + 8 * i) * K + k0 + tx] = f2bf(tile[tx][ty + 8 * i]);
}

// xt[b][e][t] = x[b][t][e]  (fp32, LDS-tiled)
__global__ __launch_bounds__(256) void transpose_x_kernel(
    const float* __restrict__ x, float* __restrict__ xt) {
    __shared__ float tile[32][33];
    int t0 = blockIdx.x * 32, e0 = blockIdx.y * 32, b = blockIdx.z;
    int tx = threadIdx.x & 31, ty = threadIdx.x >> 5;
#pragma unroll
    for (int i = 0; i < 4; i++)
        tile[ty + 8 * i][tx] = x[((size_t)b * TT + t0 + ty + 8 * i) * EE + e0 + tx];
    __syncthreads();
#pragma unroll
    for (int i = 0; i < 4; i++)
        xt[((size_t)b * EE + e0 + ty + 8 * i) * TT + t0 + tx] = tile[tx][ty + 8 * i];
}

// vt[bh][d][j] = vb[bh][j][d]  (bf16, LDS-tiled 64x64)
__global__ __launch_bounds__(256) void transpose_v_kernel(
    const u16* __restrict__ vb, u16* __restrict__ vt) {
    __shared__ u16 tile[64][66];
    int j0 = blockIdx.x * 64, bh = blockIdx.y;
    int tid = threadIdx.x;
#pragma unroll
    for (int i = 0; i < 16; i++) {
        int idx = i * 256 + tid;
        int j = idx >> 6, d = idx & 63;
        tile[j][d] = vb[((size_t)bh * TT + j0 + j) * DD + d];
    }
    __syncthreads();
#pragma unroll
    for (int i = 0; i < 16; i++) {
        int idx = i * 256 + tid;
        int d = idx >> 6, j = idx & 63;
        vt[((size_t)bh * DD + d) * TT + j0 + j] = tile[j][d];
    }
}

// ---------------------------------------------------------------- QKV GEMM
// A: xb (4096 x 768) bf16. Bt: wqkv_t (2304 x 768) bf16 (NxK). q pre-scaled by 1/8.
__global__ __launch_bounds__(256) void gemm_qkv_kernel(
    const u16* __restrict__ A, const u16* __restrict__ Bt,
    u16* __restrict__ qb, u16* __restrict__ kb, u16* __restrict__ vb)
{
    const int K = EE;
    int w = threadIdx.x >> 6, l = threadIdx.x & 63;
    int lo = l & 15, hi = l >> 4;
    int m0 = blockIdx.x * 64 + (w >> 1) * 32;
    int n0 = blockIdx.y * 64 + (w & 1) * 32;
    f32x4 c[2][2] = {};
    for (int k0 = 0; k0 < K; k0 += 32) {
        bf16x8 a0 = *(const bf16x8*)(A + (size_t)(m0 + lo) * K + k0 + hi * 8);
        bf16x8 a1 = *(const bf16x8*)(A + (size_t)(m0 + 16 + lo) * K + k0 + hi * 8);
        bf16x8 b0 = *(const bf16x8*)(Bt + (size_t)(n0 + lo) * K + k0 + hi * 8);
        bf16x8 b1 = *(const bf16x8*)(Bt + (size_t)(n0 + 16 + lo) * K + k0 + hi * 8);
        c[0][0] = __builtin_amdgcn_mfma_f32_16x16x32_bf16(a0, b0, c[0][0], 0, 0, 0);
        c[0][1] = __builtin_amdgcn_mfma_f32_16x16x32_bf16(a0, b1, c[0][1], 0, 0, 0);
        c[1][0] = __builtin_amdgcn_mfma_f32_16x16x32_bf16(a1, b0, c[1][0], 0, 0, 0);
        c[1][1] = __builtin_amdgcn_mfma_f32_16x16x32_bf16(a1, b1, c[1][1], 0, 0, 0);
    }
#pragma unroll
    for (int i = 0; i < 2; i++)
#pragma unroll
        for (int j = 0; j < 2; j++)
#pragma unroll
            for (int r = 0; r < 4; r++) {
                int m = m0 + 16 * i + hi * 4 + r;
                int n = n0 + 16 * j + lo;
                int sel = n / EE, rem = n - sel * EE;
                int h = rem >> 6, d = rem & 63;
                int b = m >> 11, t = m & 2047;
                size_t idx = ((size_t)(b * HH + h) * TT + t) * DD + d;
                float val = c[i][j][r];
                if (sel == 0) val *= 0.125f;  // fold QK^T scale into q
                u16* dst = (sel == 0) ? qb : (sel == 1) ? kb : vb;
                dst[idx] = f2bf(val);
            }
}

// ---------------------------------------------------------------- r = scale * x . wr
__global__ __launch_bounds__(256) void r_partial_kernel(
    const float* __restrict__ xt, const float* __restrict__ wr, float* __restrict__ rp) {
    int ech = blockIdx.x;           // 0..47
    int tch = blockIdx.y;           // 0..1
    int hg = blockIdx.z;            // 0..1
    int e0 = ech * 16, h0 = hg * 6;
    int tv = tch * 256 + threadIdx.x;   // float4 index into 512-wide rows
    const f32x4* xt4 = (const f32x4*)xt;
    const f32x4* wr4 = (const f32x4*)wr;
    f32x4 acc[2][6] = {};
#pragma unroll 4
    for (int e = 0; e < 16; e++) {
        f32x4 x0 = xt4[(size_t)(e0 + e) * 512 + tv];
        f32x4 x1 = xt4[(size_t)(EE + e0 + e) * 512 + tv];
#pragma unroll
        for (int hh = 0; hh < 6; hh++) {
            f32x4 w = wr4[((size_t)(h0 + hh) * EE + e0 + e) * 512 + tv];
            acc[0][hh] += w * x0;
            acc[1][hh] += w * x1;
        }
    }
    f32x4* rp4 = (f32x4*)rp;
#pragma unroll
    for (int b = 0; b < 2; b++)
#pragma unroll
        for (int hh = 0; hh < 6; hh++)
            rp4[((size_t)ech * 24 + b * 12 + h0 + hh) * 512 + tv] = acc[b][hh];
}

__global__ __launch_bounds__(256) void r_reduce_kernel(
    const float* __restrict__ rp, float* __restrict__ r, float* __restrict__ rmax) {
    int bh = blockIdx.x, tid = threadIdx.x;
    const f32x4* rp4 = (const f32x4*)rp;
    f32x4* r4 = (f32x4*)r;
    float mloc = -INFINITY;
#pragma unroll
    for (int seg = 0; seg < 2; seg++) {
        int tv = seg * 256 + tid;
        f32x4 s = {};
#pragma unroll 8
        for (int ech = 0; ech < 48; ech++)
            s += rp4[((size_t)ech * 24 + bh) * 512 + tv];
        s *= 0.125f;
        r4[(size_t)bh * 512 + tv] = s;
        mloc = fmaxf(mloc, fmaxf(fmaxf(s[0], s[1]), fmaxf(s[2], s[3])));
    }
    __shared__ float sm[256];
    sm[tid] = mloc; __syncthreads();
    for (int s = 128; s > 0; s >>= 1) {
        if (tid < s) sm[tid] = fmaxf(sm[tid], sm[tid + s]);
        __syncthreads();
    }
    if (tid == 0) rmax[bh] = sm[0];
}

// ---------------------------------------------------------------- rr attention = chunked prefix scan
__global__ __launch_bounds__(64) void scan_part_kernel(
    const float* __restrict__ r, const float* __restrict__ rmax,
    const u16* __restrict__ vb, float* __restrict__ Sv, float* __restrict__ Sl) {
    int c = blockIdx.x, bh = blockIdx.y, d = threadIdx.x;
    float mx = rmax[bh];
    const float* rp = r + (size_t)bh * TT + c * 128;
    const u16* vp = vb + ((size_t)bh * TT + c * 128) * DD + d;
    float accv = 0.f, accl = 0.f;
#pragma unroll 4
    for (int j = 0; j < 128; j++) {
        float w = __expf(rp[j] - mx);
        accv += w * bf2f(vp[(size_t)j * DD]);
        accl += w;
    }
    Sv[((size_t)bh * SCH + c) * DD + d] = accv;
    if (d == 0) Sl[bh * SCH + c] = accl;
}

__global__ __launch_bounds__(64) void scan_out_kernel(
    const float* __restrict__ r, const float* __restrict__ rmax,
    const u16* __restrict__ vb, const float* __restrict__ Sv, const float* __restrict__ Sl,
    u16* __restrict__ outr) {
    int c = blockIdx.x, bh = blockIdx.y, d = threadIdx.x;
    float mx = rmax[bh];
    float acc = 0.f, accl = 0.f;
    for (int cp = 0; cp < c; cp++) {
        acc += Sv[((size_t)bh * SCH + cp) * DD + d];
        accl += Sl[bh * SCH + cp];
    }
    const float* rp = r + (size_t)bh * TT + c * 128;
    const u16* vp = vb + ((size_t)bh * TT + c * 128) * DD + d;
    u16* op = outr + ((size_t)bh * TT + c * 128) * DD + d;
#pragma unroll 2
    for (int j = 0; j < 128; j++) {
        float w = __expf(rp[j] - mx);
        acc += w * bf2f(vp[(size_t)j * DD]);
        accl += w;
        op[(size_t)j * DD] = f2bf(acc * __builtin_amdgcn_rcpf(accl));
    }
}

// ---------------------------------------------------------------- content flash attention
// 4 waves x 32 q rows (QBLK=128); K and V^T staged in LDS per 64-key chunk
__global__ __launch_bounds__(256) void flash_kernel(
    const u16* __restrict__ qb, const u16* __restrict__ kb,
    const u16* __restrict__ vt, u16* __restrict__ outc) {
    __shared__ __align__(16) u16 Kt[KVB][72];
    __shared__ __align__(16) u16 Vt[KVB][72];
    __shared__ __align__(16) u16 Pt[4][32][72];
    int bh = blockIdx.y;
    int q0 = ((int)gridDim.x - 1 - (int)blockIdx.x) * QBLK;  // long blocks first
    int tid = threadIdx.x;
    int w = tid >> 6, l = tid & 63;
    int lo = l & 15, hi = l >> 4;
    int qw0 = q0 + w * 32;
    const u16* qbase = qb + (size_t)bh * TT * DD;
    const u16* kbase = kb + (size_t)bh * TT * DD;
    const u16* vtb = vt + (size_t)bh * DD * TT;

    bf16x8 aQ[2][2];
#pragma unroll
    for (int i = 0; i < 2; i++)
#pragma unroll
        for (int h = 0; h < 2; h++)
            aQ[i][h] = *(const bf16x8*)(qbase + (size_t)(qw0 + i * 16 + lo) * DD + h * 32 + hi * 8);

    float m[2][4], ls[2][4];
    f32x4 o[2][4] = {};
#pragma unroll
    for (int i = 0; i < 2; i++)
#pragma unroll
        for (int r = 0; r < 4; r++) { m[i][r] = -INFINITY; ls[i][r] = 0.f; }

    int srow = tid >> 3, sc8 = tid & 7;   // staging coords
    int jend = q0 + QBLK;
    for (int j0 = 0; j0 < jend; j0 += KVB) {
        __syncthreads();
        *(bf16x8*)(&Kt[srow][sc8 * 8])      = *(const bf16x8*)(kbase + (size_t)(j0 + srow) * DD + sc8 * 8);
        *(bf16x8*)(&Kt[srow + 32][sc8 * 8]) = *(const bf16x8*)(kbase + (size_t)(j0 + srow + 32) * DD + sc8 * 8);
        *(bf16x8*)(&Vt[srow][sc8 * 8])      = *(const bf16x8*)(vtb + (size_t)srow * TT + j0 + sc8 * 8);
        *(bf16x8*)(&Vt[srow + 32][sc8 * 8]) = *(const bf16x8*)(vtb + (size_t)(srow + 32) * TT + j0 + sc8 * 8);
        __syncthreads();
        if (j0 > qw0 + 31) continue;

        f32x4 s[2][4] = {};
#pragma unroll
        for (int jj = 0; jj < 4; jj++) {
            bf16x8 bk0 = *(const bf16x8*)(&Kt[jj * 16 + lo][hi * 8]);
            bf16x8 bk1 = *(const bf16x8*)(&Kt[jj * 16 + lo][32 + hi * 8]);
#pragma unroll
            for (int i = 0; i < 2; i++) {
                s[i][jj] = __builtin_amdgcn_mfma_f32_16x16x32_bf16(aQ[i][0], bk0, s[i][jj], 0, 0, 0);
                s[i][jj] = __builtin_amdgcn_mfma_f32_16x16x32_bf16(aQ[i][1], bk1, s[i][jj], 0, 0, 0);
            }
        }
        bool needmask = (j0 + 63 > qw0);
        float tm[2][4], rs[2][4];
#pragma unroll
        for (int i = 0; i < 2; i++)
#pragma unroll
            for (int r = 0; r < 4; r++) {
                if (needmask) {
                    int q = qw0 + i * 16 + hi * 4 + r;
#pragma unroll
                    for (int jj = 0; jj < 4; jj++)
                        if (j0 + jj * 16 + lo > q) s[i][jj][r] = -INFINITY;
                }
                tm[i][r] = fmaxf(fmaxf(s[i][0][r], s[i][1][r]), fmaxf(s[i][2][r], s[i][3][r]));
            }
#pragma unroll
        for (int msk = 1; msk < 16; msk <<= 1)
#pragma unroll
            for (int i = 0; i < 2; i++)
#pragma unroll
                for (int r = 0; r < 4; r++)
                    tm[i][r] = fmaxf(tm[i][r], __shfl_xor(tm[i][r], msk, 64));
#pragma unroll
        for (int i = 0; i < 2; i++)
#pragma unroll
            for (int r = 0; r < 4; r++) {
                float mn = fmaxf(m[i][r], tm[i][r]);
                float f = __expf(m[i][r] - mn);
                m[i][r] = mn;
                rs[i][r] = 0.f;
#pragma unroll
                for (int jj = 0; jj < 4; jj++) {
                    s[i][jj][r] = __expf(s[i][jj][r] - mn);
                    rs[i][r] += s[i][jj][r];
                }
                ls[i][r] *= f;
#pragma unroll
                for (int jd = 0; jd < 4; jd++) o[i][jd][r] *= f;
            }
#pragma unroll
        for (int msk = 1; msk < 16; msk <<= 1)
#pragma unroll
            for (int i = 0; i < 2; i++)
#pragma unroll
                for (int r = 0; r < 4; r++)
                    rs[i][r] += __shfl_xor(rs[i][r], msk, 64);
#pragma unroll
        for (int i = 0; i < 2; i++)
#pragma unroll
            for (int r = 0; r < 4; r++) ls[i][r] += rs[i][r];

#pragma unroll
        for (int i = 0; i < 2; i++)
#pragma unroll
            for (int jj = 0; jj < 4; jj++)
#pragma unroll
                for (int r = 0; r < 4; r++)
                    Pt[w][i * 16 + hi * 4 + r][jj * 16 + lo] = f2bf(s[i][jj][r]);
        asm volatile("" ::: "memory");
        bf16x8 aP[2][2];
#pragma unroll
        for (int i = 0; i < 2; i++) {
            aP[i][0] = *(const bf16x8*)(&Pt[w][i * 16 + lo][hi * 8]);
            aP[i][1] = *(const bf16x8*)(&Pt[w][i * 16 + lo][32 + hi * 8]);
        }
        asm volatile("" ::: "memory");
#pragma unroll
        for (int jd = 0; jd < 4; jd++) {
            bf16x8 bV0 = *(const bf16x8*)(&Vt[jd * 16 + lo][hi * 8]);
            bf16x8 bV1 = *(const bf16x8*)(&Vt[jd * 16 + lo][32 + hi * 8]);
#pragma unroll
            for (int i = 0; i < 2; i++) {
                o[i][jd] = __builtin_amdgcn_mfma_f32_16x16x32_bf16(aP[i][0], bV0, o[i][jd], 0, 0, 0);
                o[i][jd] = __builtin_amdgcn_mfma_f32_16x16x32_bf16(aP[i][1], bV1, o[i][jd], 0, 0, 0);
            }
        }
    }
    u16* ob = outc + (size_t)bh * TT * DD;
#pragma unroll
    for (int i = 0; i < 2; i++)
#pragma unroll
        for (int r = 0; r < 4; r++) {
            float inv = 1.f / ls[i][r];
#pragma unroll
            for (int jd = 0; jd < 4; jd++)
                ob[(size_t)(qw0 + i * 16 + hi * 4 + r) * DD + jd * 16 + lo] = f2bf(o[i][jd][r] * inv);
        }
}

// ---------------------------------------------------------------- combine (bf16 in, bf16 out, 8 elems/thread)
__global__ void combine_kernel(const u16* __restrict__ outr, const u16* __restrict__ outc,
                               const float* __restrict__ alpha, u16* __restrict__ comb) {
    int i8 = blockIdx.x * blockDim.x + threadIdx.x;
    if (i8 >= M4 * EE / 8) return;
    int bt = i8 / (EE / 8), c8 = i8 - bt * (EE / 8);
    int h = c8 >> 3, d8 = c8 & 7;
    int b = bt >> 11, t = bt & 2047;
    size_t src = (((size_t)(b * HH + h) * TT + t) * DD + d8 * 8) / 8;
    float a = 1.f / (1.f + __expf(-alpha[h]));
    union { u16 u[8]; bf16x8 v; } vr, vc, vo;
    vr.v = ((const bf16x8*)outr)[src];
    vc.v = ((const bf16x8*)outc)[src];
#pragma unroll
    for (int e = 0; e < 8; e++)
        vo.u[e] = f2bf(a * bf2f(vr.u[e]) + (1.f - a) * bf2f(vc.u[e]));
    ((bf16x8*)comb)[i8] = vo.v;
}

// ---------------------------------------------------------------- output GEMM
__global__ __launch_bounds__(256) void gemm_out_kernel(const u16* __restrict__ A,
                                                       const u16* __restrict__ Bt,
                                                       float* __restrict__ C) {
    const int K = EE, N = EE;
    int w = threadIdx.x >> 6, l = threadIdx.x & 63;
    int lo = l & 15, hi = l >> 4;
    int m0 = blockIdx.x * 64 + (w >> 1) * 32;
    int n0 = blockIdx.y * 64 + (w & 1) * 32;
    f32x4 c[2][2] = {};
    for (int k0 = 0; k0 < K; k0 += 32) {
        bf16x8 a0 = *(const bf16x8*)(A + (size_t)(m0 + lo) * K + k0 + hi * 8);
        bf16x8 a1 = *(const bf16x8*)(A + (size_t)(m0 + 16 + lo) * K + k0 + hi * 8);
        bf16x8 b0 = *(const bf16x8*)(Bt + (size_t)(n0 + lo) * K + k0 + hi * 8);
        bf16x8 b1 = *(const bf16x8*)(Bt + (size_t)(n0 + 16 + lo) * K + k0 + hi * 8);
        c[0][0] = __builtin_amdgcn_mfma_f32_16x16x32_bf16(a0, b0, c[0][0], 0, 0, 0);
        c[0][1] = __builtin_amdgcn_mfma_f32_16x16x32_bf16(a0, b1, c[0][1], 0, 0, 0);
        c[1][0] = __builtin_amdgcn_mfma_f32_16x16x32_bf16(a1, b0, c[1][0], 0, 0, 0);
        c[1][1] = __builtin_amdgcn_mfma_f32_16x16x32_bf16(a1, b1, c[1][1], 0, 0, 0);
    }
#pragma unroll
    for (int i = 0; i < 2; i++)
#pragma unroll
        for (int j = 0; j < 2; j++)
#pragma unroll
            for (int r = 0; r < 4; r++)
                C[(size_t)(m0 + 16 * i + hi * 4 + r) * N + n0 + 16 * j + lo] = c[i][j][r];
}

// ----------------------------------------------------------------
extern "C" void kernel_launch(void* const* d_in, const int* in_sizes, int n_in,
                              void* d_out, int out_size, void* d_ws, size_t ws_size,
                              hipStream_t stream) {
    const float* x = (const float*)d_in[0];
    const float* wq = (const float*)d_in[1];
    const float* wk = (const float*)d_in[2];
    const float* wv = (const float*)d_in[3];
    const float* wr = (const float*)d_in[4];
    const float* alpha = (const float*)d_in[5];
    const float* wo = (const float*)d_in[6];
    float* out = (float*)d_out;

    char* ws = (char*)d_ws;
    size_t off = 0;
    auto carve = [&](size_t bytes) -> char* {
        char* p = ws + off;
        off += (bytes + 255) & ~(size_t)255;
        return p;
    };
    u16* xb    = (u16*)carve((size_t)M4 * EE * 2);
    u16* wqkvt = (u16*)carve((size_t)NQKV * EE * 2);
    u16* wot   = (u16*)carve((size_t)EE * EE * 2);
    u16* qb    = (u16*)carve((size_t)BH * TT * DD * 2);
    u16* kb    = (u16*)carve((size_t)BH * TT * DD * 2);
    u16* vb    = (u16*)carve((size_t)BH * TT * DD * 2);
    u16* vt    = (u16*)carve((size_t)BH * TT * DD * 2);
    float* xt   = (float*)carve((size_t)BB * EE * TT * 4);
    float* rpbuf= (float*)carve((size_t)48 * BH * TT * 4);
    float* rbuf = (float*)carve((size_t)BH * TT * 4);
    float* rmx  = (float*)carve((size_t)BH * 4);
    float* Sv   = (float*)carve((size_t)BH * SCH * DD * 4);
    float* Sl   = (float*)carve((size_t)BH * SCH * 4);
    u16* outr  = (u16*)carve((size_t)BH * TT * DD * 2);
    u16* outc  = (u16*)carve((size_t)BH * TT * DD * 2);
    u16* comb  = (u16*)carve((size_t)M4 * EE * 2);

    cast_x_kernel<<<(M4 * EE / 4 + 255) / 256, 256, 0, stream>>>(x, xb, M4 * EE / 4);
    {
        dim3 g(EE / 32, EE / 32);
        transpose_cast_kernel<<<g, 256, 0, stream>>>(wq, wqkvt, EE, EE);
        transpose_cast_kernel<<<g, 256, 0, stream>>>(wk, wqkvt + (size_t)EE * EE, EE, EE);
        transpose_cast_kernel<<<g, 256, 0, stream>>>(wv, wqkvt + 2 * (size_t)EE * EE, EE, EE);
        transpose_cast_kernel<<<g, 256, 0, stream>>>(wo, wot, EE, EE);
    }
    transpose_x_kernel<<<dim3(TT / 32, EE / 32, BB), 256, 0, stream>>>(x, xt);

    dim3 gq(M4 / 64, NQKV / 64);
    gemm_qkv_kernel<<<gq, 256, 0, stream>>>(xb, wqkvt, qb, kb, vb);
    transpose_v_kernel<<<dim3(TT / 64, BH), 256, 0, stream>>>(vb, vt);

    r_partial_kernel<<<dim3(48, 2, 2), 256, 0, stream>>>(xt, wr, rpbuf);
    r_reduce_kernel<<<BH, 256, 0, stream>>>(rpbuf, rbuf, rmx);

    scan_part_kernel<<<dim3(SCH, BH), 64, 0, stream>>>(rbuf, rmx, vb, Sv, Sl);
    scan_out_kernel<<<dim3(SCH, BH), 64, 0, stream>>>(rbuf, rmx, vb, Sv, Sl, outr);

    dim3 gf(TT / QBLK, BH);
    flash_kernel<<<gf, 256, 0, stream>>>(qb, kb, vt, outc);

    combine_kernel<<<(M4 * EE / 8 + 255) / 256, 256, 0, stream>>>(outr, outc, alpha, comb);

    dim3 go(M4 / 64, EE / 64);
    gemm_out_kernel<<<go, 256, 0, stream>>>(comb, wot, out);
}

// Round 4
// 309.620 us; speedup vs baseline: 2.4178x; 1.0856x over previous
//
#include <hip/hip_runtime.h>
#include <math.h>

typedef __bf16 bf16x8 __attribute__((ext_vector_type(8)));
typedef float f32x4 __attribute__((ext_vector_type(4)));
typedef unsigned short u16;

#define BB 2
#define TT 2048
#define EE 768
#define HH 12
#define DD 64
#define BH (BB*HH)      /* 24 */
#define M4 (BB*TT)      /* 4096 */
#define NQKV (3*EE)     /* 2304 */
#define SCH 16          /* scan chunks (128 t each) */
#define KSEG 512        /* flash split-K segment */
#define KVB 64

__device__ __forceinline__ u16 f2bf(float f) {
    union { float f; unsigned u; } v; v.f = f;
    unsigned r = v.u + 0x7FFFu + ((v.u >> 16) & 1u);
    return (u16)(r >> 16);
}
__device__ __forceinline__ float bf2f(u16 u) {
    union { unsigned u; float f; } v; v.u = ((unsigned)u) << 16;
    return v.f;
}
// u16 index of 8-elem group `grp` in row `row` of a [*,64] u16 LDS tile, XOR-swizzled
__device__ __forceinline__ int swz(int row, int grp) {
    return row * 64 + ((grp ^ (row & 7)) << 3);
}

// ---------------------------------------------------------------- x: transpose (f32) + straight cast (bf16)
__global__ __launch_bounds__(256) void transpose_x_kernel(
    const float* __restrict__ x, float* __restrict__ xt, u16* __restrict__ xb) {
    __shared__ float tile[32][33];
    int t0 = blockIdx.x * 32, e0 = blockIdx.y * 32, b = blockIdx.z;
    int tx = threadIdx.x & 31, ty = threadIdx.x >> 5;
#pragma unroll
    for (int i = 0; i < 4; i++) {
        size_t idx = ((size_t)b * TT + t0 + ty + 8 * i) * EE + e0 + tx;
        float v = x[idx];
        tile[ty + 8 * i][tx] = v;
        xb[idx] = f2bf(v);
    }
    __syncthreads();
#pragma unroll
    for (int i = 0; i < 4; i++)
        xt[((size_t)b * EE + e0 + ty + 8 * i) * TT + t0 + tx] = tile[tx][ty + 8 * i];
}

// 4 weight transposes in one launch: z=0..2 -> wqkvt slabs, z=3 -> wot
__global__ __launch_bounds__(256) void transpose_w_kernel(
    const float* __restrict__ wq, const float* __restrict__ wk,
    const float* __restrict__ wv, const float* __restrict__ wo,
    u16* __restrict__ wqkvt, u16* __restrict__ wot) {
    __shared__ float tile[32][33];
    int z = blockIdx.z;
    const float* src = (z == 0) ? wq : (z == 1) ? wk : (z == 2) ? wv : wo;
    u16* dst = (z < 3) ? (wqkvt + (size_t)z * EE * EE) : wot;
    int n0 = blockIdx.x * 32, k0 = blockIdx.y * 32;
    int tx = threadIdx.x & 31, ty = threadIdx.x >> 5;
#pragma unroll
    for (int i = 0; i < 4; i++)
        tile[ty + 8 * i][tx] = src[(size_t)(k0 + ty + 8 * i) * EE + n0 + tx];
    __syncthreads();
#pragma unroll
    for (int i = 0; i < 4; i++)
        dst[(size_t)(n0 + ty + 8 * i) * EE + k0 + tx] = f2bf(tile[tx][ty + 8 * i]);
}

// vt[bh][d][j] = vb[bh][j][d]  (bf16, LDS-tiled 64x64)
__global__ __launch_bounds__(256) void transpose_v_kernel(
    const u16* __restrict__ vb, u16* __restrict__ vt) {
    __shared__ u16 tile[64][66];
    int j0 = blockIdx.x * 64, bh = blockIdx.y;
    int tid = threadIdx.x;
#pragma unroll
    for (int i = 0; i < 16; i++) {
        int idx = i * 256 + tid;
        int j = idx >> 6, d = idx & 63;
        tile[j][d] = vb[((size_t)bh * TT + j0 + j) * DD + d];
    }
    __syncthreads();
#pragma unroll
    for (int i = 0; i < 16; i++) {
        int idx = i * 256 + tid;
        int d = idx >> 6, j = idx & 63;
        vt[((size_t)bh * DD + d) * TT + j0 + j] = tile[j][d];
    }
}

// ---------------------------------------------------------------- QKV GEMM
__global__ __launch_bounds__(256) void gemm_qkv_kernel(
    const u16* __restrict__ A, const u16* __restrict__ Bt,
    u16* __restrict__ qb, u16* __restrict__ kb, u16* __restrict__ vb)
{
    const int K = EE;
    int w = threadIdx.x >> 6, l = threadIdx.x & 63;
    int lo = l & 15, hi = l >> 4;
    int m0 = blockIdx.x * 64 + (w >> 1) * 32;
    int n0 = blockIdx.y * 64 + (w & 1) * 32;
    f32x4 c[2][2] = {};
    for (int k0 = 0; k0 < K; k0 += 32) {
        bf16x8 a0 = *(const bf16x8*)(A + (size_t)(m0 + lo) * K + k0 + hi * 8);
        bf16x8 a1 = *(const bf16x8*)(A + (size_t)(m0 + 16 + lo) * K + k0 + hi * 8);
        bf16x8 b0 = *(const bf16x8*)(Bt + (size_t)(n0 + lo) * K + k0 + hi * 8);
        bf16x8 b1 = *(const bf16x8*)(Bt + (size_t)(n0 + 16 + lo) * K + k0 + hi * 8);
        c[0][0] = __builtin_amdgcn_mfma_f32_16x16x32_bf16(a0, b0, c[0][0], 0, 0, 0);
        c[0][1] = __builtin_amdgcn_mfma_f32_16x16x32_bf16(a0, b1, c[0][1], 0, 0, 0);
        c[1][0] = __builtin_amdgcn_mfma_f32_16x16x32_bf16(a1, b0, c[1][0], 0, 0, 0);
        c[1][1] = __builtin_amdgcn_mfma_f32_16x16x32_bf16(a1, b1, c[1][1], 0, 0, 0);
    }
#pragma unroll
    for (int i = 0; i < 2; i++)
#pragma unroll
        for (int j = 0; j < 2; j++)
#pragma unroll
            for (int r = 0; r < 4; r++) {
                int m = m0 + 16 * i + hi * 4 + r;
                int n = n0 + 16 * j + lo;
                int sel = n / EE, rem = n - sel * EE;
                int h = rem >> 6, d = rem & 63;
                int b = m >> 11, t = m & 2047;
                size_t idx = ((size_t)(b * HH + h) * TT + t) * DD + d;
                float val = c[i][j][r];
                if (sel == 0) val *= 0.125f;  // fold QK^T scale into q
                u16* dst = (sel == 0) ? qb : (sel == 1) ? kb : vb;
                dst[idx] = f2bf(val);
            }
}

// ---------------------------------------------------------------- r = scale * x . wr
__global__ __launch_bounds__(256) void r_partial_kernel(
    const float* __restrict__ xt, const float* __restrict__ wr, float* __restrict__ rp) {
    int ech = blockIdx.x;           // 0..47
    int tch = blockIdx.y;           // 0..1
    int hg = blockIdx.z;            // 0..1
    int e0 = ech * 16, h0 = hg * 6;
    int tv = tch * 256 + threadIdx.x;
    const f32x4* xt4 = (const f32x4*)xt;
    const f32x4* wr4 = (const f32x4*)wr;
    f32x4 acc[2][6] = {};
#pragma unroll 4
    for (int e = 0; e < 16; e++) {
        f32x4 x0 = xt4[(size_t)(e0 + e) * 512 + tv];
        f32x4 x1 = xt4[(size_t)(EE + e0 + e) * 512 + tv];
#pragma unroll
        for (int hh = 0; hh < 6; hh++) {
            f32x4 w = wr4[((size_t)(h0 + hh) * EE + e0 + e) * 512 + tv];
            acc[0][hh] += w * x0;
            acc[1][hh] += w * x1;
        }
    }
    f32x4* rp4 = (f32x4*)rp;
#pragma unroll
    for (int b = 0; b < 2; b++)
#pragma unroll
        for (int hh = 0; hh < 6; hh++)
            rp4[((size_t)ech * 24 + b * 12 + h0 + hh) * 512 + tv] = acc[b][hh];
}

__global__ __launch_bounds__(256) void r_reduce_kernel(
    const float* __restrict__ rp, float* __restrict__ r, float* __restrict__ rmax) {
    int bh = blockIdx.x, tid = threadIdx.x;
    const f32x4* rp4 = (const f32x4*)rp;
    f32x4* r4 = (f32x4*)r;
    float mloc = -INFINITY;
#pragma unroll
    for (int seg = 0; seg < 2; seg++) {
        int tv = seg * 256 + tid;
        f32x4 s = {};
#pragma unroll 8
        for (int ech = 0; ech < 48; ech++)
            s += rp4[((size_t)ech * 24 + bh) * 512 + tv];
        s *= 0.125f;
        r4[(size_t)bh * 512 + tv] = s;
        mloc = fmaxf(mloc, fmaxf(fmaxf(s[0], s[1]), fmaxf(s[2], s[3])));
    }
    __shared__ float sm[256];
    sm[tid] = mloc; __syncthreads();
    for (int s = 128; s > 0; s >>= 1) {
        if (tid < s) sm[tid] = fmaxf(sm[tid], sm[tid + s]);
        __syncthreads();
    }
    if (tid == 0) rmax[bh] = sm[0];
}

// ---------------------------------------------------------------- rr attention = chunked prefix scan
__global__ __launch_bounds__(64) void scan_part_kernel(
    const float* __restrict__ r, const float* __restrict__ rmax,
    const u16* __restrict__ vb, float* __restrict__ Sv, float* __restrict__ Sl) {
    int c = blockIdx.x, bh = blockIdx.y, d = threadIdx.x;
    float mx = rmax[bh];
    const float* rp = r + (size_t)bh * TT + c * 128;
    const u16* vp = vb + ((size_t)bh * TT + c * 128) * DD + d;
    float accv = 0.f, accl = 0.f;
#pragma unroll 4
    for (int j = 0; j < 128; j++) {
        float w = __expf(rp[j] - mx);
        accv += w * bf2f(vp[(size_t)j * DD]);
        accl += w;
    }
    Sv[((size_t)bh * SCH + c) * DD + d] = accv;
    if (d == 0) Sl[bh * SCH + c] = accl;
}

__global__ __launch_bounds__(64) void scan_out_kernel(
    const float* __restrict__ r, const float* __restrict__ rmax,
    const u16* __restrict__ vb, const float* __restrict__ Sv, const float* __restrict__ Sl,
    u16* __restrict__ outr) {
    int c = blockIdx.x, bh = blockIdx.y, d = threadIdx.x;
    float mx = rmax[bh];
    float acc = 0.f, accl = 0.f;
    for (int cp = 0; cp < c; cp++) {
        acc += Sv[((size_t)bh * SCH + cp) * DD + d];
        accl += Sl[bh * SCH + cp];
    }
    const float* rp = r + (size_t)bh * TT + c * 128;
    const u16* vp = vb + ((size_t)bh * TT + c * 128) * DD + d;
    u16* op = outr + ((size_t)bh * TT + c * 128) * DD + d;
#pragma unroll 2
    for (int j = 0; j < 128; j++) {
        float w = __expf(rp[j] - mx);
        acc += w * bf2f(vp[(size_t)j * DD]);
        accl += w;
        op[(size_t)j * DD] = f2bf(acc * __builtin_amdgcn_rcpf(accl));
    }
}

// ---------------------------------------------------------------- content flash attention, split-K
// grid (qt=32, sg=4, bh=24); 4 waves x 16 q-rows; keys [sg*512, min(sg*512+512, q0+64))
// writes normalized partial o + (m, l) per segment
__global__ __launch_bounds__(256) void flash_kernel(
    const u16* __restrict__ qb, const u16* __restrict__ kb,
    const u16* __restrict__ vt, u16* __restrict__ op,
    float* __restrict__ mb, float* __restrict__ lb) {
    __shared__ __align__(16) u16 Kt[64 * 64];
    __shared__ __align__(16) u16 Vt[64 * 64];
    __shared__ __align__(16) u16 Pt[4][16 * 64];
    int qt = blockIdx.x, sg = blockIdx.y, bh = blockIdx.z;
    int q0 = qt * 64;
    if (sg * KSEG > q0) return;                  // segment has no causal keys
    int ks0 = sg * KSEG;
    int kend = min(ks0 + KSEG, q0 + 64);
    int tid = threadIdx.x, w = tid >> 6, l = tid & 63;
    int lo = l & 15, hi = l >> 4;
    int qw0 = q0 + w * 16;
    const u16* qbase = qb + (size_t)bh * TT * DD;
    const u16* kbase = kb + (size_t)bh * TT * DD;
    const u16* vtb = vt + (size_t)bh * DD * TT;

    bf16x8 aQ0 = *(const bf16x8*)(qbase + (size_t)(qw0 + lo) * DD + hi * 8);
    bf16x8 aQ1 = *(const bf16x8*)(qbase + (size_t)(qw0 + lo) * DD + 32 + hi * 8);

    float m[4], ls[4];
    f32x4 o[4] = {};
#pragma unroll
    for (int r = 0; r < 4; r++) { m[r] = -INFINITY; ls[r] = 0.f; }

    int sr = tid >> 3, g = tid & 7;
    for (int j0 = ks0; j0 < kend; j0 += KVB) {
        __syncthreads();
        *(bf16x8*)(Kt + swz(sr, g))      = *(const bf16x8*)(kbase + (size_t)(j0 + sr) * DD + g * 8);
        *(bf16x8*)(Kt + swz(sr + 32, g)) = *(const bf16x8*)(kbase + (size_t)(j0 + sr + 32) * DD + g * 8);
        *(bf16x8*)(Vt + swz(sr, g))      = *(const bf16x8*)(vtb + (size_t)sr * TT + j0 + g * 8);
        *(bf16x8*)(Vt + swz(sr + 32, g)) = *(const bf16x8*)(vtb + (size_t)(sr + 32) * TT + j0 + g * 8);
        __syncthreads();
        if (j0 > qw0 + 15) continue;             // entire chunk above this wave's rows

        f32x4 s[4] = {};
#pragma unroll
        for (int jj = 0; jj < 4; jj++) {
            int row = jj * 16 + lo;
            bf16x8 bk0 = *(const bf16x8*)(Kt + swz(row, hi));
            bf16x8 bk1 = *(const bf16x8*)(Kt + swz(row, 4 + hi));
            s[jj] = __builtin_amdgcn_mfma_f32_16x16x32_bf16(aQ0, bk0, s[jj], 0, 0, 0);
            s[jj] = __builtin_amdgcn_mfma_f32_16x16x32_bf16(aQ1, bk1, s[jj], 0, 0, 0);
        }
        bool needmask = (j0 + 63 > qw0);
        float tm[4], rs[4];
#pragma unroll
        for (int r = 0; r < 4; r++) {
            if (needmask) {
                int q = qw0 + hi * 4 + r;
#pragma unroll
                for (int jj = 0; jj < 4; jj++)
                    if (j0 + jj * 16 + lo > q) s[jj][r] = -INFINITY;
            }
            tm[r] = fmaxf(fmaxf(s[0][r], s[1][r]), fmaxf(s[2][r], s[3][r]));
        }
#pragma unroll
        for (int msk = 1; msk < 16; msk <<= 1)
#pragma unroll
            for (int r = 0; r < 4; r++) tm[r] = fmaxf(tm[r], __shfl_xor(tm[r], msk, 64));
#pragma unroll
        for (int r = 0; r < 4; r++) {
            float mn = fmaxf(m[r], tm[r]);
            float f = __expf(m[r] - mn);
            m[r] = mn;
            rs[r] = 0.f;
#pragma unroll
            for (int jj = 0; jj < 4; jj++) {
                s[jj][r] = __expf(s[jj][r] - mn);
                rs[r] += s[jj][r];
            }
            ls[r] *= f;
#pragma unroll
            for (int jd = 0; jd < 4; jd++) o[jd][r] *= f;
        }
#pragma unroll
        for (int msk = 1; msk < 16; msk <<= 1)
#pragma unroll
            for (int r = 0; r < 4; r++) rs[r] += __shfl_xor(rs[r], msk, 64);
#pragma unroll
        for (int r = 0; r < 4; r++) ls[r] += rs[r];

        // P (C-layout) -> swizzled LDS -> A-layout fragments (intra-wave)
#pragma unroll
        for (int jj = 0; jj < 4; jj++)
#pragma unroll
            for (int r = 0; r < 4; r++) {
                int row = hi * 4 + r;
                int cg = jj * 2 + (lo >> 3);
                Pt[w][swz(row, cg) + (lo & 7)] = f2bf(s[jj][r]);
            }
        asm volatile("" ::: "memory");
        bf16x8 aP0 = *(const bf16x8*)(Pt[w] + swz(lo, hi));
        bf16x8 aP1 = *(const bf16x8*)(Pt[w] + swz(lo, 4 + hi));
        asm volatile("" ::: "memory");
#pragma unroll
        for (int jd = 0; jd < 4; jd++) {
            int row = jd * 16 + lo;
            bf16x8 bV0 = *(const bf16x8*)(Vt + swz(row, hi));
            bf16x8 bV1 = *(const bf16x8*)(Vt + swz(row, 4 + hi));
            o[jd] = __builtin_amdgcn_mfma_f32_16x16x32_bf16(aP0, bV0, o[jd], 0, 0, 0);
            o[jd] = __builtin_amdgcn_mfma_f32_16x16x32_bf16(aP1, bV1, o[jd], 0, 0, 0);
        }
    }
    size_t pb = (size_t)(bh * 4 + sg) * TT;
#pragma unroll
    for (int r = 0; r < 4; r++) {
        float inv = 1.f / ls[r];
#pragma unroll
        for (int jd = 0; jd < 4; jd++)
            op[(pb + qw0 + hi * 4 + r) * DD + jd * 16 + lo] = f2bf(o[jd][r] * inv);
    }
    if (lo == 0)
#pragma unroll
        for (int r = 0; r < 4; r++) {
            mb[pb + qw0 + hi * 4 + r] = m[r];
            lb[pb + qw0 + hi * 4 + r] = ls[r];
        }
}

// per-(bh,t): merge weights across segments
__global__ __launch_bounds__(256) void weights_kernel(
    const float* __restrict__ mb, const float* __restrict__ lb, float* __restrict__ wgt) {
    int bh = blockIdx.x;
#pragma unroll
    for (int k = 0; k < TT / 256; k++) {
        int t = k * 256 + threadIdx.x;
        int ns = (t >> 9) + 1;
        size_t base = (size_t)bh * 4 * TT + t;
        float M = -INFINITY;
        for (int s = 0; s < ns; s++) M = fmaxf(M, mb[base + (size_t)s * TT]);
        float e[4], L = 0.f;
        for (int s = 0; s < ns; s++) {
            e[s] = lb[base + (size_t)s * TT] * __expf(mb[base + (size_t)s * TT] - M);
            L += e[s];
        }
        float inv = 1.f / L;
        for (int s = 0; s < ns; s++) wgt[base + (size_t)s * TT] = e[s] * inv;
    }
}

// merge partials + combine with rr branch -> comb (B,T,H*D) bf16
__global__ void merge_kernel(const u16* __restrict__ op, const float* __restrict__ wgt,
                             const u16* __restrict__ outr, const float* __restrict__ alpha,
                             u16* __restrict__ comb) {
    int i8 = blockIdx.x * blockDim.x + threadIdx.x;
    if (i8 >= M4 * EE / 8) return;
    int bt = i8 / (EE / 8), c8 = i8 - bt * (EE / 8);
    int h = c8 >> 3, d8 = c8 & 7;
    int b = bt >> 11, t = bt & 2047;
    int bh = b * HH + h;
    int ns = (t >> 9) + 1;
    float acc[8] = {};
    for (int s = 0; s < ns; s++) {
        size_t row = (size_t)(bh * 4 + s) * TT + t;
        float wv = wgt[row];
        union { u16 u[8]; bf16x8 v; } pv;
        pv.v = *(const bf16x8*)(op + row * DD + d8 * 8);
#pragma unroll
        for (int e = 0; e < 8; e++) acc[e] += wv * bf2f(pv.u[e]);
    }
    float a = 1.f / (1.f + __expf(-alpha[h]));
    union { u16 u[8]; bf16x8 v; } vr, vo;
    vr.v = *(const bf16x8*)(outr + (((size_t)bh * TT + t) * DD + d8 * 8));
#pragma unroll
    for (int e = 0; e < 8; e++)
        vo.u[e] = f2bf(a * bf2f(vr.u[e]) + (1.f - a) * acc[e]);
    ((bf16x8*)comb)[i8] = vo.v;
}

// ---------------------------------------------------------------- output GEMM
__global__ __launch_bounds__(256) void gemm_out_kernel(const u16* __restrict__ A,
                                                       const u16* __restrict__ Bt,
                                                       float* __restrict__ C) {
    const int K = EE, N = EE;
    int w = threadIdx.x >> 6, l = threadIdx.x & 63;
    int lo = l & 15, hi = l >> 4;
    int m0 = blockIdx.x * 64 + (w >> 1) * 32;
    int n0 = blockIdx.y * 64 + (w & 1) * 32;
    f32x4 c[2][2] = {};
    for (int k0 = 0; k0 < K; k0 += 32) {
        bf16x8 a0 = *(const bf16x8*)(A + (size_t)(m0 + lo) * K + k0 + hi * 8);
        bf16x8 a1 = *(const bf16x8*)(A + (size_t)(m0 + 16 + lo) * K + k0 + hi * 8);
        bf16x8 b0 = *(const bf16x8*)(Bt + (size_t)(n0 + lo) * K + k0 + hi * 8);
        bf16x8 b1 = *(const bf16x8*)(Bt + (size_t)(n0 + 16 + lo) * K + k0 + hi * 8);
        c[0][0] = __builtin_amdgcn_mfma_f32_16x16x32_bf16(a0, b0, c[0][0], 0, 0, 0);
        c[0][1] = __builtin_amdgcn_mfma_f32_16x16x32_bf16(a0, b1, c[0][1], 0, 0, 0);
        c[1][0] = __builtin_amdgcn_mfma_f32_16x16x32_bf16(a1, b0, c[1][0], 0, 0, 0);
        c[1][1] = __builtin_amdgcn_mfma_f32_16x16x32_bf16(a1, b1, c[1][1], 0, 0, 0);
    }
#pragma unroll
    for (int i = 0; i < 2; i++)
#pragma unroll
        for (int j = 0; j < 2; j++)
#pragma unroll
            for (int r = 0; r < 4; r++)
                C[(size_t)(m0 + 16 * i + hi * 4 + r) * N + n0 + 16 * j + lo] = c[i][j][r];
}

// ----------------------------------------------------------------
extern "C" void kernel_launch(void* const* d_in, const int* in_sizes, int n_in,
                              void* d_out, int out_size, void* d_ws, size_t ws_size,
                              hipStream_t stream) {
    const float* x = (const float*)d_in[0];
    const float* wq = (const float*)d_in[1];
    const float* wk = (const float*)d_in[2];
    const float* wv = (const float*)d_in[3];
    const float* wr = (const float*)d_in[4];
    const float* alpha = (const float*)d_in[5];
    const float* wo = (const float*)d_in[6];
    float* out = (float*)d_out;

    char* ws = (char*)d_ws;
    size_t off = 0;
    auto carve = [&](size_t bytes) -> char* {
        char* p = ws + off;
        off += (bytes + 255) & ~(size_t)255;
        return p;
    };
    u16* xb    = (u16*)carve((size_t)M4 * EE * 2);
    u16* wqkvt = (u16*)carve((size_t)NQKV * EE * 2);
    u16* wot   = (u16*)carve((size_t)EE * EE * 2);
    u16* qb    = (u16*)carve((size_t)BH * TT * DD * 2);
    u16* kb    = (u16*)carve((size_t)BH * TT * DD * 2);
    u16* vb    = (u16*)carve((size_t)BH * TT * DD * 2);
    u16* vt    = (u16*)carve((size_t)BH * TT * DD * 2);
    float* xt   = (float*)carve((size_t)BB * EE * TT * 4);
    float* rpbuf= (float*)carve((size_t)48 * BH * TT * 4);
    float* rbuf = (float*)carve((size_t)BH * TT * 4);
    float* rmx  = (float*)carve((size_t)BH * 4);
    float* Sv   = (float*)carve((size_t)BH * SCH * DD * 4);
    float* Sl   = (float*)carve((size_t)BH * SCH * 4);
    u16* outr  = (u16*)carve((size_t)BH * TT * DD * 2);
    u16* opart = (u16*)carve((size_t)BH * 4 * TT * DD * 2);
    float* mbuf = (float*)carve((size_t)BH * 4 * TT * 4);
    float* lbuf = (float*)carve((size_t)BH * 4 * TT * 4);
    float* wgt  = (float*)carve((size_t)BH * 4 * TT * 4);
    u16* comb  = (u16*)carve((size_t)M4 * EE * 2);

    transpose_x_kernel<<<dim3(TT / 32, EE / 32, BB), 256, 0, stream>>>(x, xt, xb);
    transpose_w_kernel<<<dim3(EE / 32, EE / 32, 4), 256, 0, stream>>>(wq, wk, wv, wo, wqkvt, wot);

    dim3 gq(M4 / 64, NQKV / 64);
    gemm_qkv_kernel<<<gq, 256, 0, stream>>>(xb, wqkvt, qb, kb, vb);
    transpose_v_kernel<<<dim3(TT / 64, BH), 256, 0, stream>>>(vb, vt);

    r_partial_kernel<<<dim3(48, 2, 2), 256, 0, stream>>>(xt, wr, rpbuf);
    r_reduce_kernel<<<BH, 256, 0, stream>>>(rpbuf, rbuf, rmx);

    scan_part_kernel<<<dim3(SCH, BH), 64, 0, stream>>>(rbuf, rmx, vb, Sv, Sl);
    scan_out_kernel<<<dim3(SCH, BH), 64, 0, stream>>>(rbuf, rmx, vb, Sv, Sl, outr);

    flash_kernel<<<dim3(TT / 64, 4, BH), 256, 0, stream>>>(qb, kb, vt, opart, mbuf, lbuf);
    weights_kernel<<<BH, 256, 0, stream>>>(mbuf, lbuf, wgt);
    merge_kernel<<<(M4 * EE / 8 + 255) / 256, 256, 0, stream>>>(opart, wgt, outr, alpha, comb);

    dim3 go(M4 / 64, EE / 64);
    gemm_out_kernel<<<go, 256, 0, stream>>>(comb, wot, out);
}

// Round 5
// 219.059 us; speedup vs baseline: 3.4174x; 1.4134x over previous
//
#include <hip/hip_runtime.h>
#include <math.h>

typedef __bf16 bf16x8 __attribute__((ext_vector_type(8)));
typedef float f32x4 __attribute__((ext_vector_type(4)));
typedef unsigned short u16;

#define BB 2
#define TT 2048
#define EE 768
#define HH 12
#define DD 64
#define BH (BB*HH)      /* 24 */
#define M4 (BB*TT)      /* 4096 */
#define NQKV (3*EE)     /* 2304 */
#define SCH 16          /* scan chunks (128 t each) */
#define KSEG 512        /* flash split-K segment */
#define KVB 64

__device__ __forceinline__ u16 f2bf(float f) {
    union { float f; unsigned u; } v; v.f = f;
    unsigned r = v.u + 0x7FFFu + ((v.u >> 16) & 1u);
    return (u16)(r >> 16);
}
__device__ __forceinline__ float bf2f(u16 u) {
    union { unsigned u; float f; } v; v.u = ((unsigned)u) << 16;
    return v.f;
}
// u16 index of 8-elem group `grp` in row `row` of a [*,64] u16 LDS tile, XOR-swizzled
__device__ __forceinline__ int swz(int row, int grp) {
    return row * 64 + ((grp ^ (row & 7)) << 3);
}
// async global->LDS, 16B per lane; lds base must be wave-uniform
__device__ __forceinline__ void gld_lds16(const u16* g, u16* l) {
    __builtin_amdgcn_global_load_lds(
        (const __attribute__((address_space(1))) unsigned int*)(const void*)g,
        (__attribute__((address_space(3))) unsigned int*)(void*)l,
        16, 0, 0);
}

// ---------------------------------------------------------------- x: transpose (f32) + straight cast (bf16)
__global__ __launch_bounds__(256) void transpose_x_kernel(
    const float* __restrict__ x, float* __restrict__ xt, u16* __restrict__ xb) {
    __shared__ float tile[32][33];
    int t0 = blockIdx.x * 32, e0 = blockIdx.y * 32, b = blockIdx.z;
    int tx = threadIdx.x & 31, ty = threadIdx.x >> 5;
#pragma unroll
    for (int i = 0; i < 4; i++) {
        size_t idx = ((size_t)b * TT + t0 + ty + 8 * i) * EE + e0 + tx;
        float v = x[idx];
        tile[ty + 8 * i][tx] = v;
        xb[idx] = f2bf(v);
    }
    __syncthreads();
#pragma unroll
    for (int i = 0; i < 4; i++)
        xt[((size_t)b * EE + e0 + ty + 8 * i) * TT + t0 + tx] = tile[tx][ty + 8 * i];
}

// 4 weight transposes in one launch: z=0..2 -> wqkvt slabs, z=3 -> wot
__global__ __launch_bounds__(256) void transpose_w_kernel(
    const float* __restrict__ wq, const float* __restrict__ wk,
    const float* __restrict__ wv, const float* __restrict__ wo,
    u16* __restrict__ wqkvt, u16* __restrict__ wot) {
    __shared__ float tile[32][33];
    int z = blockIdx.z;
    const float* src = (z == 0) ? wq : (z == 1) ? wk : (z == 2) ? wv : wo;
    u16* dst = (z < 3) ? (wqkvt + (size_t)z * EE * EE) : wot;
    int n0 = blockIdx.x * 32, k0 = blockIdx.y * 32;
    int tx = threadIdx.x & 31, ty = threadIdx.x >> 5;
#pragma unroll
    for (int i = 0; i < 4; i++)
        tile[ty + 8 * i][tx] = src[(size_t)(k0 + ty + 8 * i) * EE + n0 + tx];
    __syncthreads();
#pragma unroll
    for (int i = 0; i < 4; i++)
        dst[(size_t)(n0 + ty + 8 * i) * EE + k0 + tx] = f2bf(tile[tx][ty + 8 * i]);
}

// vt[bh][d][j] = vb[bh][j][d]  (bf16, LDS-tiled 64x64)
__global__ __launch_bounds__(256) void transpose_v_kernel(
    const u16* __restrict__ vb, u16* __restrict__ vt) {
    __shared__ u16 tile[64][66];
    int j0 = blockIdx.x * 64, bh = blockIdx.y;
    int tid = threadIdx.x;
#pragma unroll
    for (int i = 0; i < 16; i++) {
        int idx = i * 256 + tid;
        int j = idx >> 6, d = idx & 63;
        tile[j][d] = vb[((size_t)bh * TT + j0 + j) * DD + d];
    }
    __syncthreads();
#pragma unroll
    for (int i = 0; i < 16; i++) {
        int idx = i * 256 + tid;
        int d = idx >> 6, j = idx & 63;
        vt[((size_t)bh * DD + d) * TT + j0 + j] = tile[j][d];
    }
}

// ---------------------------------------------------------------- QKV GEMM (m97 structure)
// A: xb (4096x768), Bt: wqkvt (2304x768). 128x128 tile, BK=32, global_load_lds staging.
__global__ __launch_bounds__(256) void gemm_qkv_kernel(
    const u16* __restrict__ A, const u16* __restrict__ Bt,
    u16* __restrict__ qb, u16* __restrict__ kb, u16* __restrict__ vb)
{
    __shared__ __align__(16) u16 As[128 * 32];
    __shared__ __align__(16) u16 Bs[128 * 32];
    const int K = EE;
    int tid = threadIdx.x;
    int w = tid >> 6, l = tid & 63;
    int lo = l & 15, hi = l >> 4;
    int wm = w >> 1, wn = w & 1;
    int m0 = blockIdx.x * 128;
    int n0 = blockIdx.y * 128;
    int srow = l >> 2, sgrp = l & 3;   // staging: row-in-chunk, 8-elem group

    f32x4 acc[4][4] = {};
    for (int k0 = 0; k0 < K; k0 += 32) {
        __syncthreads();
        // A tile: 8 chunks of 16 rows; wave w stages chunks w and w+4
        gld_lds16(A + (size_t)(m0 + w * 16 + srow) * K + k0 + sgrp * 8,       As + w * 512);
        gld_lds16(A + (size_t)(m0 + (w + 4) * 16 + srow) * K + k0 + sgrp * 8, As + (w + 4) * 512);
        gld_lds16(Bt + (size_t)(n0 + w * 16 + srow) * K + k0 + sgrp * 8,       Bs + w * 512);
        gld_lds16(Bt + (size_t)(n0 + (w + 4) * 16 + srow) * K + k0 + sgrp * 8, Bs + (w + 4) * 512);
        __syncthreads();
        bf16x8 af[4], bfr[4];
#pragma unroll
        for (int i = 0; i < 4; i++)
            af[i] = *(const bf16x8*)(As + (wm * 64 + i * 16 + lo) * 32 + hi * 8);
#pragma unroll
        for (int j = 0; j < 4; j++)
            bfr[j] = *(const bf16x8*)(Bs + (wn * 64 + j * 16 + lo) * 32 + hi * 8);
#pragma unroll
        for (int i = 0; i < 4; i++)
#pragma unroll
            for (int j = 0; j < 4; j++)
                acc[i][j] = __builtin_amdgcn_mfma_f32_16x16x32_bf16(af[i], bfr[j], acc[i][j], 0, 0, 0);
    }
    int sel = n0 / EE;
    int rem0 = n0 - sel * EE;
    u16* dst = (sel == 0) ? qb : (sel == 1) ? kb : vb;
    float mul = (sel == 0) ? 0.125f : 1.f;
#pragma unroll
    for (int j = 0; j < 4; j++) {
        int h = (rem0 + wn * 64 + j * 16) >> 6;
        int d = (wn * 64 + j * 16 + lo) & 63;
#pragma unroll
        for (int i = 0; i < 4; i++)
#pragma unroll
            for (int r = 0; r < 4; r++) {
                int m = m0 + wm * 64 + i * 16 + hi * 4 + r;
                int b = m >> 11, t = m & 2047;
                dst[((size_t)(b * HH + h) * TT + t) * DD + d] = f2bf(acc[i][j][r] * mul);
            }
    }
}

// ---------------------------------------------------------------- r = scale * x . wr
__global__ __launch_bounds__(256) void r_partial_kernel(
    const float* __restrict__ xt, const float* __restrict__ wr, float* __restrict__ rp) {
    int ech = blockIdx.x;           // 0..47
    int tch = blockIdx.y;           // 0..1
    int hg = blockIdx.z;            // 0..1
    int e0 = ech * 16, h0 = hg * 6;
    int tv = tch * 256 + threadIdx.x;
    const f32x4* xt4 = (const f32x4*)xt;
    const f32x4* wr4 = (const f32x4*)wr;
    f32x4 acc[2][6] = {};
#pragma unroll 4
    for (int e = 0; e < 16; e++) {
        f32x4 x0 = xt4[(size_t)(e0 + e) * 512 + tv];
        f32x4 x1 = xt4[(size_t)(EE + e0 + e) * 512 + tv];
#pragma unroll
        for (int hh = 0; hh < 6; hh++) {
            f32x4 w = wr4[((size_t)(h0 + hh) * EE + e0 + e) * 512 + tv];
            acc[0][hh] += w * x0;
            acc[1][hh] += w * x1;
        }
    }
    f32x4* rp4 = (f32x4*)rp;
#pragma unroll
    for (int b = 0; b < 2; b++)
#pragma unroll
        for (int hh = 0; hh < 6; hh++)
            rp4[((size_t)ech * 24 + b * 12 + h0 + hh) * 512 + tv] = acc[b][hh];
}

__global__ __launch_bounds__(256) void r_reduce_kernel(
    const float* __restrict__ rp, float* __restrict__ r, float* __restrict__ rmax) {
    int bh = blockIdx.x, tid = threadIdx.x;
    const f32x4* rp4 = (const f32x4*)rp;
    f32x4* r4 = (f32x4*)r;
    float mloc = -INFINITY;
#pragma unroll
    for (int seg = 0; seg < 2; seg++) {
        int tv = seg * 256 + tid;
        f32x4 s = {};
#pragma unroll 8
        for (int ech = 0; ech < 48; ech++)
            s += rp4[((size_t)ech * 24 + bh) * 512 + tv];
        s *= 0.125f;
        r4[(size_t)bh * 512 + tv] = s;
        mloc = fmaxf(mloc, fmaxf(fmaxf(s[0], s[1]), fmaxf(s[2], s[3])));
    }
    __shared__ float sm[256];
    sm[tid] = mloc; __syncthreads();
    for (int s = 128; s > 0; s >>= 1) {
        if (tid < s) sm[tid] = fmaxf(sm[tid], sm[tid + s]);
        __syncthreads();
    }
    if (tid == 0) rmax[bh] = sm[0];
}

// ---------------------------------------------------------------- rr attention = chunked prefix scan
__global__ __launch_bounds__(64) void scan_part_kernel(
    const float* __restrict__ r, const float* __restrict__ rmax,
    const u16* __restrict__ vb, float* __restrict__ Sv, float* __restrict__ Sl) {
    int c = blockIdx.x, bh = blockIdx.y, d = threadIdx.x;
    float mx = rmax[bh];
    const float* rp = r + (size_t)bh * TT + c * 128;
    const u16* vp = vb + ((size_t)bh * TT + c * 128) * DD + d;
    float accv = 0.f, accl = 0.f;
#pragma unroll 4
    for (int j = 0; j < 128; j++) {
        float w = __expf(rp[j] - mx);
        accv += w * bf2f(vp[(size_t)j * DD]);
        accl += w;
    }
    Sv[((size_t)bh * SCH + c) * DD + d] = accv;
    if (d == 0) Sl[bh * SCH + c] = accl;
}

__global__ __launch_bounds__(64) void scan_out_kernel(
    const float* __restrict__ r, const float* __restrict__ rmax,
    const u16* __restrict__ vb, const float* __restrict__ Sv, const float* __restrict__ Sl,
    u16* __restrict__ outr) {
    int c = blockIdx.x, bh = blockIdx.y, d = threadIdx.x;
    float mx = rmax[bh];
    float acc = 0.f, accl = 0.f;
    for (int cp = 0; cp < c; cp++) {
        acc += Sv[((size_t)bh * SCH + cp) * DD + d];
        accl += Sl[bh * SCH + cp];
    }
    const float* rp = r + (size_t)bh * TT + c * 128;
    const u16* vp = vb + ((size_t)bh * TT + c * 128) * DD + d;
    u16* op = outr + ((size_t)bh * TT + c * 128) * DD + d;
#pragma unroll 2
    for (int j = 0; j < 128; j++) {
        float w = __expf(rp[j] - mx);
        acc += w * bf2f(vp[(size_t)j * DD]);
        accl += w;
        op[(size_t)j * DD] = f2bf(acc * __builtin_amdgcn_rcpf(accl));
    }
}

// ---------------------------------------------------------------- content flash attention, split-K
__global__ __launch_bounds__(256) void flash_kernel(
    const u16* __restrict__ qb, const u16* __restrict__ kb,
    const u16* __restrict__ vt, u16* __restrict__ op,
    float* __restrict__ mb, float* __restrict__ lb) {
    __shared__ __align__(16) u16 Kt[64 * 64];
    __shared__ __align__(16) u16 Vt[64 * 64];
    __shared__ __align__(16) u16 Pt[4][16 * 64];
    int qt = blockIdx.x, sg = blockIdx.y, bh = blockIdx.z;
    int q0 = qt * 64;
    if (sg * KSEG > q0) return;                  // segment has no causal keys
    int ks0 = sg * KSEG;
    int kend = min(ks0 + KSEG, q0 + 64);
    int tid = threadIdx.x, w = tid >> 6, l = tid & 63;
    int lo = l & 15, hi = l >> 4;
    int qw0 = q0 + w * 16;
    const u16* qbase = qb + (size_t)bh * TT * DD;
    const u16* kbase = kb + (size_t)bh * TT * DD;
    const u16* vtb = vt + (size_t)bh * DD * TT;

    bf16x8 aQ0 = *(const bf16x8*)(qbase + (size_t)(qw0 + lo) * DD + hi * 8);
    bf16x8 aQ1 = *(const bf16x8*)(qbase + (size_t)(qw0 + lo) * DD + 32 + hi * 8);

    float m[4], ls[4];
    f32x4 o[4] = {};
#pragma unroll
    for (int r = 0; r < 4; r++) { m[r] = -INFINITY; ls[r] = 0.f; }

    int sr = tid >> 3, g = tid & 7;
    for (int j0 = ks0; j0 < kend; j0 += KVB) {
        __syncthreads();
        *(bf16x8*)(Kt + swz(sr, g))      = *(const bf16x8*)(kbase + (size_t)(j0 + sr) * DD + g * 8);
        *(bf16x8*)(Kt + swz(sr + 32, g)) = *(const bf16x8*)(kbase + (size_t)(j0 + sr + 32) * DD + g * 8);
        *(bf16x8*)(Vt + swz(sr, g))      = *(const bf16x8*)(vtb + (size_t)sr * TT + j0 + g * 8);
        *(bf16x8*)(Vt + swz(sr + 32, g)) = *(const bf16x8*)(vtb + (size_t)(sr + 32) * TT + j0 + g * 8);
        __syncthreads();
        if (j0 > qw0 + 15) continue;             // entire chunk above this wave's rows

        f32x4 s[4] = {};
#pragma unroll
        for (int jj = 0; jj < 4; jj++) {
            int row = jj * 16 + lo;
            bf16x8 bk0 = *(const bf16x8*)(Kt + swz(row, hi));
            bf16x8 bk1 = *(const bf16x8*)(Kt + swz(row, 4 + hi));
            s[jj] = __builtin_amdgcn_mfma_f32_16x16x32_bf16(aQ0, bk0, s[jj], 0, 0, 0);
            s[jj] = __builtin_amdgcn_mfma_f32_16x16x32_bf16(aQ1, bk1, s[jj], 0, 0, 0);
        }
        bool needmask = (j0 + 63 > qw0);
        float tm[4], rs[4];
#pragma unroll
        for (int r = 0; r < 4; r++) {
            if (needmask) {
                int q = qw0 + hi * 4 + r;
#pragma unroll
                for (int jj = 0; jj < 4; jj++)
                    if (j0 + jj * 16 + lo > q) s[jj][r] = -INFINITY;
            }
            tm[r] = fmaxf(fmaxf(s[0][r], s[1][r]), fmaxf(s[2][r], s[3][r]));
        }
#pragma unroll
        for (int msk = 1; msk < 16; msk <<= 1)
#pragma unroll
            for (int r = 0; r < 4; r++) tm[r] = fmaxf(tm[r], __shfl_xor(tm[r], msk, 64));
#pragma unroll
        for (int r = 0; r < 4; r++) {
            float mn = fmaxf(m[r], tm[r]);
            float f = __expf(m[r] - mn);
            m[r] = mn;
            rs[r] = 0.f;
#pragma unroll
            for (int jj = 0; jj < 4; jj++) {
                s[jj][r] = __expf(s[jj][r] - mn);
                rs[r] += s[jj][r];
            }
            ls[r] *= f;
#pragma unroll
            for (int jd = 0; jd < 4; jd++) o[jd][r] *= f;
        }
#pragma unroll
        for (int msk = 1; msk < 16; msk <<= 1)
#pragma unroll
            for (int r = 0; r < 4; r++) rs[r] += __shfl_xor(rs[r], msk, 64);
#pragma unroll
        for (int r = 0; r < 4; r++) ls[r] += rs[r];

#pragma unroll
        for (int jj = 0; jj < 4; jj++)
#pragma unroll
            for (int r = 0; r < 4; r++) {
                int row = hi * 4 + r;
                int cg = jj * 2 + (lo >> 3);
                Pt[w][swz(row, cg) + (lo & 7)] = f2bf(s[jj][r]);
            }
        asm volatile("" ::: "memory");
        bf16x8 aP0 = *(const bf16x8*)(Pt[w] + swz(lo, hi));
        bf16x8 aP1 = *(const bf16x8*)(Pt[w] + swz(lo, 4 + hi));
        asm volatile("" ::: "memory");
#pragma unroll
        for (int jd = 0; jd < 4; jd++) {
            int row = jd * 16 + lo;
            bf16x8 bV0 = *(const bf16x8*)(Vt + swz(row, hi));
            bf16x8 bV1 = *(const bf16x8*)(Vt + swz(row, 4 + hi));
            o[jd] = __builtin_amdgcn_mfma_f32_16x16x32_bf16(aP0, bV0, o[jd], 0, 0, 0);
            o[jd] = __builtin_amdgcn_mfma_f32_16x16x32_bf16(aP1, bV1, o[jd], 0, 0, 0);
        }
    }
    size_t pb = (size_t)(bh * 4 + sg) * TT;
#pragma unroll
    for (int r = 0; r < 4; r++) {
        float inv = 1.f / ls[r];
#pragma unroll
        for (int jd = 0; jd < 4; jd++)
            op[(pb + qw0 + hi * 4 + r) * DD + jd * 16 + lo] = f2bf(o[jd][r] * inv);
    }
    if (lo == 0)
#pragma unroll
        for (int r = 0; r < 4; r++) {
            mb[pb + qw0 + hi * 4 + r] = m[r];
            lb[pb + qw0 + hi * 4 + r] = ls[r];
        }
}

// per-(bh,t): merge weights across segments
__global__ __launch_bounds__(256) void weights_kernel(
    const float* __restrict__ mb, const float* __restrict__ lb, float* __restrict__ wgt) {
    int bh = blockIdx.x;
#pragma unroll
    for (int k = 0; k < TT / 256; k++) {
        int t = k * 256 + threadIdx.x;
        int ns = (t >> 9) + 1;
        size_t base = (size_t)bh * 4 * TT + t;
        float M = -INFINITY;
        for (int s = 0; s < ns; s++) M = fmaxf(M, mb[base + (size_t)s * TT]);
        float e[4], L = 0.f;
        for (int s = 0; s < ns; s++) {
            e[s] = lb[base + (size_t)s * TT] * __expf(mb[base + (size_t)s * TT] - M);
            L += e[s];
        }
        float inv = 1.f / L;
        for (int s = 0; s < ns; s++) wgt[base + (size_t)s * TT] = e[s] * inv;
    }
}

// merge partials + combine with rr branch -> comb (B,T,H*D) bf16
__global__ void merge_kernel(const u16* __restrict__ op, const float* __restrict__ wgt,
                             const u16* __restrict__ outr, const float* __restrict__ alpha,
                             u16* __restrict__ comb) {
    int i8 = blockIdx.x * blockDim.x + threadIdx.x;
    if (i8 >= M4 * EE / 8) return;
    int bt = i8 / (EE / 8), c8 = i8 - bt * (EE / 8);
    int h = c8 >> 3, d8 = c8 & 7;
    int b = bt >> 11, t = bt & 2047;
    int bh = b * HH + h;
    int ns = (t >> 9) + 1;
    float acc[8] = {};
    for (int s = 0; s < ns; s++) {
        size_t row = (size_t)(bh * 4 + s) * TT + t;
        float wv = wgt[row];
        union { u16 u[8]; bf16x8 v; } pv;
        pv.v = *(const bf16x8*)(op + row * DD + d8 * 8);
#pragma unroll
        for (int e = 0; e < 8; e++) acc[e] += wv * bf2f(pv.u[e]);
    }
    float a = 1.f / (1.f + __expf(-alpha[h]));
    union { u16 u[8]; bf16x8 v; } vr, vo;
    vr.v = *(const bf16x8*)(outr + (((size_t)bh * TT + t) * DD + d8 * 8));
#pragma unroll
    for (int e = 0; e < 8; e++)
        vo.u[e] = f2bf(a * bf2f(vr.u[e]) + (1.f - a) * acc[e]);
    ((bf16x8*)comb)[i8] = vo.v;
}

// ---------------------------------------------------------------- output GEMM (m97 structure)
// A: comb (4096x768), Bt: wot (768x768), C fp32 (4096x768)
__global__ __launch_bounds__(256) void gemm_out_kernel(const u16* __restrict__ A,
                                                       const u16* __restrict__ Bt,
                                                       float* __restrict__ C) {
    __shared__ __align__(16) u16 As[128 * 32];
    __shared__ __align__(16) u16 Bs[128 * 32];
    const int K = EE;
    int tid = threadIdx.x;
    int w = tid >> 6, l = tid & 63;
    int lo = l & 15, hi = l >> 4;
    int wm = w >> 1, wn = w & 1;
    int m0 = blockIdx.x * 128;
    int n0 = blockIdx.y * 128;
    int srow = l >> 2, sgrp = l & 3;

    f32x4 acc[4][4] = {};
    for (int k0 = 0; k0 < K; k0 += 32) {
        __syncthreads();
        gld_lds16(A + (size_t)(m0 + w * 16 + srow) * K + k0 + sgrp * 8,       As + w * 512);
        gld_lds16(A + (size_t)(m0 + (w + 4) * 16 + srow) * K + k0 + sgrp * 8, As + (w + 4) * 512);
        gld_lds16(Bt + (size_t)(n0 + w * 16 + srow) * K + k0 + sgrp * 8,       Bs + w * 512);
        gld_lds16(Bt + (size_t)(n0 + (w + 4) * 16 + srow) * K + k0 + sgrp * 8, Bs + (w + 4) * 512);
        __syncthreads();
        bf16x8 af[4], bfr[4];
#pragma unroll
        for (int i = 0; i < 4; i++)
            af[i] = *(const bf16x8*)(As + (wm * 64 + i * 16 + lo) * 32 + hi * 8);
#pragma unroll
        for (int j = 0; j < 4; j++)
            bfr[j] = *(const bf16x8*)(Bs + (wn * 64 + j * 16 + lo) * 32 + hi * 8);
#pragma unroll
        for (int i = 0; i < 4; i++)
#pragma unroll
            for (int j = 0; j < 4; j++)
                acc[i][j] = __builtin_amdgcn_mfma_f32_16x16x32_bf16(af[i], bfr[j], acc[i][j], 0, 0, 0);
    }
#pragma unroll
    for (int i = 0; i < 4; i++)
#pragma unroll
        for (int j = 0; j < 4; j++)
#pragma unroll
            for (int r = 0; r < 4; r++) {
                int m = m0 + wm * 64 + i * 16 + hi * 4 + r;
                int n = n0 + wn * 64 + j * 16 + lo;
                C[(size_t)m * EE + n] = acc[i][j][r];
            }
}

// ----------------------------------------------------------------
extern "C" void kernel_launch(void* const* d_in, const int* in_sizes, int n_in,
                              void* d_out, int out_size, void* d_ws, size_t ws_size,
                              hipStream_t stream) {
    const float* x = (const float*)d_in[0];
    const float* wq = (const float*)d_in[1];
    const float* wk = (const float*)d_in[2];
    const float* wv = (const float*)d_in[3];
    const float* wr = (const float*)d_in[4];
    const float* alpha = (const float*)d_in[5];
    const float* wo = (const float*)d_in[6];
    float* out = (float*)d_out;

    char* ws = (char*)d_ws;
    size_t off = 0;
    auto carve = [&](size_t bytes) -> char* {
        char* p = ws + off;
        off += (bytes + 255) & ~(size_t)255;
        return p;
    };
    u16* xb    = (u16*)carve((size_t)M4 * EE * 2);
    u16* wqkvt = (u16*)carve((size_t)NQKV * EE * 2);
    u16* wot   = (u16*)carve((size_t)EE * EE * 2);
    u16* qb    = (u16*)carve((size_t)BH * TT * DD * 2);
    u16* kb    = (u16*)carve((size_t)BH * TT * DD * 2);
    u16* vb    = (u16*)carve((size_t)BH * TT * DD * 2);
    u16* vt    = (u16*)carve((size_t)BH * TT * DD * 2);
    float* xt   = (float*)carve((size_t)BB * EE * TT * 4);
    float* rpbuf= (float*)carve((size_t)48 * BH * TT * 4);
    float* rbuf = (float*)carve((size_t)BH * TT * 4);
    float* rmx  = (float*)carve((size_t)BH * 4);
    float* Sv   = (float*)carve((size_t)BH * SCH * DD * 4);
    float* Sl   = (float*)carve((size_t)BH * SCH * 4);
    u16* outr  = (u16*)carve((size_t)BH * TT * DD * 2);
    u16* opart = (u16*)carve((size_t)BH * 4 * TT * DD * 2);
    float* mbuf = (float*)carve((size_t)BH * 4 * TT * 4);
    float* lbuf = (float*)carve((size_t)BH * 4 * TT * 4);
    float* wgt  = (float*)carve((size_t)BH * 4 * TT * 4);
    u16* comb  = (u16*)carve((size_t)M4 * EE * 2);

    transpose_x_kernel<<<dim3(TT / 32, EE / 32, BB), 256, 0, stream>>>(x, xt, xb);
    transpose_w_kernel<<<dim3(EE / 32, EE / 32, 4), 256, 0, stream>>>(wq, wk, wv, wo, wqkvt, wot);

    dim3 gq(M4 / 128, NQKV / 128);
    gemm_qkv_kernel<<<gq, 256, 0, stream>>>(xb, wqkvt, qb, kb, vb);
    transpose_v_kernel<<<dim3(TT / 64, BH), 256, 0, stream>>>(vb, vt);

    r_partial_kernel<<<dim3(48, 2, 2), 256, 0, stream>>>(xt, wr, rpbuf);
    r_reduce_kernel<<<BH, 256, 0, stream>>>(rpbuf, rbuf, rmx);

    scan_part_kernel<<<dim3(SCH, BH), 64, 0, stream>>>(rbuf, rmx, vb, Sv, Sl);
    scan_out_kernel<<<dim3(SCH, BH), 64, 0, stream>>>(rbuf, rmx, vb, Sv, Sl, outr);

    flash_kernel<<<dim3(TT / 64, 4, BH), 256, 0, stream>>>(qb, kb, vt, opart, mbuf, lbuf);
    weights_kernel<<<BH, 256, 0, stream>>>(mbuf, lbuf, wgt);
    merge_kernel<<<(M4 * EE / 8 + 255) / 256, 256, 0, stream>>>(opart, wgt, outr, alpha, comb);

    dim3 go(M4 / 128, EE / 128);
    gemm_out_kernel<<<go, 256, 0, stream>>>(comb, wot, out);
}

// Round 6
// 191.440 us; speedup vs baseline: 3.9104x; 1.1443x over previous
//
#include <hip/hip_runtime.h>
#include <math.h>

typedef __bf16 bf16x8 __attribute__((ext_vector_type(8)));
typedef float f32x4 __attribute__((ext_vector_type(4)));
typedef unsigned short u16;
typedef unsigned short u16x4 __attribute__((ext_vector_type(4)));

#define BB 2
#define TT 2048
#define EE 768
#define HH 12
#define DD 64
#define BH (BB*HH)      /* 24 */
#define M4 (BB*TT)      /* 4096 */
#define NQKV (3*EE)     /* 2304 */
#define SCH 16          /* scan chunks (128 t each) */
#define KSEG 512        /* flash split-K segment */
#define KVB 64

__device__ __forceinline__ u16 f2bf(float f) {
    union { float f; unsigned u; } v; v.f = f;
    unsigned r = v.u + 0x7FFFu + ((v.u >> 16) & 1u);
    return (u16)(r >> 16);
}
__device__ __forceinline__ float bf2f(u16 u) {
    union { unsigned u; float f; } v; v.u = ((unsigned)u) << 16;
    return v.f;
}
// pack two f32 -> u32 of 2 bf16 (lo = a, hi = b), RTNE
__device__ __forceinline__ unsigned cvtpk(float a, float b) {
    unsigned r;
    asm("v_cvt_pk_bf16_f32 %0, %1, %2" : "=v"(r) : "v"(a), "v"(b));
    return r;
}
// u16 index of 8-elem group `grp` in row `row` of a [*,64] u16 LDS tile, XOR-swizzled
__device__ __forceinline__ int swz(int row, int grp) {
    return row * 64 + ((grp ^ (row & 7)) << 3);
}
// async global->LDS, 16B per lane; lds base must be wave-uniform
__device__ __forceinline__ void gld_lds16(const u16* g, u16* l) {
    __builtin_amdgcn_global_load_lds(
        (const __attribute__((address_space(1))) unsigned int*)(const void*)g,
        (__attribute__((address_space(3))) unsigned int*)(void*)l,
        16, 0, 0);
}

// ---------------------------------------------------------------- x: transpose (f32) + straight cast (bf16)
__global__ __launch_bounds__(256) void transpose_x_kernel(
    const float* __restrict__ x, float* __restrict__ xt, u16* __restrict__ xb) {
    __shared__ float tile[32][33];
    int t0 = blockIdx.x * 32, e0 = blockIdx.y * 32, b = blockIdx.z;
    int tx = threadIdx.x & 31, ty = threadIdx.x >> 5;
#pragma unroll
    for (int i = 0; i < 4; i++) {
        size_t idx = ((size_t)b * TT + t0 + ty + 8 * i) * EE + e0 + tx;
        float v = x[idx];
        tile[ty + 8 * i][tx] = v;
        xb[idx] = f2bf(v);
    }
    __syncthreads();
#pragma unroll
    for (int i = 0; i < 4; i++)
        xt[((size_t)b * EE + e0 + ty + 8 * i) * TT + t0 + tx] = tile[tx][ty + 8 * i];
}

// 4 weight transposes in one launch: z=0..2 -> wqkvt slabs, z=3 -> wot
__global__ __launch_bounds__(256) void transpose_w_kernel(
    const float* __restrict__ wq, const float* __restrict__ wk,
    const float* __restrict__ wv, const float* __restrict__ wo,
    u16* __restrict__ wqkvt, u16* __restrict__ wot) {
    __shared__ float tile[32][33];
    int z = blockIdx.z;
    const float* src = (z == 0) ? wq : (z == 1) ? wk : (z == 2) ? wv : wo;
    u16* dst = (z < 3) ? (wqkvt + (size_t)z * EE * EE) : wot;
    int n0 = blockIdx.x * 32, k0 = blockIdx.y * 32;
    int tx = threadIdx.x & 31, ty = threadIdx.x >> 5;
#pragma unroll
    for (int i = 0; i < 4; i++)
        tile[ty + 8 * i][tx] = src[(size_t)(k0 + ty + 8 * i) * EE + n0 + tx];
    __syncthreads();
#pragma unroll
    for (int i = 0; i < 4; i++)
        dst[(size_t)(n0 + ty + 8 * i) * EE + k0 + tx] = f2bf(tile[tx][ty + 8 * i]);
}

// vt[bh][d][j] = vb[bh][j][d]  (bf16, LDS-tiled 64x64)
__global__ __launch_bounds__(256) void transpose_v_kernel(
    const u16* __restrict__ vb, u16* __restrict__ vt) {
    __shared__ u16 tile[64][66];
    int j0 = blockIdx.x * 64, bh = blockIdx.y;
    int tid = threadIdx.x;
#pragma unroll
    for (int i = 0; i < 16; i++) {
        int idx = i * 256 + tid;
        int j = idx >> 6, d = idx & 63;
        tile[j][d] = vb[((size_t)bh * TT + j0 + j) * DD + d];
    }
    __syncthreads();
#pragma unroll
    for (int i = 0; i < 16; i++) {
        int idx = i * 256 + tid;
        int d = idx >> 6, j = idx & 63;
        vt[((size_t)bh * DD + d) * TT + j0 + j] = tile[j][d];
    }
}

// ---------------------------------------------------------------- QKV GEMM (m97 structure)
__global__ __launch_bounds__(256) void gemm_qkv_kernel(
    const u16* __restrict__ A, const u16* __restrict__ Bt,
    u16* __restrict__ qb, u16* __restrict__ kb, u16* __restrict__ vb)
{
    __shared__ __align__(16) u16 As[128 * 32];
    __shared__ __align__(16) u16 Bs[128 * 32];
    const int K = EE;
    int tid = threadIdx.x;
    int w = tid >> 6, l = tid & 63;
    int lo = l & 15, hi = l >> 4;
    int wm = w >> 1, wn = w & 1;
    int m0 = blockIdx.x * 128;
    int n0 = blockIdx.y * 128;
    int srow = l >> 2, sgrp = l & 3;

    f32x4 acc[4][4] = {};
    for (int k0 = 0; k0 < K; k0 += 32) {
        __syncthreads();
        gld_lds16(A + (size_t)(m0 + w * 16 + srow) * K + k0 + sgrp * 8,       As + w * 512);
        gld_lds16(A + (size_t)(m0 + (w + 4) * 16 + srow) * K + k0 + sgrp * 8, As + (w + 4) * 512);
        gld_lds16(Bt + (size_t)(n0 + w * 16 + srow) * K + k0 + sgrp * 8,       Bs + w * 512);
        gld_lds16(Bt + (size_t)(n0 + (w + 4) * 16 + srow) * K + k0 + sgrp * 8, Bs + (w + 4) * 512);
        __syncthreads();
        bf16x8 af[4], bfr[4];
#pragma unroll
        for (int i = 0; i < 4; i++)
            af[i] = *(const bf16x8*)(As + (wm * 64 + i * 16 + lo) * 32 + hi * 8);
#pragma unroll
        for (int j = 0; j < 4; j++)
            bfr[j] = *(const bf16x8*)(Bs + (wn * 64 + j * 16 + lo) * 32 + hi * 8);
#pragma unroll
        for (int i = 0; i < 4; i++)
#pragma unroll
            for (int j = 0; j < 4; j++)
                acc[i][j] = __builtin_amdgcn_mfma_f32_16x16x32_bf16(af[i], bfr[j], acc[i][j], 0, 0, 0);
    }
    int sel = n0 / EE;
    int rem0 = n0 - sel * EE;
    u16* dst = (sel == 0) ? qb : (sel == 1) ? kb : vb;
    float mul = (sel == 0) ? 0.125f : 1.f;
#pragma unroll
    for (int j = 0; j < 4; j++) {
        int h = (rem0 + wn * 64 + j * 16) >> 6;
        int d = (wn * 64 + j * 16 + lo) & 63;
#pragma unroll
        for (int i = 0; i < 4; i++)
#pragma unroll
            for (int r = 0; r < 4; r++) {
                int m = m0 + wm * 64 + i * 16 + hi * 4 + r;
                int b = m >> 11, t = m & 2047;
                dst[((size_t)(b * HH + h) * TT + t) * DD + d] = f2bf(acc[i][j][r] * mul);
            }
    }
}

// ---------------------------------------------------------------- r = scale * x . wr
__global__ __launch_bounds__(256) void r_partial_kernel(
    const float* __restrict__ xt, const float* __restrict__ wr, float* __restrict__ rp) {
    int ech = blockIdx.x;           // 0..47
    int tch = blockIdx.y;           // 0..1
    int hg = blockIdx.z;            // 0..1
    int e0 = ech * 16, h0 = hg * 6;
    int tv = tch * 256 + threadIdx.x;
    const f32x4* xt4 = (const f32x4*)xt;
    const f32x4* wr4 = (const f32x4*)wr;
    f32x4 acc[2][6] = {};
#pragma unroll 4
    for (int e = 0; e < 16; e++) {
        f32x4 x0 = xt4[(size_t)(e0 + e) * 512 + tv];
        f32x4 x1 = xt4[(size_t)(EE + e0 + e) * 512 + tv];
#pragma unroll
        for (int hh = 0; hh < 6; hh++) {
            f32x4 w = wr4[((size_t)(h0 + hh) * EE + e0 + e) * 512 + tv];
            acc[0][hh] += w * x0;
            acc[1][hh] += w * x1;
        }
    }
    f32x4* rp4 = (f32x4*)rp;
#pragma unroll
    for (int b = 0; b < 2; b++)
#pragma unroll
        for (int hh = 0; hh < 6; hh++)
            rp4[((size_t)ech * 24 + b * 12 + h0 + hh) * 512 + tv] = acc[b][hh];
}

__global__ __launch_bounds__(256) void r_reduce_kernel(
    const float* __restrict__ rp, float* __restrict__ r, float* __restrict__ rmax) {
    int bh = blockIdx.x, tid = threadIdx.x;
    const f32x4* rp4 = (const f32x4*)rp;
    f32x4* r4 = (f32x4*)r;
    float mloc = -INFINITY;
#pragma unroll
    for (int seg = 0; seg < 2; seg++) {
        int tv = seg * 256 + tid;
        f32x4 s = {};
#pragma unroll 8
        for (int ech = 0; ech < 48; ech++)
            s += rp4[((size_t)ech * 24 + bh) * 512 + tv];
        s *= 0.125f;
        r4[(size_t)bh * 512 + tv] = s;
        mloc = fmaxf(mloc, fmaxf(fmaxf(s[0], s[1]), fmaxf(s[2], s[3])));
    }
    __shared__ float sm[256];
    sm[tid] = mloc; __syncthreads();
    for (int s = 128; s > 0; s >>= 1) {
        if (tid < s) sm[tid] = fmaxf(sm[tid], sm[tid + s]);
        __syncthreads();
    }
    if (tid == 0) rmax[bh] = sm[0];
}

// ---------------------------------------------------------------- rr attention = chunked prefix scan
__global__ __launch_bounds__(64) void scan_part_kernel(
    const float* __restrict__ r, const float* __restrict__ rmax,
    const u16* __restrict__ vb, float* __restrict__ Sv, float* __restrict__ Sl) {
    int c = blockIdx.x, bh = blockIdx.y, d = threadIdx.x;
    float mx = rmax[bh];
    const float* rp = r + (size_t)bh * TT + c * 128;
    const u16* vp = vb + ((size_t)bh * TT + c * 128) * DD + d;
    float accv = 0.f, accl = 0.f;
#pragma unroll 4
    for (int j = 0; j < 128; j++) {
        float w = __expf(rp[j] - mx);
        accv += w * bf2f(vp[(size_t)j * DD]);
        accl += w;
    }
    Sv[((size_t)bh * SCH + c) * DD + d] = accv;
    if (d == 0) Sl[bh * SCH + c] = accl;
}

__global__ __launch_bounds__(64) void scan_out_kernel(
    const float* __restrict__ r, const float* __restrict__ rmax,
    const u16* __restrict__ vb, const float* __restrict__ Sv, const float* __restrict__ Sl,
    u16* __restrict__ outr) {
    int c = blockIdx.x, bh = blockIdx.y, d = threadIdx.x;
    float mx = rmax[bh];
    float acc = 0.f, accl = 0.f;
    for (int cp = 0; cp < c; cp++) {
        acc += Sv[((size_t)bh * SCH + cp) * DD + d];
        accl += Sl[bh * SCH + cp];
    }
    const float* rp = r + (size_t)bh * TT + c * 128;
    const u16* vp = vb + ((size_t)bh * TT + c * 128) * DD + d;
    u16* op = outr + ((size_t)bh * TT + c * 128) * DD + d;
#pragma unroll 2
    for (int j = 0; j < 128; j++) {
        float w = __expf(rp[j] - mx);
        acc += w * bf2f(vp[(size_t)j * DD]);
        accl += w;
        op[(size_t)j * DD] = f2bf(acc * __builtin_amdgcn_rcpf(accl));
    }
}

// ---------------------------------------------------------------- content flash attention, split-K
// Swapped QK^T: S^T = mfma(K, Q) -> each lane owns ONE q row (q = qw0+lo, 16 scores).
// Softmax fully in-register (2 shfl per reduce). P^T B-frags assembled via cvt_pk + shfl.
// PV: O^T = mfma(V^T, P^T) -> lane owns q = lo, d = jd*16+hi*4+r.
__global__ __launch_bounds__(256) void flash_kernel(
    const u16* __restrict__ qb, const u16* __restrict__ kb,
    const u16* __restrict__ vt, u16* __restrict__ op,
    float* __restrict__ mb, float* __restrict__ lb) {
    __shared__ __align__(16) u16 Kt[64 * 64];
    __shared__ __align__(16) u16 Vt[64 * 64];
    int qt = blockIdx.x, sg = blockIdx.y, bh = blockIdx.z;
    int q0 = qt * 64;
    if (sg * KSEG > q0) return;                  // segment has no causal keys
    int ks0 = sg * KSEG;
    int kend = min(ks0 + KSEG, q0 + 64);
    int tid = threadIdx.x, w = tid >> 6, l = tid & 63;
    int lo = l & 15, hi = l >> 4;
    int qw0 = q0 + w * 16;
    const u16* qbase = qb + (size_t)bh * TT * DD;
    const u16* kbase = kb + (size_t)bh * TT * DD;
    const u16* vtb = vt + (size_t)bh * DD * TT;

    // Q as B-fragment: col=q=lo, k(d)=hi*8+e
    bf16x8 bQ0 = *(const bf16x8*)(qbase + (size_t)(qw0 + lo) * DD + hi * 8);
    bf16x8 bQ1 = *(const bf16x8*)(qbase + (size_t)(qw0 + lo) * DD + 32 + hi * 8);

    int myq = qw0 + lo;
    float m = -INFINITY, ls = 0.f;
    f32x4 o[4] = {};

    int sr = tid >> 3, g = tid & 7;
    for (int j0 = ks0; j0 < kend; j0 += KVB) {
        __syncthreads();
        *(bf16x8*)(Kt + swz(sr, g))      = *(const bf16x8*)(kbase + (size_t)(j0 + sr) * DD + g * 8);
        *(bf16x8*)(Kt + swz(sr + 32, g)) = *(const bf16x8*)(kbase + (size_t)(j0 + sr + 32) * DD + g * 8);
        *(bf16x8*)(Vt + swz(sr, g))      = *(const bf16x8*)(vtb + (size_t)sr * TT + j0 + g * 8);
        *(bf16x8*)(Vt + swz(sr + 32, g)) = *(const bf16x8*)(vtb + (size_t)(sr + 32) * TT + j0 + g * 8);
        __syncthreads();
        if (j0 > qw0 + 15) continue;             // entire chunk above this wave's rows

        // S^T tiles: s[jj][r] = score(q=myq, k=j0+jj*16+hi*4+r)
        f32x4 s[4] = {};
#pragma unroll
        for (int jj = 0; jj < 4; jj++) {
            int row = jj * 16 + lo;
            bf16x8 aK0 = *(const bf16x8*)(Kt + swz(row, hi));
            bf16x8 aK1 = *(const bf16x8*)(Kt + swz(row, 4 + hi));
            s[jj] = __builtin_amdgcn_mfma_f32_16x16x32_bf16(aK0, bQ0, s[jj], 0, 0, 0);
            s[jj] = __builtin_amdgcn_mfma_f32_16x16x32_bf16(aK1, bQ1, s[jj], 0, 0, 0);
        }
        if (j0 + 63 > qw0) {
#pragma unroll
            for (int jj = 0; jj < 4; jj++)
#pragma unroll
                for (int r = 0; r < 4; r++)
                    if (j0 + jj * 16 + hi * 4 + r > myq) s[jj][r] = -INFINITY;
        }
        // row max (lane-local 16 + 2 shfl across hi)
        float tm = -INFINITY;
#pragma unroll
        for (int jj = 0; jj < 4; jj++)
#pragma unroll
            for (int r = 0; r < 4; r++) tm = fmaxf(tm, s[jj][r]);
        tm = fmaxf(tm, __shfl_xor(tm, 16, 64));
        tm = fmaxf(tm, __shfl_xor(tm, 32, 64));
        float mn = fmaxf(m, tm);
        float f = __expf(m - mn);
        m = mn;
        float rs = 0.f;
#pragma unroll
        for (int jj = 0; jj < 4; jj++)
#pragma unroll
            for (int r = 0; r < 4; r++) {
                s[jj][r] = __expf(s[jj][r] - mn);
                rs += s[jj][r];
            }
        rs += __shfl_xor(rs, 16, 64);
        rs += __shfl_xor(rs, 32, 64);
        ls = ls * f + rs;
#pragma unroll
        for (int jd = 0; jd < 4; jd++)
#pragma unroll
            for (int r = 0; r < 4; r++) o[jd][r] *= f;

        // pack P to bf16 pairs: pw[jj][w2] covers k = j0 + jj*16 + hi*4 + 2*w2 + {0,1}
        unsigned pw[4][2];
#pragma unroll
        for (int jj = 0; jj < 4; jj++) {
            pw[jj][0] = cvtpk(s[jj][0], s[jj][1]);
            pw[jj][1] = cvtpk(s[jj][2], s[jj][3]);
        }
        // assemble P^T B-frags (col=q=lo, k=kk*32+hi*8+e) and do PV
#pragma unroll
        for (int kk = 0; kk < 2; kk++) {
            union { unsigned u[4]; bf16x8 v; } bp;
#pragma unroll
            for (int wd = 0; wd < 4; wd++) {
                int src = lo + 16 * (((hi & 1) << 1) | (wd >> 1));
                unsigned va = (unsigned)__shfl((int)pw[kk * 2][wd & 1], src, 64);
                unsigned vb2 = (unsigned)__shfl((int)pw[kk * 2 + 1][wd & 1], src, 64);
                bp.u[wd] = (hi >> 1) ? vb2 : va;
            }
#pragma unroll
            for (int jd = 0; jd < 4; jd++) {
                bf16x8 aV = *(const bf16x8*)(Vt + swz(jd * 16 + lo, kk * 4 + hi));
                o[jd] = __builtin_amdgcn_mfma_f32_16x16x32_bf16(aV, bp.v, o[jd], 0, 0, 0);
            }
        }
    }
    size_t pb = (size_t)(bh * 4 + sg) * TT;
    float inv = 1.f / ls;
#pragma unroll
    for (int jd = 0; jd < 4; jd++) {
        u16x4 pk4;
#pragma unroll
        for (int r = 0; r < 4; r++) pk4[r] = f2bf(o[jd][r] * inv);
        *(u16x4*)(op + (pb + myq) * DD + jd * 16 + hi * 4) = pk4;
    }
    if (hi == 0) {
        mb[pb + myq] = m;
        lb[pb + myq] = ls;
    }
}

// per-(bh,t): merge weights across segments
__global__ __launch_bounds__(256) void weights_kernel(
    const float* __restrict__ mb, const float* __restrict__ lb, float* __restrict__ wgt) {
    int bh = blockIdx.x;
#pragma unroll
    for (int k = 0; k < TT / 256; k++) {
        int t = k * 256 + threadIdx.x;
        int ns = (t >> 9) + 1;
        size_t base = (size_t)bh * 4 * TT + t;
        float M = -INFINITY;
        for (int s = 0; s < ns; s++) M = fmaxf(M, mb[base + (size_t)s * TT]);
        float e[4], L = 0.f;
        for (int s = 0; s < ns; s++) {
            e[s] = lb[base + (size_t)s * TT] * __expf(mb[base + (size_t)s * TT] - M);
            L += e[s];
        }
        float inv = 1.f / L;
        for (int s = 0; s < ns; s++) wgt[base + (size_t)s * TT] = e[s] * inv;
    }
}

// merge partials + combine with rr branch -> comb (B,T,H*D) bf16
__global__ void merge_kernel(const u16* __restrict__ op, const float* __restrict__ wgt,
                             const u16* __restrict__ outr, const float* __restrict__ alpha,
                             u16* __restrict__ comb) {
    int i8 = blockIdx.x * blockDim.x + threadIdx.x;
    if (i8 >= M4 * EE / 8) return;
    int bt = i8 / (EE / 8), c8 = i8 - bt * (EE / 8);
    int h = c8 >> 3, d8 = c8 & 7;
    int b = bt >> 11, t = bt & 2047;
    int bh = b * HH + h;
    int ns = (t >> 9) + 1;
    float acc[8] = {};
    for (int s = 0; s < ns; s++) {
        size_t row = (size_t)(bh * 4 + s) * TT + t;
        float wv = wgt[row];
        union { u16 u[8]; bf16x8 v; } pv;
        pv.v = *(const bf16x8*)(op + row * DD + d8 * 8);
#pragma unroll
        for (int e = 0; e < 8; e++) acc[e] += wv * bf2f(pv.u[e]);
    }
    float a = 1.f / (1.f + __expf(-alpha[h]));
    union { u16 u[8]; bf16x8 v; } vr, vo;
    vr.v = *(const bf16x8*)(outr + (((size_t)bh * TT + t) * DD + d8 * 8));
#pragma unroll
    for (int e = 0; e < 8; e++)
        vo.u[e] = f2bf(a * bf2f(vr.u[e]) + (1.f - a) * acc[e]);
    ((bf16x8*)comb)[i8] = vo.v;
}

// ---------------------------------------------------------------- output GEMM (m97 structure)
__global__ __launch_bounds__(256) void gemm_out_kernel(const u16* __restrict__ A,
                                                       const u16* __restrict__ Bt,
                                                       float* __restrict__ C) {
    __shared__ __align__(16) u16 As[128 * 32];
    __shared__ __align__(16) u16 Bs[128 * 32];
    const int K = EE;
    int tid = threadIdx.x;
    int w = tid >> 6, l = tid & 63;
    int lo = l & 15, hi = l >> 4;
    int wm = w >> 1, wn = w & 1;
    int m0 = blockIdx.x * 128;
    int n0 = blockIdx.y * 128;
    int srow = l >> 2, sgrp = l & 3;

    f32x4 acc[4][4] = {};
    for (int k0 = 0; k0 < K; k0 += 32) {
        __syncthreads();
        gld_lds16(A + (size_t)(m0 + w * 16 + srow) * K + k0 + sgrp * 8,       As + w * 512);
        gld_lds16(A + (size_t)(m0 + (w + 4) * 16 + srow) * K + k0 + sgrp * 8, As + (w + 4) * 512);
        gld_lds16(Bt + (size_t)(n0 + w * 16 + srow) * K + k0 + sgrp * 8,       Bs + w * 512);
        gld_lds16(Bt + (size_t)(n0 + (w + 4) * 16 + srow) * K + k0 + sgrp * 8, Bs + (w + 4) * 512);
        __syncthreads();
        bf16x8 af[4], bfr[4];
#pragma unroll
        for (int i = 0; i < 4; i++)
            af[i] = *(const bf16x8*)(As + (wm * 64 + i * 16 + lo) * 32 + hi * 8);
#pragma unroll
        for (int j = 0; j < 4; j++)
            bfr[j] = *(const bf16x8*)(Bs + (wn * 64 + j * 16 + lo) * 32 + hi * 8);
#pragma unroll
        for (int i = 0; i < 4; i++)
#pragma unroll
            for (int j = 0; j < 4; j++)
                acc[i][j] = __builtin_amdgcn_mfma_f32_16x16x32_bf16(af[i], bfr[j], acc[i][j], 0, 0, 0);
    }
#pragma unroll
    for (int i = 0; i < 4; i++)
#pragma unroll
        for (int j = 0; j < 4; j++)
#pragma unroll
            for (int r = 0; r < 4; r++) {
                int m = m0 + wm * 64 + i * 16 + hi * 4 + r;
                int n = n0 + wn * 64 + j * 16 + lo;
                C[(size_t)m * EE + n] = acc[i][j][r];
            }
}

// ----------------------------------------------------------------
extern "C" void kernel_launch(void* const* d_in, const int* in_sizes, int n_in,
                              void* d_out, int out_size, void* d_ws, size_t ws_size,
                              hipStream_t stream) {
    const float* x = (const float*)d_in[0];
    const float* wq = (const float*)d_in[1];
    const float* wk = (const float*)d_in[2];
    const float* wv = (const float*)d_in[3];
    const float* wr = (const float*)d_in[4];
    const float* alpha = (const float*)d_in[5];
    const float* wo = (const float*)d_in[6];
    float* out = (float*)d_out;

    char* ws = (char*)d_ws;
    size_t off = 0;
    auto carve = [&](size_t bytes) -> char* {
        char* p = ws + off;
        off += (bytes + 255) & ~(size_t)255;
        return p;
    };
    u16* xb    = (u16*)carve((size_t)M4 * EE * 2);
    u16* wqkvt = (u16*)carve((size_t)NQKV * EE * 2);
    u16* wot   = (u16*)carve((size_t)EE * EE * 2);
    u16* qb    = (u16*)carve((size_t)BH * TT * DD * 2);
    u16* kb    = (u16*)carve((size_t)BH * TT * DD * 2);
    u16* vb    = (u16*)carve((size_t)BH * TT * DD * 2);
    u16* vt    = (u16*)carve((size_t)BH * TT * DD * 2);
    float* xt   = (float*)carve((size_t)BB * EE * TT * 4);
    float* rpbuf= (float*)carve((size_t)48 * BH * TT * 4);
    float* rbuf = (float*)carve((size_t)BH * TT * 4);
    float* rmx  = (float*)carve((size_t)BH * 4);
    float* Sv   = (float*)carve((size_t)BH * SCH * DD * 4);
    float* Sl   = (float*)carve((size_t)BH * SCH * 4);
    u16* outr  = (u16*)carve((size_t)BH * TT * DD * 2);
    u16* opart = (u16*)carve((size_t)BH * 4 * TT * DD * 2);
    float* mbuf = (float*)carve((size_t)BH * 4 * TT * 4);
    float* lbuf = (float*)carve((size_t)BH * 4 * TT * 4);
    float* wgt  = (float*)carve((size_t)BH * 4 * TT * 4);
    u16* comb  = (u16*)carve((size_t)M4 * EE * 2);

    transpose_x_kernel<<<dim3(TT / 32, EE / 32, BB), 256, 0, stream>>>(x, xt, xb);
    transpose_w_kernel<<<dim3(EE / 32, EE / 32, 4), 256, 0, stream>>>(wq, wk, wv, wo, wqkvt, wot);

    dim3 gq(M4 / 128, NQKV / 128);
    gemm_qkv_kernel<<<gq, 256, 0, stream>>>(xb, wqkvt, qb, kb, vb);
    transpose_v_kernel<<<dim3(TT / 64, BH), 256, 0, stream>>>(vb, vt);

    r_partial_kernel<<<dim3(48, 2, 2), 256, 0, stream>>>(xt, wr, rpbuf);
    r_reduce_kernel<<<BH, 256, 0, stream>>>(rpbuf, rbuf, rmx);

    scan_part_kernel<<<dim3(SCH, BH), 64, 0, stream>>>(rbuf, rmx, vb, Sv, Sl);
    scan_out_kernel<<<dim3(SCH, BH), 64, 0, stream>>>(rbuf, rmx, vb, Sv, Sl, outr);

    flash_kernel<<<dim3(TT / 64, 4, BH), 256, 0, stream>>>(qb, kb, vt, opart, mbuf, lbuf);
    weights_kernel<<<BH, 256, 0, stream>>>(mbuf, lbuf, wgt);
    merge_kernel<<<(M4 * EE / 8 + 255) / 256, 256, 0, stream>>>(opart, wgt, outr, alpha, comb);

    dim3 go(M4 / 128, EE / 128);
    gemm_out_kernel<<<go, 256, 0, stream>>>(comb, wot, out);
}

// Round 7
// 178.106 us; speedup vs baseline: 4.2031x; 1.0749x over previous
//
#include <hip/hip_runtime.h>
#include <math.h>

typedef __bf16 bf16x8 __attribute__((ext_vector_type(8)));
typedef float f32x4 __attribute__((ext_vector_type(4)));
typedef float f32x16 __attribute__((ext_vector_type(16)));
typedef unsigned short u16;
typedef unsigned short u16x4 __attribute__((ext_vector_type(4)));

#define BB 2
#define TT 2048
#define EE 768
#define HH 12
#define DD 64
#define BH (BB*HH)      /* 24 */
#define M4 (BB*TT)      /* 4096 */
#define NQKV (3*EE)     /* 2304 */
#define SCH 16          /* scan chunks (128 t each) */
#define KSEG 512        /* flash split-K segment */
#define KVB 64
#define QBLK 128

__device__ __forceinline__ u16 f2bf(float f) {
    union { float f; unsigned u; } v; v.f = f;
    unsigned r = v.u + 0x7FFFu + ((v.u >> 16) & 1u);
    return (u16)(r >> 16);
}
__device__ __forceinline__ float bf2f(u16 u) {
    union { unsigned u; float f; } v; v.u = ((unsigned)u) << 16;
    return v.f;
}
// 2^x via the trans pipe directly
__device__ __forceinline__ float fexp2(float x) {
    float r;
    asm("v_exp_f32 %0, %1" : "=v"(r) : "v"(x));
    return r;
}
// pack two f32 -> u32 of 2 bf16 (lo = a, hi = b), RTNE
__device__ __forceinline__ unsigned cvtpk(float a, float b) {
    unsigned r;
    asm("v_cvt_pk_bf16_f32 %0, %1, %2" : "=v"(r) : "v"(a), "v"(b));
    return r;
}
// u16 index of 8-elem group `grp` in row `row` of a [*,64] u16 LDS tile, XOR-swizzled
__device__ __forceinline__ int swz(int row, int grp) {
    return row * 64 + ((grp ^ (row & 7)) << 3);
}
// async global->LDS, 16B per lane; lds base must be wave-uniform
__device__ __forceinline__ void gld_lds16(const u16* g, u16* l) {
    __builtin_amdgcn_global_load_lds(
        (const __attribute__((address_space(1))) unsigned int*)(const void*)g,
        (__attribute__((address_space(3))) unsigned int*)(void*)l,
        16, 0, 0);
}

// ---------------------------------------------------------------- x: transpose (f32) + straight cast (bf16)
__global__ __launch_bounds__(256) void transpose_x_kernel(
    const float* __restrict__ x, float* __restrict__ xt, u16* __restrict__ xb) {
    __shared__ float tile[32][33];
    int t0 = blockIdx.x * 32, e0 = blockIdx.y * 32, b = blockIdx.z;
    int tx = threadIdx.x & 31, ty = threadIdx.x >> 5;
#pragma unroll
    for (int i = 0; i < 4; i++) {
        size_t idx = ((size_t)b * TT + t0 + ty + 8 * i) * EE + e0 + tx;
        float v = x[idx];
        tile[ty + 8 * i][tx] = v;
        xb[idx] = f2bf(v);
    }
    __syncthreads();
#pragma unroll
    for (int i = 0; i < 4; i++)
        xt[((size_t)b * EE + e0 + ty + 8 * i) * TT + t0 + tx] = tile[tx][ty + 8 * i];
}

// 4 weight transposes in one launch: z=0..2 -> wqkvt slabs, z=3 -> wot
__global__ __launch_bounds__(256) void transpose_w_kernel(
    const float* __restrict__ wq, const float* __restrict__ wk,
    const float* __restrict__ wv, const float* __restrict__ wo,
    u16* __restrict__ wqkvt, u16* __restrict__ wot) {
    __shared__ float tile[32][33];
    int z = blockIdx.z;
    const float* src = (z == 0) ? wq : (z == 1) ? wk : (z == 2) ? wv : wo;
    u16* dst = (z < 3) ? (wqkvt + (size_t)z * EE * EE) : wot;
    int n0 = blockIdx.x * 32, k0 = blockIdx.y * 32;
    int tx = threadIdx.x & 31, ty = threadIdx.x >> 5;
#pragma unroll
    for (int i = 0; i < 4; i++)
        tile[ty + 8 * i][tx] = src[(size_t)(k0 + ty + 8 * i) * EE + n0 + tx];
    __syncthreads();
#pragma unroll
    for (int i = 0; i < 4; i++)
        dst[(size_t)(n0 + ty + 8 * i) * EE + k0 + tx] = f2bf(tile[tx][ty + 8 * i]);
}

// vt[bh][d][j] = vb[bh][j][d]  (bf16, LDS-tiled 64x64)
__global__ __launch_bounds__(256) void transpose_v_kernel(
    const u16* __restrict__ vb, u16* __restrict__ vt) {
    __shared__ u16 tile[64][66];
    int j0 = blockIdx.x * 64, bh = blockIdx.y;
    int tid = threadIdx.x;
#pragma unroll
    for (int i = 0; i < 16; i++) {
        int idx = i * 256 + tid;
        int j = idx >> 6, d = idx & 63;
        tile[j][d] = vb[((size_t)bh * TT + j0 + j) * DD + d];
    }
    __syncthreads();
#pragma unroll
    for (int i = 0; i < 16; i++) {
        int idx = i * 256 + tid;
        int d = idx >> 6, j = idx & 63;
        vt[((size_t)bh * DD + d) * TT + j0 + j] = tile[j][d];
    }
}

// ---------------------------------------------------------------- QKV GEMM (m97 structure)
__global__ __launch_bounds__(256) void gemm_qkv_kernel(
    const u16* __restrict__ A, const u16* __restrict__ Bt,
    u16* __restrict__ qb, u16* __restrict__ kb, u16* __restrict__ vb)
{
    __shared__ __align__(16) u16 As[128 * 32];
    __shared__ __align__(16) u16 Bs[128 * 32];
    const int K = EE;
    int tid = threadIdx.x;
    int w = tid >> 6, l = tid & 63;
    int lo = l & 15, hi = l >> 4;
    int wm = w >> 1, wn = w & 1;
    int m0 = blockIdx.x * 128;
    int n0 = blockIdx.y * 128;
    int srow = l >> 2, sgrp = l & 3;

    f32x4 acc[4][4] = {};
    for (int k0 = 0; k0 < K; k0 += 32) {
        __syncthreads();
        gld_lds16(A + (size_t)(m0 + w * 16 + srow) * K + k0 + sgrp * 8,       As + w * 512);
        gld_lds16(A + (size_t)(m0 + (w + 4) * 16 + srow) * K + k0 + sgrp * 8, As + (w + 4) * 512);
        gld_lds16(Bt + (size_t)(n0 + w * 16 + srow) * K + k0 + sgrp * 8,       Bs + w * 512);
        gld_lds16(Bt + (size_t)(n0 + (w + 4) * 16 + srow) * K + k0 + sgrp * 8, Bs + (w + 4) * 512);
        __syncthreads();
        bf16x8 af[4], bfr[4];
#pragma unroll
        for (int i = 0; i < 4; i++)
            af[i] = *(const bf16x8*)(As + (wm * 64 + i * 16 + lo) * 32 + hi * 8);
#pragma unroll
        for (int j = 0; j < 4; j++)
            bfr[j] = *(const bf16x8*)(Bs + (wn * 64 + j * 16 + lo) * 32 + hi * 8);
#pragma unroll
        for (int i = 0; i < 4; i++)
#pragma unroll
            for (int j = 0; j < 4; j++)
                acc[i][j] = __builtin_amdgcn_mfma_f32_16x16x32_bf16(af[i], bfr[j], acc[i][j], 0, 0, 0);
    }
    int sel = n0 / EE;
    int rem0 = n0 - sel * EE;
    u16* dst = (sel == 0) ? qb : (sel == 1) ? kb : vb;
    // q pre-scaled by 1/sqrt(D) * log2(e) so flash can use exp2 directly
    float mul = (sel == 0) ? 0.125f * 1.44269504f : 1.f;
#pragma unroll
    for (int j = 0; j < 4; j++) {
        int h = (rem0 + wn * 64 + j * 16) >> 6;
        int d = (wn * 64 + j * 16 + lo) & 63;
#pragma unroll
        for (int i = 0; i < 4; i++)
#pragma unroll
            for (int r = 0; r < 4; r++) {
                int m = m0 + wm * 64 + i * 16 + hi * 4 + r;
                int b = m >> 11, t = m & 2047;
                dst[((size_t)(b * HH + h) * TT + t) * DD + d] = f2bf(acc[i][j][r] * mul);
            }
    }
}

// ---------------------------------------------------------------- r = scale * x . wr
__global__ __launch_bounds__(256) void r_partial_kernel(
    const float* __restrict__ xt, const float* __restrict__ wr, float* __restrict__ rp) {
    int ech = blockIdx.x;           // 0..47
    int tch = blockIdx.y;           // 0..1
    int hg = blockIdx.z;            // 0..1
    int e0 = ech * 16, h0 = hg * 6;
    int tv = tch * 256 + threadIdx.x;
    const f32x4* xt4 = (const f32x4*)xt;
    const f32x4* wr4 = (const f32x4*)wr;
    f32x4 acc[2][6] = {};
#pragma unroll 4
    for (int e = 0; e < 16; e++) {
        f32x4 x0 = xt4[(size_t)(e0 + e) * 512 + tv];
        f32x4 x1 = xt4[(size_t)(EE + e0 + e) * 512 + tv];
#pragma unroll
        for (int hh = 0; hh < 6; hh++) {
            f32x4 w = wr4[((size_t)(h0 + hh) * EE + e0 + e) * 512 + tv];
            acc[0][hh] += w * x0;
            acc[1][hh] += w * x1;
        }
    }
    f32x4* rp4 = (f32x4*)rp;
#pragma unroll
    for (int b = 0; b < 2; b++)
#pragma unroll
        for (int hh = 0; hh < 6; hh++)
            rp4[((size_t)ech * 24 + b * 12 + h0 + hh) * 512 + tv] = acc[b][hh];
}

__global__ __launch_bounds__(256) void r_reduce_kernel(
    const float* __restrict__ rp, float* __restrict__ r, float* __restrict__ rmax) {
    int bh = blockIdx.x, tid = threadIdx.x;
    const f32x4* rp4 = (const f32x4*)rp;
    f32x4* r4 = (f32x4*)r;
    float mloc = -INFINITY;
#pragma unroll
    for (int seg = 0; seg < 2; seg++) {
        int tv = seg * 256 + tid;
        f32x4 s = {};
#pragma unroll 8
        for (int ech = 0; ech < 48; ech++)
            s += rp4[((size_t)ech * 24 + bh) * 512 + tv];
        s *= 0.125f;
        r4[(size_t)bh * 512 + tv] = s;
        mloc = fmaxf(mloc, fmaxf(fmaxf(s[0], s[1]), fmaxf(s[2], s[3])));
    }
    __shared__ float sm[256];
    sm[tid] = mloc; __syncthreads();
    for (int s = 128; s > 0; s >>= 1) {
        if (tid < s) sm[tid] = fmaxf(sm[tid], sm[tid + s]);
        __syncthreads();
    }
    if (tid == 0) rmax[bh] = sm[0];
}

// ---------------------------------------------------------------- rr attention = chunked prefix scan
__global__ __launch_bounds__(64) void scan_part_kernel(
    const float* __restrict__ r, const float* __restrict__ rmax,
    const u16* __restrict__ vb, float* __restrict__ Sv, float* __restrict__ Sl) {
    int c = blockIdx.x, bh = blockIdx.y, d = threadIdx.x;
    float mx = rmax[bh];
    const float* rp = r + (size_t)bh * TT + c * 128;
    const u16* vp = vb + ((size_t)bh * TT + c * 128) * DD + d;
    float accv = 0.f, accl = 0.f;
#pragma unroll 4
    for (int j = 0; j < 128; j++) {
        float w = __expf(rp[j] - mx);
        accv += w * bf2f(vp[(size_t)j * DD]);
        accl += w;
    }
    Sv[((size_t)bh * SCH + c) * DD + d] = accv;
    if (d == 0) Sl[bh * SCH + c] = accl;
}

__global__ __launch_bounds__(64) void scan_out_kernel(
    const float* __restrict__ r, const float* __restrict__ rmax,
    const u16* __restrict__ vb, const float* __restrict__ Sv, const float* __restrict__ Sl,
    u16* __restrict__ outr) {
    int c = blockIdx.x, bh = blockIdx.y, d = threadIdx.x;
    float mx = rmax[bh];
    float acc = 0.f, accl = 0.f;
    for (int cp = 0; cp < c; cp++) {
        acc += Sv[((size_t)bh * SCH + cp) * DD + d];
        accl += Sl[bh * SCH + cp];
    }
    const float* rp = r + (size_t)bh * TT + c * 128;
    const u16* vp = vb + ((size_t)bh * TT + c * 128) * DD + d;
    u16* op = outr + ((size_t)bh * TT + c * 128) * DD + d;
#pragma unroll 2
    for (int j = 0; j < 128; j++) {
        float w = __expf(rp[j] - mx);
        acc += w * bf2f(vp[(size_t)j * DD]);
        accl += w;
        op[(size_t)j * DD] = f2bf(acc * __builtin_amdgcn_rcpf(accl));
    }
}

// ---------------------------------------------------------------- content flash attention, split-K, 32x32 MFMA
// S^T = mfma32(K, Q): lane owns q = qw0 + (l&31); 32 scores split across hb = l>>5 halves.
// Softmax in-register (1 shfl per reduce). P^T B-frags via cvt_pk + permlane32_swap.
// PV: O^T = mfma32(V^T, P^T): lane owns q, d = dt*32 + (reg&3)+8*(reg>>2)+4*hb.
__global__ __launch_bounds__(256) void flash_kernel(
    const u16* __restrict__ qb, const u16* __restrict__ kb,
    const u16* __restrict__ vt, u16* __restrict__ op,
    float* __restrict__ mb, float* __restrict__ lb) {
    __shared__ __align__(16) u16 Kt[64 * 64];
    __shared__ __align__(16) u16 Vt[64 * 64];
    int qt = (int)gridDim.x - 1 - (int)blockIdx.x;   // heavy tiles first
    int sg = blockIdx.y, bh = blockIdx.z;
    int q0 = qt * QBLK;
    int ks0 = sg * KSEG;
    if (ks0 > q0) return;                   // segment has no causal keys for this tile
    int kend = min(ks0 + KSEG, q0 + QBLK);
    int tid = threadIdx.x, w = tid >> 6, l = tid & 63;
    int q31 = l & 31, hb = l >> 5;
    int qw0 = q0 + w * 32;
    int myq = qw0 + q31;
    const u16* qbase = qb + (size_t)bh * TT * DD;
    const u16* kbase = kb + (size_t)bh * TT * DD;
    const u16* vtb = vt + (size_t)bh * DD * TT;

    // Q B-frags: col=q, k(d) = mm*16 + hb*8 + e
    bf16x8 bQ[4];
#pragma unroll
    for (int mm = 0; mm < 4; mm++)
        bQ[mm] = *(const bf16x8*)(qbase + (size_t)myq * DD + mm * 16 + hb * 8);

    float m_ = -INFINITY, ls = 0.f;
    f32x16 o[2] = {};

    int sr = tid >> 3, g = tid & 7;
    for (int j0 = ks0; j0 < kend; j0 += KVB) {
        __syncthreads();
        *(bf16x8*)(Kt + swz(sr, g))      = *(const bf16x8*)(kbase + (size_t)(j0 + sr) * DD + g * 8);
        *(bf16x8*)(Kt + swz(sr + 32, g)) = *(const bf16x8*)(kbase + (size_t)(j0 + sr + 32) * DD + g * 8);
        *(bf16x8*)(Vt + swz(sr, g))      = *(const bf16x8*)(vtb + (size_t)sr * TT + j0 + g * 8);
        *(bf16x8*)(Vt + swz(sr + 32, g)) = *(const bf16x8*)(vtb + (size_t)(sr + 32) * TT + j0 + g * 8);
        __syncthreads();
        if (j0 > qw0 + 31) continue;        // chunk entirely above this wave's rows

        // S^T: s[kt][reg] = score(q=myq, k = j0 + kt*32 + (reg&3)+8*(reg>>2)+4*hb)
        f32x16 s[2] = {};
#pragma unroll
        for (int kt = 0; kt < 2; kt++)
#pragma unroll
            for (int mm = 0; mm < 4; mm++) {
                bf16x8 aK = *(const bf16x8*)(Kt + swz(kt * 32 + q31, mm * 2 + hb));
                s[kt] = __builtin_amdgcn_mfma_f32_32x32x16_bf16(aK, bQ[mm], s[kt], 0, 0, 0);
            }
        if (j0 + 63 > qw0) {
#pragma unroll
            for (int kt = 0; kt < 2; kt++)
#pragma unroll
                for (int reg = 0; reg < 16; reg++) {
                    int k = j0 + kt * 32 + (reg & 3) + 8 * (reg >> 2) + 4 * hb;
                    if (k > myq) s[kt][reg] = -INFINITY;
                }
        }
        float tm = -INFINITY;
#pragma unroll
        for (int kt = 0; kt < 2; kt++)
#pragma unroll
            for (int reg = 0; reg < 16; reg++) tm = fmaxf(tm, s[kt][reg]);
        tm = fmaxf(tm, __shfl_xor(tm, 32, 64));
        float mn = fmaxf(m_, tm);
        float f = fexp2(m_ - mn);
        m_ = mn;
        float rs = 0.f;
#pragma unroll
        for (int kt = 0; kt < 2; kt++)
#pragma unroll
            for (int reg = 0; reg < 16; reg++) {
                s[kt][reg] = fexp2(s[kt][reg] - mn);
                rs += s[kt][reg];
            }
        rs += __shfl_xor(rs, 32, 64);
        ls = ls * f + rs;
#pragma unroll
        for (int dt = 0; dt < 2; dt++)
#pragma unroll
            for (int reg = 0; reg < 16; reg++) o[dt][reg] *= f;

        // P^T B-frags + PV
#pragma unroll
        for (int kt = 0; kt < 2; kt++) {
            unsigned W[4][2];
#pragma unroll
            for (int g4 = 0; g4 < 4; g4++) {
                W[g4][0] = cvtpk(s[kt][4 * g4], s[kt][4 * g4 + 1]);
                W[g4][1] = cvtpk(s[kt][4 * g4 + 2], s[kt][4 * g4 + 3]);
            }
#pragma unroll
            for (int f2 = 0; f2 < 2; f2++) {
                unsigned a0 = W[2 * f2][0], b0 = W[2 * f2 + 1][0];
                unsigned a1 = W[2 * f2][1], b1 = W[2 * f2 + 1][1];
                asm volatile("v_permlane32_swap_b32 %0, %1" : "+v"(a0), "+v"(b0));
                asm volatile("v_permlane32_swap_b32 %0, %1" : "+v"(a1), "+v"(b1));
                union { unsigned u[4]; bf16x8 v; } bp;
                bp.u[0] = a0; bp.u[1] = a1; bp.u[2] = b0; bp.u[3] = b1;
#pragma unroll
                for (int dt = 0; dt < 2; dt++) {
                    bf16x8 aV = *(const bf16x8*)(Vt + swz(dt * 32 + q31, kt * 4 + f2 * 2 + hb));
                    o[dt] = __builtin_amdgcn_mfma_f32_32x32x16_bf16(aV, bp.v, o[dt], 0, 0, 0);
                }
            }
        }
    }
    size_t pb = (size_t)(bh * 4 + sg) * TT;
    float inv = 1.f / ls;
#pragma unroll
    for (int dt = 0; dt < 2; dt++)
#pragma unroll
        for (int g4 = 0; g4 < 4; g4++) {
            u16x4 pk4;
#pragma unroll
            for (int c = 0; c < 4; c++) pk4[c] = f2bf(o[dt][4 * g4 + c] * inv);
            *(u16x4*)(op + (pb + myq) * DD + dt * 32 + 8 * g4 + 4 * hb) = pk4;
        }
    if (hb == 0) {
        mb[pb + myq] = m_;
        lb[pb + myq] = ls;
    }
}

// per-(bh,t): merge weights across segments (m is in base-2 domain)
__global__ __launch_bounds__(256) void weights_kernel(
    const float* __restrict__ mb, const float* __restrict__ lb, float* __restrict__ wgt) {
    int bh = blockIdx.x;
#pragma unroll
    for (int k = 0; k < TT / 256; k++) {
        int t = k * 256 + threadIdx.x;
        int ns = (t >> 9) + 1;
        size_t base = (size_t)bh * 4 * TT + t;
        float M = -INFINITY;
        for (int s = 0; s < ns; s++) M = fmaxf(M, mb[base + (size_t)s * TT]);
        float e[4], L = 0.f;
        for (int s = 0; s < ns; s++) {
            e[s] = lb[base + (size_t)s * TT] * fexp2(mb[base + (size_t)s * TT] - M);
            L += e[s];
        }
        float inv = 1.f / L;
        for (int s = 0; s < ns; s++) wgt[base + (size_t)s * TT] = e[s] * inv;
    }
}

// merge partials + combine with rr branch -> comb (B,T,H*D) bf16
__global__ void merge_kernel(const u16* __restrict__ op, const float* __restrict__ wgt,
                             const u16* __restrict__ outr, const float* __restrict__ alpha,
                             u16* __restrict__ comb) {
    int i8 = blockIdx.x * blockDim.x + threadIdx.x;
    if (i8 >= M4 * EE / 8) return;
    int bt = i8 / (EE / 8), c8 = i8 - bt * (EE / 8);
    int h = c8 >> 3, d8 = c8 & 7;
    int b = bt >> 11, t = bt & 2047;
    int bh = b * HH + h;
    int ns = (t >> 9) + 1;
    float acc[8] = {};
    for (int s = 0; s < ns; s++) {
        size_t row = (size_t)(bh * 4 + s) * TT + t;
        float wv = wgt[row];
        union { u16 u[8]; bf16x8 v; } pv;
        pv.v = *(const bf16x8*)(op + row * DD + d8 * 8);
#pragma unroll
        for (int e = 0; e < 8; e++) acc[e] += wv * bf2f(pv.u[e]);
    }
    float a = 1.f / (1.f + __expf(-alpha[h]));
    union { u16 u[8]; bf16x8 v; } vr, vo;
    vr.v = *(const bf16x8*)(outr + (((size_t)bh * TT + t) * DD + d8 * 8));
#pragma unroll
    for (int e = 0; e < 8; e++)
        vo.u[e] = f2bf(a * bf2f(vr.u[e]) + (1.f - a) * acc[e]);
    ((bf16x8*)comb)[i8] = vo.v;
}

// ---------------------------------------------------------------- output GEMM (m97 structure)
__global__ __launch_bounds__(256) void gemm_out_kernel(const u16* __restrict__ A,
                                                       const u16* __restrict__ Bt,
                                                       float* __restrict__ C) {
    __shared__ __align__(16) u16 As[128 * 32];
    __shared__ __align__(16) u16 Bs[128 * 32];
    const int K = EE;
    int tid = threadIdx.x;
    int w = tid >> 6, l = tid & 63;
    int lo = l & 15, hi = l >> 4;
    int wm = w >> 1, wn = w & 1;
    int m0 = blockIdx.x * 128;
    int n0 = blockIdx.y * 128;
    int srow = l >> 2, sgrp = l & 3;

    f32x4 acc[4][4] = {};
    for (int k0 = 0; k0 < K; k0 += 32) {
        __syncthreads();
        gld_lds16(A + (size_t)(m0 + w * 16 + srow) * K + k0 + sgrp * 8,       As + w * 512);
        gld_lds16(A + (size_t)(m0 + (w + 4) * 16 + srow) * K + k0 + sgrp * 8, As + (w + 4) * 512);
        gld_lds16(Bt + (size_t)(n0 + w * 16 + srow) * K + k0 + sgrp * 8,       Bs + w * 512);
        gld_lds16(Bt + (size_t)(n0 + (w + 4) * 16 + srow) * K + k0 + sgrp * 8, Bs + (w + 4) * 512);
        __syncthreads();
        bf16x8 af[4], bfr[4];
#pragma unroll
        for (int i = 0; i < 4; i++)
            af[i] = *(const bf16x8*)(As + (wm * 64 + i * 16 + lo) * 32 + hi * 8);
#pragma unroll
        for (int j = 0; j < 4; j++)
            bfr[j] = *(const bf16x8*)(Bs + (wn * 64 + j * 16 + lo) * 32 + hi * 8);
#pragma unroll
        for (int i = 0; i < 4; i++)
#pragma unroll
            for (int j = 0; j < 4; j++)
                acc[i][j] = __builtin_amdgcn_mfma_f32_16x16x32_bf16(af[i], bfr[j], acc[i][j], 0, 0, 0);
    }
#pragma unroll
    for (int i = 0; i < 4; i++)
#pragma unroll
        for (int j = 0; j < 4; j++)
#pragma unroll
            for (int r = 0; r < 4; r++) {
                int m = m0 + wm * 64 + i * 16 + hi * 4 + r;
                int n = n0 + wn * 64 + j * 16 + lo;
                C[(size_t)m * EE + n] = acc[i][j][r];
            }
}

// ----------------------------------------------------------------
extern "C" void kernel_launch(void* const* d_in, const int* in_sizes, int n_in,
                              void* d_out, int out_size, void* d_ws, size_t ws_size,
                              hipStream_t stream) {
    const float* x = (const float*)d_in[0];
    const float* wq = (const float*)d_in[1];
    const float* wk = (const float*)d_in[2];
    const float* wv = (const float*)d_in[3];
    const float* wr = (const float*)d_in[4];
    const float* alpha = (const float*)d_in[5];
    const float* wo = (const float*)d_in[6];
    float* out = (float*)d_out;

    char* ws = (char*)d_ws;
    size_t off = 0;
    auto carve = [&](size_t bytes) -> char* {
        char* p = ws + off;
        off += (bytes + 255) & ~(size_t)255;
        return p;
    };
    u16* xb    = (u16*)carve((size_t)M4 * EE * 2);
    u16* wqkvt = (u16*)carve((size_t)NQKV * EE * 2);
    u16* wot   = (u16*)carve((size_t)EE * EE * 2);
    u16* qb    = (u16*)carve((size_t)BH * TT * DD * 2);
    u16* kb    = (u16*)carve((size_t)BH * TT * DD * 2);
    u16* vb    = (u16*)carve((size_t)BH * TT * DD * 2);
    u16* vt    = (u16*)carve((size_t)BH * TT * DD * 2);
    float* xt   = (float*)carve((size_t)BB * EE * TT * 4);
    float* rpbuf= (float*)carve((size_t)48 * BH * TT * 4);
    float* rbuf = (float*)carve((size_t)BH * TT * 4);
    float* rmx  = (float*)carve((size_t)BH * 4);
    float* Sv   = (float*)carve((size_t)BH * SCH * DD * 4);
    float* Sl   = (float*)carve((size_t)BH * SCH * 4);
    u16* outr  = (u16*)carve((size_t)BH * TT * DD * 2);
    u16* opart = (u16*)carve((size_t)BH * 4 * TT * DD * 2);
    float* mbuf = (float*)carve((size_t)BH * 4 * TT * 4);
    float* lbuf = (float*)carve((size_t)BH * 4 * TT * 4);
    float* wgt  = (float*)carve((size_t)BH * 4 * TT * 4);
    u16* comb  = (u16*)carve((size_t)M4 * EE * 2);

    transpose_x_kernel<<<dim3(TT / 32, EE / 32, BB), 256, 0, stream>>>(x, xt, xb);
    transpose_w_kernel<<<dim3(EE / 32, EE / 32, 4), 256, 0, stream>>>(wq, wk, wv, wo, wqkvt, wot);

    dim3 gq(M4 / 128, NQKV / 128);
    gemm_qkv_kernel<<<gq, 256, 0, stream>>>(xb, wqkvt, qb, kb, vb);
    transpose_v_kernel<<<dim3(TT / 64, BH), 256, 0, stream>>>(vb, vt);

    r_partial_kernel<<<dim3(48, 2, 2), 256, 0, stream>>>(xt, wr, rpbuf);
    r_reduce_kernel<<<BH, 256, 0, stream>>>(rpbuf, rbuf, rmx);

    scan_part_kernel<<<dim3(SCH, BH), 64, 0, stream>>>(rbuf, rmx, vb, Sv, Sl);
    scan_out_kernel<<<dim3(SCH, BH), 64, 0, stream>>>(rbuf, rmx, vb, Sv, Sl, outr);

    flash_kernel<<<dim3(TT / QBLK, 4, BH), 256, 0, stream>>>(qb, kb, vt, opart, mbuf, lbuf);
    weights_kernel<<<BH, 256, 0, stream>>>(mbuf, lbuf, wgt);
    merge_kernel<<<(M4 * EE / 8 + 255) / 256, 256, 0, stream>>>(opart, wgt, outr, alpha, comb);

    dim3 go(M4 / 128, EE / 128);
    gemm_out_kernel<<<go, 256, 0, stream>>>(comb, wot, out);
}

// Round 8
// 162.003 us; speedup vs baseline: 4.6209x; 1.0994x over previous
//
#include <hip/hip_runtime.h>
#include <math.h>

typedef __bf16 bf16x8 __attribute__((ext_vector_type(8)));
typedef float f32x4 __attribute__((ext_vector_type(4)));
typedef float f32x16 __attribute__((ext_vector_type(16)));
typedef unsigned short u16;
typedef unsigned short u16x4 __attribute__((ext_vector_type(4)));

#define BB 2
#define TT 2048
#define EE 768
#define HH 12
#define DD 64
#define BH (BB*HH)      /* 24 */
#define M4 (BB*TT)      /* 4096 */
#define NQKV (3*EE)     /* 2304 */
#define SCH 16          /* scan chunks (128 t each) */
#define KSEG 512        /* flash split-K segment */
#define KVB 64
#define QBLK 128

__device__ __forceinline__ u16 f2bf(float f) {
    union { float f; unsigned u; } v; v.f = f;
    unsigned r = v.u + 0x7FFFu + ((v.u >> 16) & 1u);
    return (u16)(r >> 16);
}
__device__ __forceinline__ float bf2f(u16 u) {
    union { unsigned u; float f; } v; v.u = ((unsigned)u) << 16;
    return v.f;
}
// 2^x via the trans pipe directly
__device__ __forceinline__ float fexp2(float x) {
    float r;
    asm("v_exp_f32 %0, %1" : "=v"(r) : "v"(x));
    return r;
}
// pack two f32 -> u32 of 2 bf16 (lo = a, hi = b), RTNE
__device__ __forceinline__ unsigned cvtpk(float a, float b) {
    unsigned r;
    asm("v_cvt_pk_bf16_f32 %0, %1, %2" : "=v"(r) : "v"(a), "v"(b));
    return r;
}
// u16 index of 8-elem group `grp` in row `row` of a [*,64] u16 LDS tile, XOR-swizzled
__device__ __forceinline__ int swz(int row, int grp) {
    return row * 64 + ((grp ^ (row & 7)) << 3);
}
// async global->LDS, 16B per lane; lds base must be wave-uniform
__device__ __forceinline__ void gld_lds16(const u16* g, u16* l) {
    __builtin_amdgcn_global_load_lds(
        (const __attribute__((address_space(1))) unsigned int*)(const void*)g,
        (__attribute__((address_space(3))) unsigned int*)(void*)l,
        16, 0, 0);
}

// ---------------------------------------------------------------- x: transpose (f32) + straight cast (bf16)
__global__ __launch_bounds__(256) void transpose_x_kernel(
    const float* __restrict__ x, float* __restrict__ xt, u16* __restrict__ xb) {
    __shared__ float tile[32][33];
    int t0 = blockIdx.x * 32, e0 = blockIdx.y * 32, b = blockIdx.z;
    int tx = threadIdx.x & 31, ty = threadIdx.x >> 5;
#pragma unroll
    for (int i = 0; i < 4; i++) {
        size_t idx = ((size_t)b * TT + t0 + ty + 8 * i) * EE + e0 + tx;
        float v = x[idx];
        tile[ty + 8 * i][tx] = v;
        xb[idx] = f2bf(v);
    }
    __syncthreads();
#pragma unroll
    for (int i = 0; i < 4; i++)
        xt[((size_t)b * EE + e0 + ty + 8 * i) * TT + t0 + tx] = tile[tx][ty + 8 * i];
}

// 4 weight transposes in one launch: z=0..2 -> wqkvt slabs, z=3 -> wot
__global__ __launch_bounds__(256) void transpose_w_kernel(
    const float* __restrict__ wq, const float* __restrict__ wk,
    const float* __restrict__ wv, const float* __restrict__ wo,
    u16* __restrict__ wqkvt, u16* __restrict__ wot) {
    __shared__ float tile[32][33];
    int z = blockIdx.z;
    const float* src = (z == 0) ? wq : (z == 1) ? wk : (z == 2) ? wv : wo;
    u16* dst = (z < 3) ? (wqkvt + (size_t)z * EE * EE) : wot;
    int n0 = blockIdx.x * 32, k0 = blockIdx.y * 32;
    int tx = threadIdx.x & 31, ty = threadIdx.x >> 5;
#pragma unroll
    for (int i = 0; i < 4; i++)
        tile[ty + 8 * i][tx] = src[(size_t)(k0 + ty + 8 * i) * EE + n0 + tx];
    __syncthreads();
#pragma unroll
    for (int i = 0; i < 4; i++)
        dst[(size_t)(n0 + ty + 8 * i) * EE + k0 + tx] = f2bf(tile[tx][ty + 8 * i]);
}

// vt[bh][d][j] = vb[bh][j][d]  (bf16, LDS-tiled 64x64)
__global__ __launch_bounds__(256) void transpose_v_kernel(
    const u16* __restrict__ vb, u16* __restrict__ vt) {
    __shared__ u16 tile[64][66];
    int j0 = blockIdx.x * 64, bh = blockIdx.y;
    int tid = threadIdx.x;
#pragma unroll
    for (int i = 0; i < 16; i++) {
        int idx = i * 256 + tid;
        int j = idx >> 6, d = idx & 63;
        tile[j][d] = vb[((size_t)bh * TT + j0 + j) * DD + d];
    }
    __syncthreads();
#pragma unroll
    for (int i = 0; i < 16; i++) {
        int idx = i * 256 + tid;
        int d = idx >> 6, j = idx & 63;
        vt[((size_t)bh * DD + d) * TT + j0 + j] = tile[j][d];
    }
}

// ---------------------------------------------------------------- QKV GEMM (m97 structure)
__global__ __launch_bounds__(256) void gemm_qkv_kernel(
    const u16* __restrict__ A, const u16* __restrict__ Bt,
    u16* __restrict__ qb, u16* __restrict__ kb, u16* __restrict__ vb)
{
    __shared__ __align__(16) u16 As[128 * 32];
    __shared__ __align__(16) u16 Bs[128 * 32];
    const int K = EE;
    int tid = threadIdx.x;
    int w = tid >> 6, l = tid & 63;
    int lo = l & 15, hi = l >> 4;
    int wm = w >> 1, wn = w & 1;
    int m0 = blockIdx.x * 128;
    int n0 = blockIdx.y * 128;
    int srow = l >> 2, sgrp = l & 3;

    f32x4 acc[4][4] = {};
    for (int k0 = 0; k0 < K; k0 += 32) {
        __syncthreads();
        gld_lds16(A + (size_t)(m0 + w * 16 + srow) * K + k0 + sgrp * 8,       As + w * 512);
        gld_lds16(A + (size_t)(m0 + (w + 4) * 16 + srow) * K + k0 + sgrp * 8, As + (w + 4) * 512);
        gld_lds16(Bt + (size_t)(n0 + w * 16 + srow) * K + k0 + sgrp * 8,       Bs + w * 512);
        gld_lds16(Bt + (size_t)(n0 + (w + 4) * 16 + srow) * K + k0 + sgrp * 8, Bs + (w + 4) * 512);
        __syncthreads();
        bf16x8 af[4], bfr[4];
#pragma unroll
        for (int i = 0; i < 4; i++)
            af[i] = *(const bf16x8*)(As + (wm * 64 + i * 16 + lo) * 32 + hi * 8);
#pragma unroll
        for (int j = 0; j < 4; j++)
            bfr[j] = *(const bf16x8*)(Bs + (wn * 64 + j * 16 + lo) * 32 + hi * 8);
#pragma unroll
        for (int i = 0; i < 4; i++)
#pragma unroll
            for (int j = 0; j < 4; j++)
                acc[i][j] = __builtin_amdgcn_mfma_f32_16x16x32_bf16(af[i], bfr[j], acc[i][j], 0, 0, 0);
    }
    int sel = n0 / EE;
    int rem0 = n0 - sel * EE;
    u16* dst = (sel == 0) ? qb : (sel == 1) ? kb : vb;
    // q pre-scaled by 1/sqrt(D) * log2(e) so flash can use exp2 directly
    float mul = (sel == 0) ? 0.125f * 1.44269504f : 1.f;
#pragma unroll
    for (int j = 0; j < 4; j++) {
        int h = (rem0 + wn * 64 + j * 16) >> 6;
        int d = (wn * 64 + j * 16 + lo) & 63;
#pragma unroll
        for (int i = 0; i < 4; i++)
#pragma unroll
            for (int r = 0; r < 4; r++) {
                int m = m0 + wm * 64 + i * 16 + hi * 4 + r;
                int b = m >> 11, t = m & 2047;
                dst[((size_t)(b * HH + h) * TT + t) * DD + d] = f2bf(acc[i][j][r] * mul);
            }
    }
}

// ---------------------------------------------------------------- r = scale * x . wr
__global__ __launch_bounds__(256) void r_partial_kernel(
    const float* __restrict__ xt, const float* __restrict__ wr, float* __restrict__ rp) {
    int ech = blockIdx.x;           // 0..47
    int tch = blockIdx.y;           // 0..1
    int hg = blockIdx.z;            // 0..1
    int e0 = ech * 16, h0 = hg * 6;
    int tv = tch * 256 + threadIdx.x;
    const f32x4* xt4 = (const f32x4*)xt;
    const f32x4* wr4 = (const f32x4*)wr;
    f32x4 acc[2][6] = {};
#pragma unroll 4
    for (int e = 0; e < 16; e++) {
        f32x4 x0 = xt4[(size_t)(e0 + e) * 512 + tv];
        f32x4 x1 = xt4[(size_t)(EE + e0 + e) * 512 + tv];
#pragma unroll
        for (int hh = 0; hh < 6; hh++) {
            f32x4 w = wr4[((size_t)(h0 + hh) * EE + e0 + e) * 512 + tv];
            acc[0][hh] += w * x0;
            acc[1][hh] += w * x1;
        }
    }
    f32x4* rp4 = (f32x4*)rp;
#pragma unroll
    for (int b = 0; b < 2; b++)
#pragma unroll
        for (int hh = 0; hh < 6; hh++)
            rp4[((size_t)ech * 24 + b * 12 + h0 + hh) * 512 + tv] = acc[b][hh];
}

__global__ __launch_bounds__(256) void r_reduce_kernel(
    const float* __restrict__ rp, float* __restrict__ r, float* __restrict__ rmax) {
    int bh = blockIdx.x, tid = threadIdx.x;
    const f32x4* rp4 = (const f32x4*)rp;
    f32x4* r4 = (f32x4*)r;
    float mloc = -INFINITY;
#pragma unroll
    for (int seg = 0; seg < 2; seg++) {
        int tv = seg * 256 + tid;
        f32x4 s = {};
#pragma unroll 8
        for (int ech = 0; ech < 48; ech++)
            s += rp4[((size_t)ech * 24 + bh) * 512 + tv];
        s *= 0.125f;
        r4[(size_t)bh * 512 + tv] = s;
        mloc = fmaxf(mloc, fmaxf(fmaxf(s[0], s[1]), fmaxf(s[2], s[3])));
    }
    __shared__ float sm[256];
    sm[tid] = mloc; __syncthreads();
    for (int s = 128; s > 0; s >>= 1) {
        if (tid < s) sm[tid] = fmaxf(sm[tid], sm[tid + s]);
        __syncthreads();
    }
    if (tid == 0) rmax[bh] = sm[0];
}

// ---------------------------------------------------------------- rr attention = chunked prefix scan
__global__ __launch_bounds__(64) void scan_part_kernel(
    const float* __restrict__ r, const float* __restrict__ rmax,
    const u16* __restrict__ vb, float* __restrict__ Sv, float* __restrict__ Sl) {
    int c = blockIdx.x, bh = blockIdx.y, d = threadIdx.x;
    float mx = rmax[bh];
    const float* rp = r + (size_t)bh * TT + c * 128;
    const u16* vp = vb + ((size_t)bh * TT + c * 128) * DD + d;
    float accv = 0.f, accl = 0.f;
#pragma unroll 4
    for (int j = 0; j < 128; j++) {
        float w = __expf(rp[j] - mx);
        accv += w * bf2f(vp[(size_t)j * DD]);
        accl += w;
    }
    Sv[((size_t)bh * SCH + c) * DD + d] = accv;
    if (d == 0) Sl[bh * SCH + c] = accl;
}

__global__ __launch_bounds__(64) void scan_out_kernel(
    const float* __restrict__ r, const float* __restrict__ rmax,
    const u16* __restrict__ vb, const float* __restrict__ Sv, const float* __restrict__ Sl,
    u16* __restrict__ outr) {
    int c = blockIdx.x, bh = blockIdx.y, d = threadIdx.x;
    float mx = rmax[bh];
    float acc = 0.f, accl = 0.f;
    for (int cp = 0; cp < c; cp++) {
        acc += Sv[((size_t)bh * SCH + cp) * DD + d];
        accl += Sl[bh * SCH + cp];
    }
    const float* rp = r + (size_t)bh * TT + c * 128;
    const u16* vp = vb + ((size_t)bh * TT + c * 128) * DD + d;
    u16* op = outr + ((size_t)bh * TT + c * 128) * DD + d;
#pragma unroll 2
    for (int j = 0; j < 128; j++) {
        float w = __expf(rp[j] - mx);
        acc += w * bf2f(vp[(size_t)j * DD]);
        accl += w;
        op[(size_t)j * DD] = f2bf(acc * __builtin_amdgcn_rcpf(accl));
    }
}

// ---------------------------------------------------------------- content flash attention, split-K, 32x32 MFMA
// Double-buffered async K/V staging (global_load_lds, pre-swizzled global src).
// S^T = mfma32(K, Q): lane owns q = qw0 + (l&31); softmax in-register; defer-max THR=8.
// P^T B-frags via cvt_pk + permlane32_swap. PV: O^T = mfma32(V^T, P^T).
__global__ __launch_bounds__(256) void flash_kernel(
    const u16* __restrict__ qb, const u16* __restrict__ kb,
    const u16* __restrict__ vt, u16* __restrict__ op,
    float* __restrict__ mb, float* __restrict__ lb) {
    __shared__ __align__(16) u16 KV[2][2][64 * 64];   // [buf][K/V][row*64]
    int qt = (int)gridDim.x - 1 - (int)blockIdx.x;   // heavy tiles first
    int sg = blockIdx.y, bh = blockIdx.z;
    int q0 = qt * QBLK;
    int ks0 = sg * KSEG;
    if (ks0 > q0) return;                   // segment has no causal keys for this tile
    int kend = min(ks0 + KSEG, q0 + QBLK);
    int nc = (kend - ks0) >> 6;
    int tid = threadIdx.x, w = tid >> 6, l = tid & 63;
    int q31 = l & 31, hb = l >> 5;
    int qw0 = q0 + w * 32;
    int myq = qw0 + q31;
    const u16* qbase = qb + (size_t)bh * TT * DD;
    const u16* kbase = kb + (size_t)bh * TT * DD;
    const u16* vtb = vt + (size_t)bh * DD * TT;

    // staging coords: lane -> (row, slot); global src pre-swizzled so linear LDS dest
    // matches the swz() read pattern
    int sr0 = w * 8 + (l >> 3);
    int sg8 = (((l & 7) ^ (sr0 & 7)) << 3);
    auto stage = [&](int j0, int bbuf) {
        u16* kd = &KV[bbuf][0][0];
        u16* vd = &KV[bbuf][1][0];
        gld_lds16(kbase + (size_t)(j0 + sr0) * DD + sg8,      kd + w * 512);
        gld_lds16(kbase + (size_t)(j0 + sr0 + 32) * DD + sg8, kd + 2048 + w * 512);
        gld_lds16(vtb + (size_t)sr0 * TT + j0 + sg8,          vd + w * 512);
        gld_lds16(vtb + (size_t)(sr0 + 32) * TT + j0 + sg8,   vd + 2048 + w * 512);
    };

    // Q B-frags: col=q, k(d) = mm*16 + hb*8 + e
    bf16x8 bQ[4];
#pragma unroll
    for (int mm = 0; mm < 4; mm++)
        bQ[mm] = *(const bf16x8*)(qbase + (size_t)myq * DD + mm * 16 + hb * 8);

    float m_ = -INFINITY, ls = 0.f;
    f32x16 o[2] = {};

    stage(ks0, 0);
    __syncthreads();
    for (int ci = 0; ci < nc; ci++) {
        int j0 = ks0 + ci * 64;
        int bbuf = ci & 1;
        if (ci + 1 < nc) stage(j0 + 64, bbuf ^ 1);   // async, overlaps compute below
        if (j0 <= qw0 + 31) {
            const u16* Kt = &KV[bbuf][0][0];
            const u16* Vt = &KV[bbuf][1][0];
            // S^T: s[kt][reg] = score(q=myq, k = j0 + kt*32 + (reg&3)+8*(reg>>2)+4*hb)
            f32x16 s[2] = {};
#pragma unroll
            for (int kt = 0; kt < 2; kt++)
#pragma unroll
                for (int mm = 0; mm < 4; mm++) {
                    bf16x8 aK = *(const bf16x8*)(Kt + swz(kt * 32 + q31, mm * 2 + hb));
                    s[kt] = __builtin_amdgcn_mfma_f32_32x32x16_bf16(aK, bQ[mm], s[kt], 0, 0, 0);
                }
            if (j0 + 63 > qw0) {
#pragma unroll
                for (int kt = 0; kt < 2; kt++)
#pragma unroll
                    for (int reg = 0; reg < 16; reg++) {
                        int k = j0 + kt * 32 + (reg & 3) + 8 * (reg >> 2) + 4 * hb;
                        if (k > myq) s[kt][reg] = -INFINITY;
                    }
            }
            float tm = -INFINITY;
#pragma unroll
            for (int kt = 0; kt < 2; kt++)
#pragma unroll
                for (int reg = 0; reg < 16; reg++) tm = fmaxf(tm, s[kt][reg]);
            tm = fmaxf(tm, __shfl_xor(tm, 32, 64));
            // defer-max: only rescale when the new tile max meaningfully exceeds m_
            if (__any(tm > m_ + 8.f)) {
                float mn = fmaxf(m_, tm);
                float f = fexp2(m_ - mn);
                m_ = mn;
                ls *= f;
#pragma unroll
                for (int dt = 0; dt < 2; dt++)
#pragma unroll
                    for (int reg = 0; reg < 16; reg++) o[dt][reg] *= f;
            }
            float rs = 0.f;
#pragma unroll
            for (int kt = 0; kt < 2; kt++)
#pragma unroll
                for (int reg = 0; reg < 16; reg++) {
                    s[kt][reg] = fexp2(s[kt][reg] - m_);
                    rs += s[kt][reg];
                }
            rs += __shfl_xor(rs, 32, 64);
            ls += rs;

            // P^T B-frags + PV
#pragma unroll
            for (int kt = 0; kt < 2; kt++) {
                unsigned W[4][2];
#pragma unroll
                for (int g4 = 0; g4 < 4; g4++) {
                    W[g4][0] = cvtpk(s[kt][4 * g4], s[kt][4 * g4 + 1]);
                    W[g4][1] = cvtpk(s[kt][4 * g4 + 2], s[kt][4 * g4 + 3]);
                }
#pragma unroll
                for (int f2 = 0; f2 < 2; f2++) {
                    unsigned a0 = W[2 * f2][0], b0 = W[2 * f2 + 1][0];
                    unsigned a1 = W[2 * f2][1], b1 = W[2 * f2 + 1][1];
                    asm volatile("v_permlane32_swap_b32 %0, %1" : "+v"(a0), "+v"(b0));
                    asm volatile("v_permlane32_swap_b32 %0, %1" : "+v"(a1), "+v"(b1));
                    union { unsigned u[4]; bf16x8 v; } bp;
                    bp.u[0] = a0; bp.u[1] = a1; bp.u[2] = b0; bp.u[3] = b1;
#pragma unroll
                    for (int dt = 0; dt < 2; dt++) {
                        bf16x8 aV = *(const bf16x8*)(Vt + swz(dt * 32 + q31, kt * 4 + f2 * 2 + hb));
                        o[dt] = __builtin_amdgcn_mfma_f32_32x32x16_bf16(aV, bp.v, o[dt], 0, 0, 0);
                    }
                }
            }
        }
        __syncthreads();   // drains next-chunk loads (after compute) + guards buffer reuse
    }
    size_t pb = (size_t)(bh * 4 + sg) * TT;
    float inv = 1.f / ls;
#pragma unroll
    for (int dt = 0; dt < 2; dt++)
#pragma unroll
        for (int g4 = 0; g4 < 4; g4++) {
            u16x4 pk4;
#pragma unroll
            for (int c = 0; c < 4; c++) pk4[c] = f2bf(o[dt][4 * g4 + c] * inv);
            *(u16x4*)(op + (pb + myq) * DD + dt * 32 + 8 * g4 + 4 * hb) = pk4;
        }
    if (hb == 0) {
        mb[pb + myq] = m_;
        lb[pb + myq] = ls;
    }
}

// merge partials (weights computed inline, base-2 domain) + combine with rr branch
__global__ void merge_kernel(const u16* __restrict__ op,
                             const float* __restrict__ mb, const float* __restrict__ lb,
                             const u16* __restrict__ outr, const float* __restrict__ alpha,
                             u16* __restrict__ comb) {
    int i8 = blockIdx.x * blockDim.x + threadIdx.x;
    if (i8 >= M4 * EE / 8) return;
    int bt = i8 / (EE / 8), c8 = i8 - bt * (EE / 8);
    int h = c8 >> 3, d8 = c8 & 7;
    int b = bt >> 11, t = bt & 2047;
    int bh = b * HH + h;
    int ns = (t >> 9) + 1;
    size_t base = (size_t)bh * 4 * TT + t;
    float M = -INFINITY;
    for (int s = 0; s < ns; s++) M = fmaxf(M, mb[base + (size_t)s * TT]);
    float e[4], L = 0.f;
    for (int s = 0; s < ns; s++) {
        e[s] = lb[base + (size_t)s * TT] * fexp2(mb[base + (size_t)s * TT] - M);
        L += e[s];
    }
    float invL = 1.f / L;
    float acc[8] = {};
    for (int s = 0; s < ns; s++) {
        size_t row = base + (size_t)s * TT;
        float wv = e[s] * invL;
        union { u16 u[8]; bf16x8 v; } pv;
        pv.v = *(const bf16x8*)(op + row * DD + d8 * 8);
#pragma unroll
        for (int ee = 0; ee < 8; ee++) acc[ee] += wv * bf2f(pv.u[ee]);
    }
    float a = 1.f / (1.f + __expf(-alpha[h]));
    union { u16 u[8]; bf16x8 v; } vr, vo;
    vr.v = *(const bf16x8*)(outr + (((size_t)bh * TT + t) * DD + d8 * 8));
#pragma unroll
    for (int ee = 0; ee < 8; ee++)
        vo.u[ee] = f2bf(a * bf2f(vr.u[ee]) + (1.f - a) * acc[ee]);
    ((bf16x8*)comb)[i8] = vo.v;
}

// ---------------------------------------------------------------- output GEMM (m97 structure)
__global__ __launch_bounds__(256) void gemm_out_kernel(const u16* __restrict__ A,
                                                       const u16* __restrict__ Bt,
                                                       float* __restrict__ C) {
    __shared__ __align__(16) u16 As[128 * 32];
    __shared__ __align__(16) u16 Bs[128 * 32];
    const int K = EE;
    int tid = threadIdx.x;
    int w = tid >> 6, l = tid & 63;
    int lo = l & 15, hi = l >> 4;
    int wm = w >> 1, wn = w & 1;
    int m0 = blockIdx.x * 128;
    int n0 = blockIdx.y * 128;
    int srow = l >> 2, sgrp = l & 3;

    f32x4 acc[4][4] = {};
    for (int k0 = 0; k0 < K; k0 += 32) {
        __syncthreads();
        gld_lds16(A + (size_t)(m0 + w * 16 + srow) * K + k0 + sgrp * 8,       As + w * 512);
        gld_lds16(A + (size_t)(m0 + (w + 4) * 16 + srow) * K + k0 + sgrp * 8, As + (w + 4) * 512);
        gld_lds16(Bt + (size_t)(n0 + w * 16 + srow) * K + k0 + sgrp * 8,       Bs + w * 512);
        gld_lds16(Bt + (size_t)(n0 + (w + 4) * 16 + srow) * K + k0 + sgrp * 8, Bs + (w + 4) * 512);
        __syncthreads();
        bf16x8 af[4], bfr[4];
#pragma unroll
        for (int i = 0; i < 4; i++)
            af[i] = *(const bf16x8*)(As + (wm * 64 + i * 16 + lo) * 32 + hi * 8);
#pragma unroll
        for (int j = 0; j < 4; j++)
            bfr[j] = *(const bf16x8*)(Bs + (wn * 64 + j * 16 + lo) * 32 + hi * 8);
#pragma unroll
        for (int i = 0; i < 4; i++)
#pragma unroll
            for (int j = 0; j < 4; j++)
                acc[i][j] = __builtin_amdgcn_mfma_f32_16x16x32_bf16(af[i], bfr[j], acc[i][j], 0, 0, 0);
    }
#pragma unroll
    for (int i = 0; i < 4; i++)
#pragma unroll
        for (int j = 0; j < 4; j++)
#pragma unroll
            for (int r = 0; r < 4; r++) {
                int m = m0 + wm * 64 + i * 16 + hi * 4 + r;
                int n = n0 + wn * 64 + j * 16 + lo;
                C[(size_t)m * EE + n] = acc[i][j][r];
            }
}

// ----------------------------------------------------------------
extern "C" void kernel_launch(void* const* d_in, const int* in_sizes, int n_in,
                              void* d_out, int out_size, void* d_ws, size_t ws_size,
                              hipStream_t stream) {
    const float* x = (const float*)d_in[0];
    const float* wq = (const float*)d_in[1];
    const float* wk = (const float*)d_in[2];
    const float* wv = (const float*)d_in[3];
    const float* wr = (const float*)d_in[4];
    const float* alpha = (const float*)d_in[5];
    const float* wo = (const float*)d_in[6];
    float* out = (float*)d_out;

    char* ws = (char*)d_ws;
    size_t off = 0;
    auto carve = [&](size_t bytes) -> char* {
        char* p = ws + off;
        off += (bytes + 255) & ~(size_t)255;
        return p;
    };
    u16* xb    = (u16*)carve((size_t)M4 * EE * 2);
    u16* wqkvt = (u16*)carve((size_t)NQKV * EE * 2);
    u16* wot   = (u16*)carve((size_t)EE * EE * 2);
    u16* qb    = (u16*)carve((size_t)BH * TT * DD * 2);
    u16* kb    = (u16*)carve((size_t)BH * TT * DD * 2);
    u16* vb    = (u16*)carve((size_t)BH * TT * DD * 2);
    u16* vt    = (u16*)carve((size_t)BH * TT * DD * 2);
    float* xt   = (float*)carve((size_t)BB * EE * TT * 4);
    float* rpbuf= (float*)carve((size_t)48 * BH * TT * 4);
    float* rbuf = (float*)carve((size_t)BH * TT * 4);
    float* rmx  = (float*)carve((size_t)BH * 4);
    float* Sv   = (float*)carve((size_t)BH * SCH * DD * 4);
    float* Sl   = (float*)carve((size_t)BH * SCH * 4);
    u16* outr  = (u16*)carve((size_t)BH * TT * DD * 2);
    u16* opart = (u16*)carve((size_t)BH * 4 * TT * DD * 2);
    float* mbuf = (float*)carve((size_t)BH * 4 * TT * 4);
    float* lbuf = (float*)carve((size_t)BH * 4 * TT * 4);
    u16* comb  = (u16*)carve((size_t)M4 * EE * 2);

    transpose_x_kernel<<<dim3(TT / 32, EE / 32, BB), 256, 0, stream>>>(x, xt, xb);
    transpose_w_kernel<<<dim3(EE / 32, EE / 32, 4), 256, 0, stream>>>(wq, wk, wv, wo, wqkvt, wot);

    dim3 gq(M4 / 128, NQKV / 128);
    gemm_qkv_kernel<<<gq, 256, 0, stream>>>(xb, wqkvt, qb, kb, vb);
    transpose_v_kernel<<<dim3(TT / 64, BH), 256, 0, stream>>>(vb, vt);

    r_partial_kernel<<<dim3(48, 2, 2), 256, 0, stream>>>(xt, wr, rpbuf);
    r_reduce_kernel<<<BH, 256, 0, stream>>>(rpbuf, rbuf, rmx);

    scan_part_kernel<<<dim3(SCH, BH), 64, 0, stream>>>(rbuf, rmx, vb, Sv, Sl);
    scan_out_kernel<<<dim3(SCH, BH), 64, 0, stream>>>(rbuf, rmx, vb, Sv, Sl, outr);

    flash_kernel<<<dim3(TT / QBLK, 4, BH), 256, 0, stream>>>(qb, kb, vt, opart, mbuf, lbuf);
    merge_kernel<<<(M4 * EE / 8 + 255) / 256, 256, 0, stream>>>(opart, mbuf, lbuf, outr, alpha, comb);

    dim3 go(M4 / 128, EE / 128);
    gemm_out_kernel<<<go, 256, 0, stream>>>(comb, wot, out);
}